// Round 1
// baseline (1965.711 us; speedup 1.0000x reference)
//
#include <hip/hip_runtime.h>
#include <hip/hip_bf16.h>
#include <cstdint>
#include <cstddef>

#define DEV static __device__ __forceinline__

constexpr int GRAPHS = 128;
constexpr int NPG    = 1000;   // nodes per graph
constexpr int EPG    = 4000;   // edges per graph
constexpr int TOTN   = GRAPHS * NPG;  // 128000
constexpr int HD     = 64;
constexpr int OBSD   = 1500;
constexpr int AD     = 15;

// ---------- helpers ----------
DEV float bf2f_lo(unsigned u){ return __uint_as_float(u << 16); }
DEV float bf2f_hi(unsigned u){ return __uint_as_float(u & 0xffff0000u); }

DEV void cvt8(uint4 u, float* f){
  f[0]=bf2f_lo(u.x); f[1]=bf2f_hi(u.x);
  f[2]=bf2f_lo(u.y); f[3]=bf2f_hi(u.y);
  f[4]=bf2f_lo(u.z); f[5]=bf2f_hi(u.z);
  f[6]=bf2f_lo(u.w); f[7]=bf2f_hi(u.w);
}

DEV unsigned short f2b(float f){   // round-to-nearest-even bf16
  unsigned u = __float_as_uint(f);
  return (unsigned short)((u + 0x7fffu + ((u >> 16) & 1u)) >> 16);
}

DEV ushort4 pack4(float4 v){
  ushort4 r; r.x=f2b(v.x); r.y=f2b(v.y); r.z=f2b(v.z); r.w=f2b(v.w); return r;
}

DEV void fma4(float4& a, float s, const float4 w){
  a.x = fmaf(s, w.x, a.x); a.y = fmaf(s, w.y, a.y);
  a.z = fmaf(s, w.z, a.z); a.w = fmaf(s, w.w, a.w);
}

DEV float4 add4(float4 a, float4 b){
  return make_float4(a.x+b.x, a.y+b.y, a.z+b.z, a.w+b.w);
}

DEV float4 relu4(float4 a){
  return make_float4(fmaxf(a.x,0.f), fmaxf(a.y,0.f), fmaxf(a.z,0.f), fmaxf(a.w,0.f));
}

// LayerNorm over 64 cols spread across a 16-lane cg group (4 cols/lane).
DEV float4 ln4(float4 t, float4 gg, float4 bb){
  float sm = t.x+t.y+t.z+t.w;
  float sq = t.x*t.x+t.y*t.y+t.z*t.z+t.w*t.w;
  #pragma unroll
  for (int m=1;m<16;m<<=1){ sm += __shfl_xor(sm, m); sq += __shfl_xor(sq, m); }
  float mean = sm*0.015625f;
  float var  = sq*0.015625f - mean*mean;
  float rs   = rsqrtf(var + 1e-5f);
  return make_float4((t.x-mean)*rs*gg.x+bb.x, (t.y-mean)*rs*gg.y+bb.y,
                     (t.z-mean)*rs*gg.z+bb.z, (t.w-mean)*rs*gg.w+bb.w);
}

// ---------- K1: x = node_feats @ W_in  [128000,32]x[32,64] ----------
__global__ __launch_bounds__(256) void k_in(const float* __restrict__ nf,
                                            const float* __restrict__ Win,
                                            float* __restrict__ x){
  __shared__ float  s_nf[256*36];   // 256 nodes, stride 36 (pad)
  __shared__ float4 s_w[512];       // 32x64 = [k][16 f4]
  const int tid = threadIdx.x;
  const int node0 = blockIdx.x * 256;
  const float4* W4 = (const float4*)Win;
  s_w[tid] = W4[tid]; s_w[tid+256] = W4[tid+256];
  const float4* nf4 = (const float4*)nf;
  float4* snf4 = (float4*)s_nf;
  #pragma unroll
  for (int r=0;r<8;r++){
    int i = tid + 256*r; int n = i>>3, k4 = i&7;
    snf4[n*9 + k4] = nf4[(size_t)(node0+n)*8 + k4];
  }
  __syncthreads();
  const int ng = tid>>2, cg = tid&3;   // 64 node-groups x 4 col-groups
  float4 acc[4][4];
  #pragma unroll
  for (int i=0;i<4;i++){ acc[i][0]=make_float4(0,0,0,0); acc[i][1]=make_float4(0,0,0,0);
                         acc[i][2]=make_float4(0,0,0,0); acc[i][3]=make_float4(0,0,0,0); }
  #pragma unroll 4
  for (int k=0;k<32;k++){
    float nv[4];
    #pragma unroll
    for (int i=0;i<4;i++) nv[i] = s_nf[(ng + 64*i)*36 + k];
    float4 w[4];
    #pragma unroll
    for (int j=0;j<4;j++) w[j] = s_w[k*16 + cg*4 + j];
    #pragma unroll
    for (int i=0;i<4;i++){
      #pragma unroll
      for (int j=0;j<4;j++) fma4(acc[i][j], nv[i], w[j]);
    }
  }
  float4* x4 = (float4*)x;
  #pragma unroll
  for (int i=0;i<4;i++){
    size_t nidx = (size_t)(node0 + ng + 64*i) * 16;
    #pragma unroll
    for (int j=0;j<4;j++) x4[nidx + cg*4 + j] = acc[i][j];
  }
}

// ---------- K2: qkv(bf16) = x @ [Wq|Wk|Wv]  [.,64]x[64,192] ----------
__global__ __launch_bounds__(128) void k_qkv(const float* __restrict__ x,
                                             const float* __restrict__ Wq_l,
                                             const float* __restrict__ Wk_l,
                                             const float* __restrict__ Wv_l,
                                             unsigned short* __restrict__ qkv){
  __shared__ float s_w[64*192];     // [k][192]
  __shared__ float s_x[32*68];      // 32 nodes, stride 68
  const int tid = threadIdx.x;
  const int node0 = blockIdx.x * 32;
  float4* sw4 = (float4*)s_w;
  const float4* q4  = (const float4*)Wq_l;
  const float4* kk4 = (const float4*)Wk_l;
  const float4* v4  = (const float4*)Wv_l;
  #pragma unroll
  for (int r=0;r<24;r++){
    int i = tid + 128*r;
    int sec = i >> 10, rem = i & 1023;
    int k = rem >> 4, c4 = rem & 15;
    const float4* src = (sec==0) ? q4 : (sec==1) ? kk4 : v4;
    sw4[k*48 + sec*16 + c4] = src[k*16 + c4];
  }
  float4* sx4 = (float4*)s_x;
  const float4* x4 = (const float4*)x;
  #pragma unroll
  for (int r=0;r<4;r++){
    int i = tid + 128*r; int n = i>>4, k4 = i&15;
    sx4[n*17 + k4] = x4[(size_t)(node0+n)*16 + k4];
  }
  __syncthreads();
  const int ng = tid>>4, cg = tid&15;   // 8 node-groups(4 ea) x 16 col-groups(12 ea)
  float4 acc[4][3];
  #pragma unroll
  for (int i=0;i<4;i++){ acc[i][0]=make_float4(0,0,0,0); acc[i][1]=make_float4(0,0,0,0);
                         acc[i][2]=make_float4(0,0,0,0); }
  #pragma unroll 2
  for (int k=0;k<64;k++){
    float4 w[3];
    #pragma unroll
    for (int s=0;s<3;s++) w[s] = sw4[k*48 + s*16 + cg];
    #pragma unroll
    for (int i=0;i<4;i++){
      float xv = s_x[(ng*4+i)*68 + k];
      fma4(acc[i][0], xv, w[0]); fma4(acc[i][1], xv, w[1]); fma4(acc[i][2], xv, w[2]);
    }
  }
  ushort4* out4 = (ushort4*)qkv;
  #pragma unroll
  for (int i=0;i<4;i++){
    size_t node = (size_t)(node0 + ng*4 + i);
    #pragma unroll
    for (int s=0;s<3;s++) out4[node*48 + s*16 + cg] = pack4(acc[i][s]);
  }
}

// ---------- K4: edge attention (per graph/head/half-node-range) ----------
__global__ __launch_bounds__(256) void k_edge(const unsigned short* __restrict__ qkv,
    const int* __restrict__ esrc, const int* __restrict__ edst,
    float* __restrict__ agg, float* __restrict__ denom){
  __shared__ float s_agg[500*17];
  __shared__ float s_den[500];
  const int tid = threadIdx.x;
  const int g    = blockIdx.x >> 3;
  const int hh   = (blockIdx.x >> 1) & 3;
  const int half = blockIdx.x & 1;
  const int ebase = g * EPG;
  const int nbase = g * NPG + half * 500;
  for (int i=tid;i<500*17;i+=256) s_agg[i] = 0.f;
  for (int i=tid;i<500;  i+=256) s_den[i] = 0.f;
  __syncthreads();
  for (int idx=tid; idx<EPG; idx+=256){
    int dst = edst[ebase + idx];
    unsigned rel = (unsigned)(dst - nbase);
    if (rel >= 500u) continue;
    int src = esrc[ebase + idx];
    const uint4* qp = (const uint4*)(qkv + (size_t)dst*192 + hh*16);
    const uint4* kp = (const uint4*)(qkv + (size_t)src*192 + 64 + hh*16);
    float qf[16], kf[16];
    cvt8(qp[0], qf); cvt8(qp[1], qf+8);
    cvt8(kp[0], kf); cvt8(kp[1], kf+8);
    float s = 0.f;
    #pragma unroll
    for (int d=0;d<16;d++) s = fmaf(qf[d], kf[d], s);
    // softmax is shift-invariant: skip segment_max (|s| <= ~8, exp safe in fp32)
    float w = __expf(s * 0.25f);
    unsafeAtomicAdd(&s_den[rel], w);
    const uint4* vp = (const uint4*)(qkv + (size_t)src*192 + 128 + hh*16);
    float vf[16];
    cvt8(vp[0], vf); cvt8(vp[1], vf+8);
    #pragma unroll
    for (int d=0;d<16;d++) unsafeAtomicAdd(&s_agg[rel*17 + d], w * vf[d]);
  }
  __syncthreads();
  float4* agg4 = (float4*)agg;
  for (int i=tid; i<2000; i+=256){
    int nl = i>>2, d4 = i&3;
    float4 o = make_float4(s_agg[nl*17+d4*4], s_agg[nl*17+d4*4+1],
                           s_agg[nl*17+d4*4+2], s_agg[nl*17+d4*4+3]);
    agg4[(size_t)(nbase+nl)*16 + hh*4 + d4] = o;
  }
  for (int i=tid;i<500;i+=256) denom[(size_t)(nbase+i)*4 + hh] = s_den[i];
}

// ---------- K5: x = LN(x + (agg/denom) @ Wo) ----------
__global__ __launch_bounds__(128) void k_attn(const float* __restrict__ agg,
    const float* __restrict__ denom, const float* __restrict__ Wo_l,
    const float* __restrict__ lg, const float* __restrict__ lb,
    float* __restrict__ x){
  __shared__ float4 s_w[1024];     // 64x64
  __shared__ float  s_a[32*68];
  const int tid = threadIdx.x, node0 = blockIdx.x*32;
  const float4* w4 = (const float4*)Wo_l;
  #pragma unroll
  for (int r=0;r<8;r++) s_w[tid + 128*r] = w4[tid + 128*r];
  const float4* agg4 = (const float4*)agg;
  float4* sa4 = (float4*)s_a;
  #pragma unroll
  for (int r=0;r<4;r++){
    int i = tid + 128*r; int n = i>>4, c4 = i&15;
    float4 a = agg4[(size_t)(node0+n)*16 + c4];
    float den = denom[(size_t)(node0+n)*4 + (c4>>2)];
    float inv = 1.0f/(den + 1e-9f);
    a.x*=inv; a.y*=inv; a.z*=inv; a.w*=inv;
    sa4[n*17 + c4] = a;
  }
  __syncthreads();
  const int ng = tid>>4, cg = tid&15;
  float4 acc[4];
  #pragma unroll
  for (int i=0;i<4;i++) acc[i]=make_float4(0,0,0,0);
  #pragma unroll 2
  for (int k=0;k<64;k++){
    float4 w = s_w[k*16 + cg];
    #pragma unroll
    for (int i=0;i<4;i++){ float a = s_a[(ng*4+i)*68 + k]; fma4(acc[i], a, w); }
  }
  float4* x4 = (float4*)x;
  float4 gg = ((const float4*)lg)[cg];
  float4 bb = ((const float4*)lb)[cg];
  #pragma unroll
  for (int i=0;i<4;i++){
    size_t idx = (size_t)(node0 + ng*4 + i)*16 + cg;
    float4 t = add4(x4[idx], acc[i]);
    x4[idx] = ln4(t, gg, bb);
  }
}

// ---------- K6: h(bf16) = relu(x @ W1 + b1)  [.,64]x[64,128] ----------
__global__ __launch_bounds__(128) void k_ffn1(const float* __restrict__ x,
    const float* __restrict__ W1_l, const float* __restrict__ b1_l,
    unsigned short* __restrict__ h){
  __shared__ float4 s_w[2048];   // 64x128
  __shared__ float  s_x[32*68];
  const int tid = threadIdx.x, node0 = blockIdx.x*32;
  const float4* w4 = (const float4*)W1_l;
  #pragma unroll
  for (int r=0;r<16;r++) s_w[tid + 128*r] = w4[tid + 128*r];
  float4* sx4 = (float4*)s_x;
  const float4* x4 = (const float4*)x;
  #pragma unroll
  for (int r=0;r<4;r++){
    int i = tid + 128*r; int n = i>>4, k4 = i&15;
    sx4[n*17 + k4] = x4[(size_t)(node0+n)*16 + k4];
  }
  __syncthreads();
  const int ng = tid>>4, cg = tid&15;   // cols = cg*8 .. +7
  float4 a0[4], a1[4];
  #pragma unroll
  for (int i=0;i<4;i++){ a0[i]=make_float4(0,0,0,0); a1[i]=make_float4(0,0,0,0); }
  #pragma unroll 2
  for (int k=0;k<64;k++){
    float4 w0 = s_w[k*32 + cg*2], w1 = s_w[k*32 + cg*2 + 1];
    #pragma unroll
    for (int i=0;i<4;i++){
      float xv = s_x[(ng*4+i)*68 + k];
      fma4(a0[i], xv, w0); fma4(a1[i], xv, w1);
    }
  }
  float4 bb0 = ((const float4*)b1_l)[cg*2], bb1 = ((const float4*)b1_l)[cg*2+1];
  ushort4* h4 = (ushort4*)h;
  #pragma unroll
  for (int i=0;i<4;i++){
    size_t node = (size_t)(node0 + ng*4 + i);
    h4[node*32 + cg*2]     = pack4(relu4(add4(a0[i], bb0)));
    h4[node*32 + cg*2 + 1] = pack4(relu4(add4(a1[i], bb1)));
  }
}

// ---------- K7: x = LN(x + h @ W2 + b2)  [.,128]x[128,64] ----------
__global__ __launch_bounds__(128) void k_ffn2(const unsigned short* __restrict__ h,
    const float* __restrict__ W2_l, const float* __restrict__ b2_l,
    const float* __restrict__ lg, const float* __restrict__ lb,
    float* __restrict__ x){
  __shared__ float4 s_w[2048];    // 128x64
  __shared__ float  s_h[32*132];
  const int tid = threadIdx.x, node0 = blockIdx.x*32;
  const float4* w4 = (const float4*)W2_l;
  #pragma unroll
  for (int r=0;r<16;r++) s_w[tid + 128*r] = w4[tid + 128*r];
  float4* sh4 = (float4*)s_h;
  const uint4* h8 = (const uint4*)h;
  #pragma unroll
  for (int r=0;r<4;r++){
    int i = tid + 128*r; int n = i>>4, k8 = i&15;
    uint4 u = h8[(size_t)(node0+n)*16 + k8];
    float f[8]; cvt8(u, f);
    sh4[n*33 + k8*2]     = make_float4(f[0],f[1],f[2],f[3]);
    sh4[n*33 + k8*2 + 1] = make_float4(f[4],f[5],f[6],f[7]);
  }
  __syncthreads();
  const int ng = tid>>4, cg = tid&15;
  float4 acc[4];
  #pragma unroll
  for (int i=0;i<4;i++) acc[i]=make_float4(0,0,0,0);
  #pragma unroll 2
  for (int k=0;k<128;k++){
    float4 w = s_w[k*16 + cg];
    #pragma unroll
    for (int i=0;i<4;i++){ float hv = s_h[(ng*4+i)*132 + k]; fma4(acc[i], hv, w); }
  }
  float4* x4 = (float4*)x;
  float4 bb2 = ((const float4*)b2_l)[cg];
  float4 gg  = ((const float4*)lg)[cg];
  float4 bb  = ((const float4*)lb)[cg];
  #pragma unroll
  for (int i=0;i<4;i++){
    size_t idx = (size_t)(node0 + ng*4 + i)*16 + cg;
    float4 t = add4(add4(x4[idx], acc[i]), bb2);
    x4[idx] = ln4(t, gg, bb);
  }
}

// ---------- policy head: one block per batch element ----------
__global__ __launch_bounds__(512) void k_policy(const float* __restrict__ x,
    const float* __restrict__ obs, const int* __restrict__ agents,
    const float* __restrict__ Wr, const float* __restrict__ br,
    const float* __restrict__ Wp1, const float* __restrict__ bp1,
    const float* __restrict__ Wp2, const float* __restrict__ bp2,
    const float* __restrict__ Wlog, const float* __restrict__ blog,
    float* __restrict__ out){
  __shared__ float s_in[AD + OBSD];
  __shared__ float s_f1[512];
  __shared__ float s_f2[512];
  __shared__ float s_xa[64];
  const int tid = threadIdx.x, b = blockIdx.x;
  for (int i=tid;i<OBSD;i+=512) s_in[AD+i] = obs[(size_t)b*OBSD + i];
  if (tid < 64) s_xa[tid] = x[(size_t)agents[b]*HD + tid];
  __syncthreads();
  if (tid < AD){
    float a = br[tid];
    #pragma unroll 4
    for (int k=0;k<HD;k++) a = fmaf(s_xa[k], Wr[k*AD + tid], a);
    s_in[tid] = a;
  }
  __syncthreads();
  {
    float a = bp1[tid];
    #pragma unroll 4
    for (int k=0;k<AD+OBSD;k++) a = fmaf(s_in[k], Wp1[(size_t)k*512 + tid], a);
    s_f1[tid] = tanhf(a);
  }
  __syncthreads();
  {
    float a = bp2[tid];
    #pragma unroll 4
    for (int k=0;k<512;k++) a = fmaf(s_f1[k], Wp2[(size_t)k*512 + tid], a);
    s_f2[tid] = tanhf(a);
  }
  __syncthreads();
  if (tid < AD){
    float a = blog[tid];
    #pragma unroll 4
    for (int k=0;k<512;k++) a = fmaf(s_f2[k], Wlog[k*AD + tid], a);
    out[(size_t)b*AD + tid] = a;
  }
}

// ---------- value head: one block per batch element ----------
__global__ __launch_bounds__(128) void k_value(const float* __restrict__ obs,
    const float* __restrict__ Wv1, const float* __restrict__ bv1,
    const float* __restrict__ Wv2, const float* __restrict__ bv2,
    const float* __restrict__ Wvo, const float* __restrict__ bvo,
    float* __restrict__ out){
  __shared__ float s_obs[OBSD];
  __shared__ float s_v[128];
  __shared__ float s_r[128];
  const int tid = threadIdx.x, b = blockIdx.x;
  for (int i=tid;i<OBSD;i+=128) s_obs[i] = obs[(size_t)b*OBSD + i];
  __syncthreads();
  float a = bv1[tid];
  #pragma unroll 4
  for (int k=0;k<OBSD;k++) a = fmaf(s_obs[k], Wv1[(size_t)k*128 + tid], a);
  s_v[tid] = tanhf(a);
  __syncthreads();
  float a2 = bv2[tid];
  #pragma unroll 4
  for (int k=0;k<128;k++) a2 = fmaf(s_v[k], Wv2[k*128 + tid], a2);
  s_r[tid] = tanhf(a2) * Wvo[tid];
  __syncthreads();
  if (tid < 64){
    float v = s_r[tid] + s_r[tid+64];
    #pragma unroll
    for (int m=32;m>=1;m>>=1) v += __shfl_xor(v, m);
    if (tid==0) out[b] = v + bvo[0];
  }
}

// ---------- launch ----------
extern "C" void kernel_launch(void* const* d_in, const int* in_sizes, int n_in,
                              void* d_out, int out_size, void* d_ws, size_t ws_size,
                              hipStream_t stream) {
  (void)in_sizes; (void)n_in; (void)out_size; (void)ws_size;
  const float* nf     = (const float*)d_in[0];
  const float* obs    = (const float*)d_in[1];
  const int*   esrc   = (const int*)d_in[2];
  const int*   edst   = (const int*)d_in[3];
  const int*   agents = (const int*)d_in[4];
  const float* Win    = (const float*)d_in[5];
  const float* Wq     = (const float*)d_in[6];
  const float* Wk     = (const float*)d_in[7];
  const float* Wv     = (const float*)d_in[8];
  const float* Wo     = (const float*)d_in[9];
  const float* ln1g   = (const float*)d_in[10];
  const float* ln1b   = (const float*)d_in[11];
  const float* W1     = (const float*)d_in[12];
  const float* b1     = (const float*)d_in[13];
  const float* W2     = (const float*)d_in[14];
  const float* b2     = (const float*)d_in[15];
  const float* ln2g   = (const float*)d_in[16];
  const float* ln2b   = (const float*)d_in[17];
  const float* Wr     = (const float*)d_in[18];
  const float* br     = (const float*)d_in[19];
  const float* Wp1    = (const float*)d_in[20];
  const float* bp1    = (const float*)d_in[21];
  const float* Wp2    = (const float*)d_in[22];
  const float* bp2    = (const float*)d_in[23];
  const float* Wlog   = (const float*)d_in[24];
  const float* blog   = (const float*)d_in[25];
  const float* Wv1    = (const float*)d_in[26];
  const float* bv1    = (const float*)d_in[27];
  const float* Wv2    = (const float*)d_in[28];
  const float* bv2    = (const float*)d_in[29];
  const float* Wvo    = (const float*)d_in[30];
  const float* bvo    = (const float*)d_in[31];
  float* out = (float*)d_out;

  // workspace: x(f32) | agg(f32) | denom(f32) | qkv(bf16, aliased by h)
  float* x     = (float*)d_ws;
  float* agg   = x + (size_t)TOTN*HD;
  float* denom = agg + (size_t)TOTN*HD;
  unsigned short* qkv = (unsigned short*)(denom + (size_t)TOTN*4);
  unsigned short* hbuf = qkv;   // FFN intermediate reuses qkv region

  k_in<<<TOTN/256, 256, 0, stream>>>(nf, Win, x);
  for (int l=0; l<4; l++){
    k_qkv <<<TOTN/32, 128, 0, stream>>>(x, Wq + l*4096, Wk + l*4096, Wv + l*4096, qkv);
    k_edge<<<GRAPHS*8, 256, 0, stream>>>(qkv, esrc, edst, agg, denom);
    k_attn<<<TOTN/32, 128, 0, stream>>>(agg, denom, Wo + l*4096,
                                        ln1g + l*64, ln1b + l*64, x);
    k_ffn1<<<TOTN/32, 128, 0, stream>>>(x, W1 + l*8192, b1 + l*128, hbuf);
    k_ffn2<<<TOTN/32, 128, 0, stream>>>(hbuf, W2 + l*8192, b2 + l*64,
                                        ln2g + l*64, ln2b + l*64, x);
  }
  k_policy<<<GRAPHS, 512, 0, stream>>>(x, obs, agents, Wr, br, Wp1, bp1,
                                       Wp2, bp2, Wlog, blog, out);
  k_value <<<GRAPHS, 128, 0, stream>>>(obs, Wv1, bv1, Wv2, bv2, Wvo, bvo,
                                       out + GRAPHS*AD);
}

// Round 2
// 1507.297 us; speedup vs baseline: 1.3041x; 1.3041x over previous
//
#include <hip/hip_runtime.h>
#include <hip/hip_bf16.h>
#include <cstdint>
#include <cstddef>

#define DEV static __device__ __forceinline__

constexpr int GRAPHS = 128;
constexpr int NPG    = 1000;   // nodes per graph
constexpr int EPG    = 4000;   // edges per graph
constexpr int TOTN   = GRAPHS * NPG;  // 128000
constexpr int HD     = 64;
constexpr int OBSD   = 1500;
constexpr int AD     = 15;

// ---------- helpers ----------
DEV float bf2f_lo(unsigned u){ return __uint_as_float(u << 16); }
DEV float bf2f_hi(unsigned u){ return __uint_as_float(u & 0xffff0000u); }

DEV void cvt8(uint4 u, float* f){
  f[0]=bf2f_lo(u.x); f[1]=bf2f_hi(u.x);
  f[2]=bf2f_lo(u.y); f[3]=bf2f_hi(u.y);
  f[4]=bf2f_lo(u.z); f[5]=bf2f_hi(u.z);
  f[6]=bf2f_lo(u.w); f[7]=bf2f_hi(u.w);
}

DEV unsigned short f2b(float f){   // round-to-nearest-even bf16
  unsigned u = __float_as_uint(f);
  return (unsigned short)((u + 0x7fffu + ((u >> 16) & 1u)) >> 16);
}

DEV ushort4 pack4(float4 v){
  ushort4 r; r.x=f2b(v.x); r.y=f2b(v.y); r.z=f2b(v.z); r.w=f2b(v.w); return r;
}

DEV void fma4(float4& a, float s, const float4 w){
  a.x = fmaf(s, w.x, a.x); a.y = fmaf(s, w.y, a.y);
  a.z = fmaf(s, w.z, a.z); a.w = fmaf(s, w.w, a.w);
}

DEV float4 add4(float4 a, float4 b){
  return make_float4(a.x+b.x, a.y+b.y, a.z+b.z, a.w+b.w);
}

DEV float4 relu4(float4 a){
  return make_float4(fmaxf(a.x,0.f), fmaxf(a.y,0.f), fmaxf(a.z,0.f), fmaxf(a.w,0.f));
}

// LayerNorm over 64 cols spread across a 16-lane cg group (4 cols/lane).
DEV float4 ln4(float4 t, float4 gg, float4 bb){
  float sm = t.x+t.y+t.z+t.w;
  float sq = t.x*t.x+t.y*t.y+t.z*t.z+t.w*t.w;
  #pragma unroll
  for (int m=1;m<16;m<<=1){ sm += __shfl_xor(sm, m); sq += __shfl_xor(sq, m); }
  float mean = sm*0.015625f;
  float var  = sq*0.015625f - mean*mean;
  float rs   = rsqrtf(var + 1e-5f);
  return make_float4((t.x-mean)*rs*gg.x+bb.x, (t.y-mean)*rs*gg.y+bb.y,
                     (t.z-mean)*rs*gg.z+bb.z, (t.w-mean)*rs*gg.w+bb.w);
}

// ---------- K1: x = node_feats @ W_in  [128000,32]x[32,64] ----------
__global__ __launch_bounds__(256) void k_in(const float* __restrict__ nf,
                                            const float* __restrict__ Win,
                                            float* __restrict__ x){
  __shared__ float  s_nf[256*36];
  __shared__ float4 s_w[512];
  const int tid = threadIdx.x;
  const int node0 = blockIdx.x * 256;
  const float4* W4 = (const float4*)Win;
  s_w[tid] = W4[tid]; s_w[tid+256] = W4[tid+256];
  const float4* nf4 = (const float4*)nf;
  float4* snf4 = (float4*)s_nf;
  #pragma unroll
  for (int r=0;r<8;r++){
    int i = tid + 256*r; int n = i>>3, k4 = i&7;
    snf4[n*9 + k4] = nf4[(size_t)(node0+n)*8 + k4];
  }
  __syncthreads();
  const int ng = tid>>2, cg = tid&3;
  float4 acc[4][4];
  #pragma unroll
  for (int i=0;i<4;i++){ acc[i][0]=make_float4(0,0,0,0); acc[i][1]=make_float4(0,0,0,0);
                         acc[i][2]=make_float4(0,0,0,0); acc[i][3]=make_float4(0,0,0,0); }
  #pragma unroll 4
  for (int k=0;k<32;k++){
    float nv[4];
    #pragma unroll
    for (int i=0;i<4;i++) nv[i] = s_nf[(ng + 64*i)*36 + k];
    float4 w[4];
    #pragma unroll
    for (int j=0;j<4;j++) w[j] = s_w[k*16 + cg*4 + j];
    #pragma unroll
    for (int i=0;i<4;i++){
      #pragma unroll
      for (int j=0;j<4;j++) fma4(acc[i][j], nv[i], w[j]);
    }
  }
  float4* x4 = (float4*)x;
  #pragma unroll
  for (int i=0;i<4;i++){
    size_t nidx = (size_t)(node0 + ng + 64*i) * 16;
    #pragma unroll
    for (int j=0;j<4;j++) x4[nidx + cg*4 + j] = acc[i][j];
  }
}

// ---------- K2: qkv(bf16) = x @ [Wq|Wk|Wv]  64 nodes/block ----------
__global__ __launch_bounds__(256) void k_qkv(const float* __restrict__ x,
                                             const float* __restrict__ Wq_l,
                                             const float* __restrict__ Wk_l,
                                             const float* __restrict__ Wv_l,
                                             unsigned short* __restrict__ qkv){
  __shared__ float s_w[64*192];     // 48KB
  __shared__ float s_x[64*68];      // 17.4KB
  const int tid = threadIdx.x;
  const int node0 = blockIdx.x * 64;
  float4* sw4 = (float4*)s_w;
  const float4* q4  = (const float4*)Wq_l;
  const float4* kk4 = (const float4*)Wk_l;
  const float4* v4  = (const float4*)Wv_l;
  #pragma unroll
  for (int r=0;r<12;r++){
    int i = tid + 256*r;           // 3072 float4s
    int sec = i >> 10, rem = i & 1023;
    int k = rem >> 4, c4 = rem & 15;
    const float4* src = (sec==0) ? q4 : (sec==1) ? kk4 : v4;
    sw4[k*48 + sec*16 + c4] = src[k*16 + c4];
  }
  float4* sx4 = (float4*)s_x;
  const float4* x4 = (const float4*)x;
  #pragma unroll
  for (int r=0;r<4;r++){
    int i = tid + 256*r; int n = i>>4, k4 = i&15;   // 1024 float4s
    sx4[n*17 + k4] = x4[(size_t)(node0+n)*16 + k4];
  }
  __syncthreads();
  const int ng = tid>>4, cg = tid&15;   // 16 node-groups(4 ea) x 16 col-groups(12 ea)
  float4 acc[4][3];
  #pragma unroll
  for (int i=0;i<4;i++){ acc[i][0]=make_float4(0,0,0,0); acc[i][1]=make_float4(0,0,0,0);
                         acc[i][2]=make_float4(0,0,0,0); }
  #pragma unroll 2
  for (int k=0;k<64;k++){
    float4 w[3];
    #pragma unroll
    for (int s=0;s<3;s++) w[s] = sw4[k*48 + s*16 + cg];
    #pragma unroll
    for (int i=0;i<4;i++){
      float xv = s_x[(ng*4+i)*68 + k];
      fma4(acc[i][0], xv, w[0]); fma4(acc[i][1], xv, w[1]); fma4(acc[i][2], xv, w[2]);
    }
  }
  ushort4* out4 = (ushort4*)qkv;
  #pragma unroll
  for (int i=0;i<4;i++){
    size_t node = (size_t)(node0 + ng*4 + i);
    #pragma unroll
    for (int s=0;s<3;s++) out4[node*48 + s*16 + cg] = pack4(acc[i][s]);
  }
}

// ---------- K4: edge attention (per graph/head/half-node-range) ----------
__global__ __launch_bounds__(256) void k_edge(const unsigned short* __restrict__ qkv,
    const int* __restrict__ esrc, const int* __restrict__ edst,
    float* __restrict__ agg, float* __restrict__ denom){
  __shared__ float s_agg[500*17];
  __shared__ float s_den[500];
  const int tid = threadIdx.x;
  const int g    = blockIdx.x >> 3;
  const int hh   = (blockIdx.x >> 1) & 3;
  const int half = blockIdx.x & 1;
  const int ebase = g * EPG;
  const int nbase = g * NPG + half * 500;
  for (int i=tid;i<500*17;i+=256) s_agg[i] = 0.f;
  for (int i=tid;i<500;  i+=256) s_den[i] = 0.f;
  __syncthreads();
  for (int idx=tid; idx<EPG; idx+=256){
    int dst = edst[ebase + idx];
    unsigned rel = (unsigned)(dst - nbase);
    if (rel >= 500u) continue;
    int src = esrc[ebase + idx];
    const uint4* qp = (const uint4*)(qkv + (size_t)dst*192 + hh*16);
    const uint4* kp = (const uint4*)(qkv + (size_t)src*192 + 64 + hh*16);
    float qf[16], kf[16];
    cvt8(qp[0], qf); cvt8(qp[1], qf+8);
    cvt8(kp[0], kf); cvt8(kp[1], kf+8);
    float s = 0.f;
    #pragma unroll
    for (int d=0;d<16;d++) s = fmaf(qf[d], kf[d], s);
    float w = __expf(s * 0.25f);   // softmax shift-invariance: skip segment_max
    unsafeAtomicAdd(&s_den[rel], w);
    const uint4* vp = (const uint4*)(qkv + (size_t)src*192 + 128 + hh*16);
    float vf[16];
    cvt8(vp[0], vf); cvt8(vp[1], vf+8);
    #pragma unroll
    for (int d=0;d<16;d++) unsafeAtomicAdd(&s_agg[rel*17 + d], w * vf[d]);
  }
  __syncthreads();
  float4* agg4 = (float4*)agg;
  for (int i=tid; i<2000; i+=256){
    int nl = i>>2, d4 = i&3;
    float4 o = make_float4(s_agg[nl*17+d4*4], s_agg[nl*17+d4*4+1],
                           s_agg[nl*17+d4*4+2], s_agg[nl*17+d4*4+3]);
    agg4[(size_t)(nbase+nl)*16 + hh*4 + d4] = o;
  }
  for (int i=tid;i<500;i+=256) denom[(size_t)(nbase+i)*4 + hh] = s_den[i];
}

// ---------- K5: x = LN(x + (agg/denom) @ Wo)  64 nodes/block ----------
__global__ __launch_bounds__(256) void k_attn(const float* __restrict__ agg,
    const float* __restrict__ denom, const float* __restrict__ Wo_l,
    const float* __restrict__ lg, const float* __restrict__ lb,
    float* __restrict__ x){
  __shared__ float4 s_w[1024];     // 64x64 = 16KB
  __shared__ float  s_a[64*68];    // 17.4KB
  const int tid = threadIdx.x, node0 = blockIdx.x*64;
  const float4* w4 = (const float4*)Wo_l;
  #pragma unroll
  for (int r=0;r<4;r++) s_w[tid + 256*r] = w4[tid + 256*r];
  const float4* agg4 = (const float4*)agg;
  float4* sa4 = (float4*)s_a;
  #pragma unroll
  for (int r=0;r<4;r++){
    int i = tid + 256*r; int n = i>>4, c4 = i&15;
    float4 a = agg4[(size_t)(node0+n)*16 + c4];
    float den = denom[(size_t)(node0+n)*4 + (c4>>2)];
    float inv = 1.0f/(den + 1e-9f);
    a.x*=inv; a.y*=inv; a.z*=inv; a.w*=inv;
    sa4[n*17 + c4] = a;
  }
  __syncthreads();
  const int ng = tid>>4, cg = tid&15;
  float4 acc[4];
  #pragma unroll
  for (int i=0;i<4;i++) acc[i]=make_float4(0,0,0,0);
  #pragma unroll 2
  for (int k=0;k<64;k++){
    float4 w = s_w[k*16 + cg];
    #pragma unroll
    for (int i=0;i<4;i++){ float a = s_a[(ng*4+i)*68 + k]; fma4(acc[i], a, w); }
  }
  float4* x4 = (float4*)x;
  float4 gg = ((const float4*)lg)[cg];
  float4 bb = ((const float4*)lb)[cg];
  #pragma unroll
  for (int i=0;i<4;i++){
    size_t idx = (size_t)(node0 + ng*4 + i)*16 + cg;
    float4 t = add4(x4[idx], acc[i]);
    x4[idx] = ln4(t, gg, bb);
  }
}

// ---------- K6: h(bf16) = relu(x @ W1 + b1)  64 nodes/block ----------
__global__ __launch_bounds__(256) void k_ffn1(const float* __restrict__ x,
    const float* __restrict__ W1_l, const float* __restrict__ b1_l,
    unsigned short* __restrict__ h){
  __shared__ float4 s_w[2048];   // 64x128 = 32KB
  __shared__ float  s_x[64*68];  // 17.4KB
  const int tid = threadIdx.x, node0 = blockIdx.x*64;
  const float4* w4 = (const float4*)W1_l;
  #pragma unroll
  for (int r=0;r<8;r++) s_w[tid + 256*r] = w4[tid + 256*r];
  float4* sx4 = (float4*)s_x;
  const float4* x4 = (const float4*)x;
  #pragma unroll
  for (int r=0;r<4;r++){
    int i = tid + 256*r; int n = i>>4, k4 = i&15;
    sx4[n*17 + k4] = x4[(size_t)(node0+n)*16 + k4];
  }
  __syncthreads();
  const int ng = tid>>4, cg = tid&15;   // cols = cg*8 .. +7
  float4 a0[4], a1[4];
  #pragma unroll
  for (int i=0;i<4;i++){ a0[i]=make_float4(0,0,0,0); a1[i]=make_float4(0,0,0,0); }
  #pragma unroll 2
  for (int k=0;k<64;k++){
    float4 w0 = s_w[k*32 + cg*2], w1 = s_w[k*32 + cg*2 + 1];
    #pragma unroll
    for (int i=0;i<4;i++){
      float xv = s_x[(ng*4+i)*68 + k];
      fma4(a0[i], xv, w0); fma4(a1[i], xv, w1);
    }
  }
  float4 bb0 = ((const float4*)b1_l)[cg*2], bb1 = ((const float4*)b1_l)[cg*2+1];
  ushort4* h4 = (ushort4*)h;
  #pragma unroll
  for (int i=0;i<4;i++){
    size_t node = (size_t)(node0 + ng*4 + i);
    h4[node*32 + cg*2]     = pack4(relu4(add4(a0[i], bb0)));
    h4[node*32 + cg*2 + 1] = pack4(relu4(add4(a1[i], bb1)));
  }
}

// ---------- K7: x = LN(x + h @ W2 + b2)  64 nodes/block ----------
__global__ __launch_bounds__(256) void k_ffn2(const unsigned short* __restrict__ h,
    const float* __restrict__ W2_l, const float* __restrict__ b2_l,
    const float* __restrict__ lg, const float* __restrict__ lb,
    float* __restrict__ x){
  __shared__ float4 s_w[2048];    // 128x64 = 32KB
  __shared__ float  s_h[64*133];  // stride 133 (odd): conflict-free reads
  const int tid = threadIdx.x, node0 = blockIdx.x*64;
  const float4* w4 = (const float4*)W2_l;
  #pragma unroll
  for (int r=0;r<8;r++) s_w[tid + 256*r] = w4[tid + 256*r];
  const uint4* h8 = (const uint4*)h;
  #pragma unroll
  for (int r=0;r<4;r++){
    int i = tid + 256*r; int n = i>>4, k8 = i&15;
    uint4 u = h8[(size_t)(node0+n)*16 + k8];
    float f[8]; cvt8(u, f);
    #pragma unroll
    for (int j=0;j<8;j++) s_h[n*133 + k8*8 + j] = f[j];
  }
  __syncthreads();
  const int ng = tid>>4, cg = tid&15;
  float4 acc[4];
  #pragma unroll
  for (int i=0;i<4;i++) acc[i]=make_float4(0,0,0,0);
  #pragma unroll 2
  for (int k=0;k<128;k++){
    float4 w = s_w[k*16 + cg];
    #pragma unroll
    for (int i=0;i<4;i++){ float hv = s_h[(ng*4+i)*133 + k]; fma4(acc[i], hv, w); }
  }
  float4* x4 = (float4*)x;
  float4 bb2 = ((const float4*)b2_l)[cg];
  float4 gg  = ((const float4*)lg)[cg];
  float4 bb  = ((const float4*)lb)[cg];
  #pragma unroll
  for (int i=0;i<4;i++){
    size_t idx = (size_t)(node0 + ng*4 + i)*16 + cg;
    float4 t = add4(add4(x4[idx], acc[i]), bb2);
    x4[idx] = ln4(t, gg, bb);
  }
}

// ---------- heads: feat assembly ----------
__global__ __launch_bounds__(256) void k_feat(const float* __restrict__ x,
    const float* __restrict__ obs, const int* __restrict__ agents,
    const float* __restrict__ Wr, const float* __restrict__ br,
    float* __restrict__ feat){
  __shared__ float s_xa[64];
  const int b = blockIdx.x, tid = threadIdx.x;
  if (tid < 64) s_xa[tid] = x[(size_t)agents[b]*HD + tid];
  __syncthreads();
  if (tid < AD){
    float a = br[tid];
    #pragma unroll 8
    for (int k=0;k<HD;k++) a = fmaf(s_xa[k], Wr[k*AD + tid], a);
    feat[(size_t)b*1536 + tid] = a;
  }
  for (int i=tid;i<OBSD;i+=256) feat[(size_t)b*1536 + AD + i] = obs[(size_t)b*OBSD + i];
  if (tid < 21) feat[(size_t)b*1536 + 1515 + tid] = 0.f;
}

// ---------- heads: split-K partial GEMM  (M=128 rows) ----------
// grid: (N/COLS, 128/ROWS, KS); block ROWS*COLS threads; one partial per thread
template<int ROWS, int COLS, int CH, int KS, int N>
__global__ __launch_bounds__(ROWS*COLS) void k_gemm_part(
    const float* __restrict__ A, int lda, int K,
    const float* __restrict__ W, float* __restrict__ part){
  constexpr int BT = ROWS*COLS;
  __shared__ float s_a[ROWS*CH];
  const int tid = threadIdx.x;
  const int ct = blockIdx.x, rg = blockIdx.y, ks = blockIdx.z;
  const int chunk = (K + KS - 1) / KS;
  const int k0 = ks * chunk;
  const int len = min(K - k0, chunk);
  const int row0 = rg * ROWS;
  #pragma unroll
  for (int rr=0; rr<ROWS; rr++)
    for (int i=tid; i<len; i+=BT)
      s_a[rr*CH + i] = A[(size_t)(row0+rr)*lda + k0 + i];
  __syncthreads();
  const int r = tid / COLS, c = tid % COLS;
  const float* wp = W + (size_t)k0*N + ct*COLS + c;
  const float* ap = s_a + r*CH;
  float acc = 0.f;
  #pragma unroll 8
  for (int k=0;k<len;k++) acc = fmaf(ap[k], wp[(size_t)k*N], acc);
  part[((size_t)ks*128 + row0 + r)*N + ct*COLS + c] = acc;
}

template<int KS, int N, bool TANH>
__global__ __launch_bounds__(256) void k_reduce(const float* __restrict__ part,
    const float* __restrict__ bias, float* __restrict__ out, int MN){
  const int idx = blockIdx.x*256 + threadIdx.x;
  if (idx >= MN) return;
  float s = bias[idx & (N-1)];
  #pragma unroll
  for (int ks=0;ks<KS;ks++) s += part[(size_t)ks*MN + idx];
  out[idx] = TANH ? tanhf(s) : s;
}

// ---------- heads: logits ----------
__global__ __launch_bounds__(256) void k_logits(const float* __restrict__ f2,
    const float* __restrict__ Wlog, const float* __restrict__ blog,
    float* __restrict__ out){
  __shared__ float s_f[512];
  __shared__ float s_p[16*AD];
  const int b = blockIdx.x, tid = threadIdx.x;
  s_f[tid]     = f2[(size_t)b*512 + tid];
  s_f[tid+256] = f2[(size_t)b*512 + 256 + tid];
  __syncthreads();
  if (tid < 240){
    int c = tid % AD, kc = tid / AD;   // 16 k-chunks of 32
    float a = 0.f;
    #pragma unroll 8
    for (int j=0;j<32;j++){ int k = kc*32 + j; a = fmaf(s_f[k], Wlog[k*AD + c], a); }
    s_p[tid] = a;
  }
  __syncthreads();
  if (tid < AD){
    float a = blog[tid];
    #pragma unroll
    for (int kc=0;kc<16;kc++) a += s_p[kc*AD + tid];
    out[(size_t)b*AD + tid] = a;
  }
}

// ---------- heads: value finish (vh2 + readout) ----------
__global__ __launch_bounds__(128) void k_vfin(const float* __restrict__ vh,
    const float* __restrict__ Wv2, const float* __restrict__ bv2,
    const float* __restrict__ Wvo, const float* __restrict__ bvo,
    float* __restrict__ out){
  __shared__ float s_v[128];
  __shared__ float s_r[128];
  const int b = blockIdx.x, tid = threadIdx.x;
  s_v[tid] = vh[(size_t)b*128 + tid];
  __syncthreads();
  float a = bv2[tid];
  #pragma unroll 8
  for (int k=0;k<128;k++) a = fmaf(s_v[k], Wv2[k*128 + tid], a);
  s_r[tid] = tanhf(a) * Wvo[tid];
  __syncthreads();
  if (tid < 64){
    float v = s_r[tid] + s_r[tid+64];
    #pragma unroll
    for (int m=32;m>=1;m>>=1) v += __shfl_xor(v, m);
    if (tid==0) out[GRAPHS*AD + b] = v + bvo[0];
  }
}

// ---------- launch ----------
extern "C" void kernel_launch(void* const* d_in, const int* in_sizes, int n_in,
                              void* d_out, int out_size, void* d_ws, size_t ws_size,
                              hipStream_t stream) {
  (void)in_sizes; (void)n_in; (void)out_size; (void)ws_size;
  const float* nf     = (const float*)d_in[0];
  const float* obs    = (const float*)d_in[1];
  const int*   esrc   = (const int*)d_in[2];
  const int*   edst   = (const int*)d_in[3];
  const int*   agents = (const int*)d_in[4];
  const float* Win    = (const float*)d_in[5];
  const float* Wq     = (const float*)d_in[6];
  const float* Wk     = (const float*)d_in[7];
  const float* Wv     = (const float*)d_in[8];
  const float* Wo     = (const float*)d_in[9];
  const float* ln1g   = (const float*)d_in[10];
  const float* ln1b   = (const float*)d_in[11];
  const float* W1     = (const float*)d_in[12];
  const float* b1     = (const float*)d_in[13];
  const float* W2     = (const float*)d_in[14];
  const float* b2     = (const float*)d_in[15];
  const float* ln2g   = (const float*)d_in[16];
  const float* ln2b   = (const float*)d_in[17];
  const float* Wr     = (const float*)d_in[18];
  const float* br     = (const float*)d_in[19];
  const float* Wp1    = (const float*)d_in[20];
  const float* bp1    = (const float*)d_in[21];
  const float* Wp2    = (const float*)d_in[22];
  const float* bp2    = (const float*)d_in[23];
  const float* Wlog   = (const float*)d_in[24];
  const float* blog   = (const float*)d_in[25];
  const float* Wv1    = (const float*)d_in[26];
  const float* bv1    = (const float*)d_in[27];
  const float* Wv2    = (const float*)d_in[28];
  const float* bv2    = (const float*)d_in[29];
  const float* Wvo    = (const float*)d_in[30];
  const float* bvo    = (const float*)d_in[31];
  float* out = (float*)d_out;

  // workspace: x(f32) | agg(f32) | denom(f32) | qkv(bf16, aliased by h)
  float* x     = (float*)d_ws;
  float* agg   = x + (size_t)TOTN*HD;
  float* denom = agg + (size_t)TOTN*HD;
  unsigned short* qkv = (unsigned short*)(denom + (size_t)TOTN*4);
  unsigned short* hbuf = qkv;
  // head buffers alias agg (agg dead after last k_attn)
  float* feat = agg;                    // 128*1536
  float* f1   = feat + 128*1536;        // 128*512
  float* f2   = f1 + 128*512;           // 128*512
  float* vh   = f2 + 128*512;           // 128*128
  float* part = vh + 128*128;           // up to 4*128*512

  k_in<<<TOTN/256, 256, 0, stream>>>(nf, Win, x);
  for (int l=0; l<4; l++){
    k_qkv <<<TOTN/64, 256, 0, stream>>>(x, Wq + l*4096, Wk + l*4096, Wv + l*4096, qkv);
    k_edge<<<GRAPHS*8, 256, 0, stream>>>(qkv, esrc, edst, agg, denom);
    k_attn<<<TOTN/64, 256, 0, stream>>>(agg, denom, Wo + l*4096,
                                        ln1g + l*64, ln1b + l*64, x);
    k_ffn1<<<TOTN/64, 256, 0, stream>>>(x, W1 + l*8192, b1 + l*128, hbuf);
    k_ffn2<<<TOTN/64, 256, 0, stream>>>(hbuf, W2 + l*8192, b2 + l*64,
                                        ln2g + l*64, ln2b + l*64, x);
  }
  // policy head
  k_feat<<<GRAPHS, 256, 0, stream>>>(x, obs, agents, Wr, br, feat);
  k_gemm_part<2,256,384,4,512><<<dim3(2,64,4), 512, 0, stream>>>(feat, 1536, 1515, Wp1, part);
  k_reduce<4,512,true><<<256, 256, 0, stream>>>(part, bp1, f1, 128*512);
  k_gemm_part<2,256,256,2,512><<<dim3(2,64,2), 512, 0, stream>>>(f1, 512, 512, Wp2, part);
  k_reduce<2,512,true><<<256, 256, 0, stream>>>(part, bp2, f2, 128*512);
  k_logits<<<GRAPHS, 256, 0, stream>>>(f2, Wlog, blog, out);
  // value head
  k_gemm_part<4,128,192,8,128><<<dim3(1,32,8), 512, 0, stream>>>(obs, 1500, 1500, Wv1, part);
  k_reduce<8,128,true><<<64, 256, 0, stream>>>(part, bv1, vh, 128*128);
  k_vfin<<<GRAPHS, 128, 0, stream>>>(vh, Wv2, bv2, Wvo, bvo, out);
}

// Round 3
// 977.084 us; speedup vs baseline: 2.0118x; 1.5426x over previous
//
#include <hip/hip_runtime.h>
#include <hip/hip_bf16.h>
#include <cstdint>
#include <cstddef>

#define DEV static __device__ __forceinline__

constexpr int GRAPHS = 128;
constexpr int NPG    = 1000;   // nodes per graph
constexpr int EPG    = 4000;   // edges per graph
constexpr int TOTN   = GRAPHS * NPG;  // 128000
constexpr int TOTE   = GRAPHS * EPG;  // 512000
constexpr int HD     = 64;
constexpr int OBSD   = 1500;
constexpr int AD     = 15;

// ---------- helpers ----------
DEV float bf2f_lo(unsigned u){ return __uint_as_float(u << 16); }
DEV float bf2f_hi(unsigned u){ return __uint_as_float(u & 0xffff0000u); }

DEV void cvt8(uint4 u, float* f){
  f[0]=bf2f_lo(u.x); f[1]=bf2f_hi(u.x);
  f[2]=bf2f_lo(u.y); f[3]=bf2f_hi(u.y);
  f[4]=bf2f_lo(u.z); f[5]=bf2f_hi(u.z);
  f[6]=bf2f_lo(u.w); f[7]=bf2f_hi(u.w);
}

DEV unsigned short f2b(float f){   // round-to-nearest-even bf16
  unsigned u = __float_as_uint(f);
  return (unsigned short)((u + 0x7fffu + ((u >> 16) & 1u)) >> 16);
}

DEV ushort4 pack4(float4 v){
  ushort4 r; r.x=f2b(v.x); r.y=f2b(v.y); r.z=f2b(v.z); r.w=f2b(v.w); return r;
}

DEV void fma4(float4& a, float s, const float4 w){
  a.x = fmaf(s, w.x, a.x); a.y = fmaf(s, w.y, a.y);
  a.z = fmaf(s, w.z, a.z); a.w = fmaf(s, w.w, a.w);
}

DEV float4 add4(float4 a, float4 b){
  return make_float4(a.x+b.x, a.y+b.y, a.z+b.z, a.w+b.w);
}

DEV float4 relu4(float4 a){
  return make_float4(fmaxf(a.x,0.f), fmaxf(a.y,0.f), fmaxf(a.z,0.f), fmaxf(a.w,0.f));
}

// LayerNorm over 64 cols spread across a 16-lane cg group (4 cols/lane).
DEV float4 ln4(float4 t, float4 gg, float4 bb){
  float sm = t.x+t.y+t.z+t.w;
  float sq = t.x*t.x+t.y*t.y+t.z*t.z+t.w*t.w;
  #pragma unroll
  for (int m=1;m<16;m<<=1){ sm += __shfl_xor(sm, m); sq += __shfl_xor(sq, m); }
  float mean = sm*0.015625f;
  float var  = sq*0.015625f - mean*mean;
  float rs   = rsqrtf(var + 1e-5f);
  return make_float4((t.x-mean)*rs*gg.x+bb.x, (t.y-mean)*rs*gg.y+bb.y,
                     (t.z-mean)*rs*gg.z+bb.z, (t.w-mean)*rs*gg.w+bb.w);
}

// ---------- CSR build (once per call; reused by all 4 layers) ----------
__global__ __launch_bounds__(256) void k_zero(int* __restrict__ cnt){
  cnt[blockIdx.x*256 + threadIdx.x] = 0;
}

__global__ __launch_bounds__(256) void k_hist(const int* __restrict__ edst,
                                              int* __restrict__ cnt){
  int e = blockIdx.x*256 + threadIdx.x;
  atomicAdd(&cnt[edst[e]], 1);
}

// per-graph exclusive scan of 1000 counts -> absolute row starts (+ cursor copy)
__global__ __launch_bounds__(1024) void k_scan(const int* __restrict__ cnt,
    int* __restrict__ rstart, int* __restrict__ cursor){
  __shared__ int s[1024];
  const int g = blockIdx.x, tid = threadIdx.x;
  int v = (tid < NPG) ? cnt[g*NPG + tid] : 0;
  s[tid] = v;
  __syncthreads();
  #pragma unroll
  for (int off=1; off<1024; off<<=1){
    int t = (tid >= off) ? s[tid-off] : 0;
    __syncthreads();
    s[tid] += t;
    __syncthreads();
  }
  if (tid < NPG){
    int r = g*EPG + (s[tid] - v);
    rstart[g*NPG+tid] = r;
    cursor[g*NPG+tid] = r;
  }
}

__global__ __launch_bounds__(256) void k_scatter(const int* __restrict__ esrc,
    const int* __restrict__ edst, int* __restrict__ cursor,
    int* __restrict__ esorted){
  int e = blockIdx.x*256 + threadIdx.x;
  int pos = atomicAdd(&cursor[edst[e]], 1);
  esorted[pos] = esrc[e];
}

// ---------- K1: x = node_feats @ W_in  [128000,32]x[32,64] ----------
__global__ __launch_bounds__(256) void k_in(const float* __restrict__ nf,
                                            const float* __restrict__ Win,
                                            float* __restrict__ x){
  __shared__ float  s_nf[256*36];
  __shared__ float4 s_w[512];
  const int tid = threadIdx.x;
  const int node0 = blockIdx.x * 256;
  const float4* W4 = (const float4*)Win;
  s_w[tid] = W4[tid]; s_w[tid+256] = W4[tid+256];
  const float4* nf4 = (const float4*)nf;
  float4* snf4 = (float4*)s_nf;
  #pragma unroll
  for (int r=0;r<8;r++){
    int i = tid + 256*r; int n = i>>3, k4 = i&7;
    snf4[n*9 + k4] = nf4[(size_t)(node0+n)*8 + k4];
  }
  __syncthreads();
  const int ng = tid>>2, cg = tid&3;
  float4 acc[4][4];
  #pragma unroll
  for (int i=0;i<4;i++){ acc[i][0]=make_float4(0,0,0,0); acc[i][1]=make_float4(0,0,0,0);
                         acc[i][2]=make_float4(0,0,0,0); acc[i][3]=make_float4(0,0,0,0); }
  #pragma unroll 4
  for (int k=0;k<32;k++){
    float nv[4];
    #pragma unroll
    for (int i=0;i<4;i++) nv[i] = s_nf[(ng + 64*i)*36 + k];
    float4 w[4];
    #pragma unroll
    for (int j=0;j<4;j++) w[j] = s_w[k*16 + cg*4 + j];
    #pragma unroll
    for (int i=0;i<4;i++){
      #pragma unroll
      for (int j=0;j<4;j++) fma4(acc[i][j], nv[i], w[j]);
    }
  }
  float4* x4 = (float4*)x;
  #pragma unroll
  for (int i=0;i<4;i++){
    size_t nidx = (size_t)(node0 + ng + 64*i) * 16;
    #pragma unroll
    for (int j=0;j<4;j++) x4[nidx + cg*4 + j] = acc[i][j];
  }
}

// ---------- K2: qkv(bf16) = x @ [Wq|Wk|Wv]  64 nodes/block ----------
__global__ __launch_bounds__(256) void k_qkv(const float* __restrict__ x,
                                             const float* __restrict__ Wq_l,
                                             const float* __restrict__ Wk_l,
                                             const float* __restrict__ Wv_l,
                                             unsigned short* __restrict__ qkv){
  __shared__ float s_w[64*192];
  __shared__ float s_x[64*68];
  const int tid = threadIdx.x;
  const int node0 = blockIdx.x * 64;
  float4* sw4 = (float4*)s_w;
  const float4* q4  = (const float4*)Wq_l;
  const float4* kk4 = (const float4*)Wk_l;
  const float4* v4  = (const float4*)Wv_l;
  #pragma unroll
  for (int r=0;r<12;r++){
    int i = tid + 256*r;
    int sec = i >> 10, rem = i & 1023;
    int k = rem >> 4, c4 = rem & 15;
    const float4* src = (sec==0) ? q4 : (sec==1) ? kk4 : v4;
    sw4[k*48 + sec*16 + c4] = src[k*16 + c4];
  }
  float4* sx4 = (float4*)s_x;
  const float4* x4 = (const float4*)x;
  #pragma unroll
  for (int r=0;r<4;r++){
    int i = tid + 256*r; int n = i>>4, k4 = i&15;
    sx4[n*17 + k4] = x4[(size_t)(node0+n)*16 + k4];
  }
  __syncthreads();
  const int ng = tid>>4, cg = tid&15;
  float4 acc[4][3];
  #pragma unroll
  for (int i=0;i<4;i++){ acc[i][0]=make_float4(0,0,0,0); acc[i][1]=make_float4(0,0,0,0);
                         acc[i][2]=make_float4(0,0,0,0); }
  #pragma unroll 2
  for (int k=0;k<64;k++){
    float4 w[3];
    #pragma unroll
    for (int s=0;s<3;s++) w[s] = sw4[k*48 + s*16 + cg];
    #pragma unroll
    for (int i=0;i<4;i++){
      float xv = s_x[(ng*4+i)*68 + k];
      fma4(acc[i][0], xv, w[0]); fma4(acc[i][1], xv, w[1]); fma4(acc[i][2], xv, w[2]);
    }
  }
  ushort4* out4 = (ushort4*)qkv;
  #pragma unroll
  for (int i=0;i<4;i++){
    size_t node = (size_t)(node0 + ng*4 + i);
    #pragma unroll
    for (int s=0;s<3;s++) out4[node*48 + s*16 + cg] = pack4(acc[i][s]);
  }
}

// ---------- K4: edge attention via CSR gather. 16 lanes/node, 4 nodes/wave ----
// lane l: node_sub = l>>4, dims (l&15)*4..+3, head = (l&15)>>2.
// Writes NORMALIZED attention input (agg/denom) directly.
__global__ __launch_bounds__(256) void k_edge2(const unsigned short* __restrict__ qkv,
    const int* __restrict__ rstart, const int* __restrict__ cnt,
    const int* __restrict__ esorted, float* __restrict__ attn_in){
  const int tid = threadIdx.x;
  const int lane = tid & 63;
  const int sub  = lane >> 4;
  const int dg   = lane & 15;
  const int wave = tid >> 6;
  const int node = blockIdx.x*16 + wave*4 + sub;
  const ushort4* row = (const ushort4*)(qkv + (size_t)node*192);
  ushort4 qu = row[dg];
  float q0=bf2f_lo(qu.x), q1=bf2f_lo(qu.y), q2=bf2f_lo(qu.z), q3=bf2f_lo(qu.w);
  // note ushort4 fields are 16-bit; widen via <<16
  q0 = __uint_as_float((unsigned)qu.x << 16);
  q1 = __uint_as_float((unsigned)qu.y << 16);
  q2 = __uint_as_float((unsigned)qu.z << 16);
  q3 = __uint_as_float((unsigned)qu.w << 16);
  const int rs = rstart[node];
  const int n  = cnt[node];
  float a0=0.f, a1=0.f, a2=0.f, a3=0.f, den=0.f;
  for (int i=0;i<n;i++){
    int src = esorted[rs + i];
    const ushort4* kr = (const ushort4*)(qkv + (size_t)src*192 + 64);
    const ushort4* vr = (const ushort4*)(qkv + (size_t)src*192 + 128);
    ushort4 ku = kr[dg];
    ushort4 vu = vr[dg];
    float k0 = __uint_as_float((unsigned)ku.x << 16);
    float k1 = __uint_as_float((unsigned)ku.y << 16);
    float k2 = __uint_as_float((unsigned)ku.z << 16);
    float k3 = __uint_as_float((unsigned)ku.w << 16);
    float p = q0*k0 + q1*k1 + q2*k2 + q3*k3;
    p += __shfl_xor(p, 1);
    p += __shfl_xor(p, 2);          // sum over the 4 lanes of this head
    float w = __expf(p * 0.25f);    // softmax shift-invariant; skip segment_max
    den += w;
    a0 = fmaf(w, __uint_as_float((unsigned)vu.x << 16), a0);
    a1 = fmaf(w, __uint_as_float((unsigned)vu.y << 16), a1);
    a2 = fmaf(w, __uint_as_float((unsigned)vu.z << 16), a2);
    a3 = fmaf(w, __uint_as_float((unsigned)vu.w << 16), a3);
  }
  float inv = 1.0f/(den + 1e-9f);
  ((float4*)attn_in)[(size_t)node*16 + dg] = make_float4(a0*inv, a1*inv, a2*inv, a3*inv);
}

// ---------- K5: x = LN(x + attn_in @ Wo)  64 nodes/block ----------
__global__ __launch_bounds__(256) void k_attn(const float* __restrict__ attn_in,
    const float* __restrict__ Wo_l,
    const float* __restrict__ lg, const float* __restrict__ lb,
    float* __restrict__ x){
  __shared__ float4 s_w[1024];
  __shared__ float  s_a[64*68];
  const int tid = threadIdx.x, node0 = blockIdx.x*64;
  const float4* w4 = (const float4*)Wo_l;
  #pragma unroll
  for (int r=0;r<4;r++) s_w[tid + 256*r] = w4[tid + 256*r];
  const float4* agg4 = (const float4*)attn_in;
  float4* sa4 = (float4*)s_a;
  #pragma unroll
  for (int r=0;r<4;r++){
    int i = tid + 256*r; int n = i>>4, c4 = i&15;
    sa4[n*17 + c4] = agg4[(size_t)(node0+n)*16 + c4];
  }
  __syncthreads();
  const int ng = tid>>4, cg = tid&15;
  float4 acc[4];
  #pragma unroll
  for (int i=0;i<4;i++) acc[i]=make_float4(0,0,0,0);
  #pragma unroll 2
  for (int k=0;k<64;k++){
    float4 w = s_w[k*16 + cg];
    #pragma unroll
    for (int i=0;i<4;i++){ float a = s_a[(ng*4+i)*68 + k]; fma4(acc[i], a, w); }
  }
  float4* x4 = (float4*)x;
  float4 gg = ((const float4*)lg)[cg];
  float4 bb = ((const float4*)lb)[cg];
  #pragma unroll
  for (int i=0;i<4;i++){
    size_t idx = (size_t)(node0 + ng*4 + i)*16 + cg;
    float4 t = add4(x4[idx], acc[i]);
    x4[idx] = ln4(t, gg, bb);
  }
}

// ---------- K6: h(bf16) = relu(x @ W1 + b1)  64 nodes/block ----------
__global__ __launch_bounds__(256) void k_ffn1(const float* __restrict__ x,
    const float* __restrict__ W1_l, const float* __restrict__ b1_l,
    unsigned short* __restrict__ h){
  __shared__ float4 s_w[2048];
  __shared__ float  s_x[64*68];
  const int tid = threadIdx.x, node0 = blockIdx.x*64;
  const float4* w4 = (const float4*)W1_l;
  #pragma unroll
  for (int r=0;r<8;r++) s_w[tid + 256*r] = w4[tid + 256*r];
  float4* sx4 = (float4*)s_x;
  const float4* x4 = (const float4*)x;
  #pragma unroll
  for (int r=0;r<4;r++){
    int i = tid + 256*r; int n = i>>4, k4 = i&15;
    sx4[n*17 + k4] = x4[(size_t)(node0+n)*16 + k4];
  }
  __syncthreads();
  const int ng = tid>>4, cg = tid&15;
  float4 a0[4], a1[4];
  #pragma unroll
  for (int i=0;i<4;i++){ a0[i]=make_float4(0,0,0,0); a1[i]=make_float4(0,0,0,0); }
  #pragma unroll 2
  for (int k=0;k<64;k++){
    float4 w0 = s_w[k*32 + cg*2], w1 = s_w[k*32 + cg*2 + 1];
    #pragma unroll
    for (int i=0;i<4;i++){
      float xv = s_x[(ng*4+i)*68 + k];
      fma4(a0[i], xv, w0); fma4(a1[i], xv, w1);
    }
  }
  float4 bb0 = ((const float4*)b1_l)[cg*2], bb1 = ((const float4*)b1_l)[cg*2+1];
  ushort4* h4 = (ushort4*)h;
  #pragma unroll
  for (int i=0;i<4;i++){
    size_t node = (size_t)(node0 + ng*4 + i);
    h4[node*32 + cg*2]     = pack4(relu4(add4(a0[i], bb0)));
    h4[node*32 + cg*2 + 1] = pack4(relu4(add4(a1[i], bb1)));
  }
}

// ---------- K7: x = LN(x + h @ W2 + b2)  64 nodes/block ----------
__global__ __launch_bounds__(256) void k_ffn2(const unsigned short* __restrict__ h,
    const float* __restrict__ W2_l, const float* __restrict__ b2_l,
    const float* __restrict__ lg, const float* __restrict__ lb,
    float* __restrict__ x){
  __shared__ float4 s_w[2048];
  __shared__ float  s_h[64*133];  // odd stride: conflict-free scalar reads
  const int tid = threadIdx.x, node0 = blockIdx.x*64;
  const float4* w4 = (const float4*)W2_l;
  #pragma unroll
  for (int r=0;r<8;r++) s_w[tid + 256*r] = w4[tid + 256*r];
  const uint4* h8 = (const uint4*)h;
  #pragma unroll
  for (int r=0;r<4;r++){
    int i = tid + 256*r; int n = i>>4, k8 = i&15;
    uint4 u = h8[(size_t)(node0+n)*16 + k8];
    float f[8]; cvt8(u, f);
    #pragma unroll
    for (int j=0;j<8;j++) s_h[n*133 + k8*8 + j] = f[j];
  }
  __syncthreads();
  const int ng = tid>>4, cg = tid&15;
  float4 acc[4];
  #pragma unroll
  for (int i=0;i<4;i++) acc[i]=make_float4(0,0,0,0);
  #pragma unroll 2
  for (int k=0;k<128;k++){
    float4 w = s_w[k*16 + cg];
    #pragma unroll
    for (int i=0;i<4;i++){ float hv = s_h[(ng*4+i)*133 + k]; fma4(acc[i], hv, w); }
  }
  float4* x4 = (float4*)x;
  float4 bb2 = ((const float4*)b2_l)[cg];
  float4 gg  = ((const float4*)lg)[cg];
  float4 bb  = ((const float4*)lb)[cg];
  #pragma unroll
  for (int i=0;i<4;i++){
    size_t idx = (size_t)(node0 + ng*4 + i)*16 + cg;
    float4 t = add4(add4(x4[idx], acc[i]), bb2);
    x4[idx] = ln4(t, gg, bb);
  }
}

// ---------- heads: feat assembly ----------
__global__ __launch_bounds__(256) void k_feat(const float* __restrict__ x,
    const float* __restrict__ obs, const int* __restrict__ agents,
    const float* __restrict__ Wr, const float* __restrict__ br,
    float* __restrict__ feat){
  __shared__ float s_xa[64];
  const int b = blockIdx.x, tid = threadIdx.x;
  if (tid < 64) s_xa[tid] = x[(size_t)agents[b]*HD + tid];
  __syncthreads();
  if (tid < AD){
    float a = br[tid];
    #pragma unroll 8
    for (int k=0;k<HD;k++) a = fmaf(s_xa[k], Wr[k*AD + tid], a);
    feat[(size_t)b*1536 + tid] = a;
  }
  for (int i=tid;i<OBSD;i+=256) feat[(size_t)b*1536 + AD + i] = obs[(size_t)b*OBSD + i];
  if (tid < 21) feat[(size_t)b*1536 + 1515 + tid] = 0.f;
}

// ---------- heads: split-K partial GEMM ----------
template<int ROWS, int COLS, int CH, int KS, int N>
__global__ __launch_bounds__(ROWS*COLS) void k_gemm_part(
    const float* __restrict__ A, int lda, int K,
    const float* __restrict__ W, float* __restrict__ part){
  constexpr int BT = ROWS*COLS;
  __shared__ float s_a[ROWS*CH];
  const int tid = threadIdx.x;
  const int ct = blockIdx.x, rg = blockIdx.y, ks = blockIdx.z;
  const int chunk = (K + KS - 1) / KS;
  const int k0 = ks * chunk;
  const int len = min(K - k0, chunk);
  const int row0 = rg * ROWS;
  #pragma unroll
  for (int rr=0; rr<ROWS; rr++)
    for (int i=tid; i<len; i+=BT)
      s_a[rr*CH + i] = A[(size_t)(row0+rr)*lda + k0 + i];
  __syncthreads();
  const int r = tid / COLS, c = tid % COLS;
  const float* wp = W + (size_t)k0*N + ct*COLS + c;
  const float* ap = s_a + r*CH;
  float acc = 0.f;
  #pragma unroll 8
  for (int k=0;k<len;k++) acc = fmaf(ap[k], wp[(size_t)k*N], acc);
  part[((size_t)ks*128 + row0 + r)*N + ct*COLS + c] = acc;
}

template<int KS, int N, bool TANH>
__global__ __launch_bounds__(256) void k_reduce(const float* __restrict__ part,
    const float* __restrict__ bias, float* __restrict__ out, int MN){
  const int idx = blockIdx.x*256 + threadIdx.x;
  if (idx >= MN) return;
  float s = bias[idx & (N-1)];
  #pragma unroll
  for (int ks=0;ks<KS;ks++) s += part[(size_t)ks*MN + idx];
  out[idx] = TANH ? tanhf(s) : s;
}

// ---------- heads: logits ----------
__global__ __launch_bounds__(256) void k_logits(const float* __restrict__ f2,
    const float* __restrict__ Wlog, const float* __restrict__ blog,
    float* __restrict__ out){
  __shared__ float s_f[512];
  __shared__ float s_p[16*AD];
  const int b = blockIdx.x, tid = threadIdx.x;
  s_f[tid]     = f2[(size_t)b*512 + tid];
  s_f[tid+256] = f2[(size_t)b*512 + 256 + tid];
  __syncthreads();
  if (tid < 240){
    int c = tid % AD, kc = tid / AD;
    float a = 0.f;
    #pragma unroll 8
    for (int j=0;j<32;j++){ int k = kc*32 + j; a = fmaf(s_f[k], Wlog[k*AD + c], a); }
    s_p[tid] = a;
  }
  __syncthreads();
  if (tid < AD){
    float a = blog[tid];
    #pragma unroll
    for (int kc=0;kc<16;kc++) a += s_p[kc*AD + tid];
    out[(size_t)b*AD + tid] = a;
  }
}

// ---------- heads: value finish ----------
__global__ __launch_bounds__(128) void k_vfin(const float* __restrict__ vh,
    const float* __restrict__ Wv2, const float* __restrict__ bv2,
    const float* __restrict__ Wvo, const float* __restrict__ bvo,
    float* __restrict__ out){
  __shared__ float s_v[128];
  __shared__ float s_r[128];
  const int b = blockIdx.x, tid = threadIdx.x;
  s_v[tid] = vh[(size_t)b*128 + tid];
  __syncthreads();
  float a = bv2[tid];
  #pragma unroll 8
  for (int k=0;k<128;k++) a = fmaf(s_v[k], Wv2[k*128 + tid], a);
  s_r[tid] = tanhf(a) * Wvo[tid];
  __syncthreads();
  if (tid < 64){
    float v = s_r[tid] + s_r[tid+64];
    #pragma unroll
    for (int m=32;m>=1;m>>=1) v += __shfl_xor(v, m);
    if (tid==0) out[GRAPHS*AD + b] = v + bvo[0];
  }
}

// ---------- launch ----------
extern "C" void kernel_launch(void* const* d_in, const int* in_sizes, int n_in,
                              void* d_out, int out_size, void* d_ws, size_t ws_size,
                              hipStream_t stream) {
  (void)in_sizes; (void)n_in; (void)out_size; (void)ws_size;
  const float* nf     = (const float*)d_in[0];
  const float* obs    = (const float*)d_in[1];
  const int*   esrc   = (const int*)d_in[2];
  const int*   edst   = (const int*)d_in[3];
  const int*   agents = (const int*)d_in[4];
  const float* Win    = (const float*)d_in[5];
  const float* Wq     = (const float*)d_in[6];
  const float* Wk     = (const float*)d_in[7];
  const float* Wv     = (const float*)d_in[8];
  const float* Wo     = (const float*)d_in[9];
  const float* ln1g   = (const float*)d_in[10];
  const float* ln1b   = (const float*)d_in[11];
  const float* W1     = (const float*)d_in[12];
  const float* b1     = (const float*)d_in[13];
  const float* W2     = (const float*)d_in[14];
  const float* b2     = (const float*)d_in[15];
  const float* ln2g   = (const float*)d_in[16];
  const float* ln2b   = (const float*)d_in[17];
  const float* Wr     = (const float*)d_in[18];
  const float* br     = (const float*)d_in[19];
  const float* Wp1    = (const float*)d_in[20];
  const float* bp1    = (const float*)d_in[21];
  const float* Wp2    = (const float*)d_in[22];
  const float* bp2    = (const float*)d_in[23];
  const float* Wlog   = (const float*)d_in[24];
  const float* blog   = (const float*)d_in[25];
  const float* Wv1    = (const float*)d_in[26];
  const float* bv1    = (const float*)d_in[27];
  const float* Wv2    = (const float*)d_in[28];
  const float* bv2    = (const float*)d_in[29];
  const float* Wvo    = (const float*)d_in[30];
  const float* bvo    = (const float*)d_in[31];
  float* out = (float*)d_out;

  // workspace layout
  float* x       = (float*)d_ws;                       // TOTN*64 f32
  float* attn_in = x + (size_t)TOTN*HD;                // TOTN*64 f32
  unsigned short* qkv = (unsigned short*)(attn_in + (size_t)TOTN*HD); // TOTN*192 bf16
  unsigned short* hbuf = qkv;                          // ffn intermediate aliases qkv
  int* cnt     = (int*)(qkv + (size_t)TOTN*192);       // TOTN
  int* rstart  = cnt + TOTN;                           // TOTN
  int* cursor  = rstart + TOTN;                        // TOTN
  int* esorted = cursor + TOTN;                        // TOTE
  // head buffers alias attn_in (dead after last k_attn)
  float* feat = attn_in;
  float* f1   = feat + 128*1536;
  float* f2   = f1 + 128*512;
  float* vh   = f2 + 128*512;
  float* part = vh + 128*128;

  // CSR build (edge topology is layer-invariant)
  k_zero   <<<TOTN/256, 256, 0, stream>>>(cnt);
  k_hist   <<<TOTE/256, 256, 0, stream>>>(edst, cnt);
  k_scan   <<<GRAPHS, 1024, 0, stream>>>(cnt, rstart, cursor);
  k_scatter<<<TOTE/256, 256, 0, stream>>>(esrc, edst, cursor, esorted);

  k_in<<<TOTN/256, 256, 0, stream>>>(nf, Win, x);
  for (int l=0; l<4; l++){
    k_qkv <<<TOTN/64, 256, 0, stream>>>(x, Wq + l*4096, Wk + l*4096, Wv + l*4096, qkv);
    k_edge2<<<TOTN/16, 256, 0, stream>>>(qkv, rstart, cnt, esorted, attn_in);
    k_attn<<<TOTN/64, 256, 0, stream>>>(attn_in, Wo + l*4096,
                                        ln1g + l*64, ln1b + l*64, x);
    k_ffn1<<<TOTN/64, 256, 0, stream>>>(x, W1 + l*8192, b1 + l*128, hbuf);
    k_ffn2<<<TOTN/64, 256, 0, stream>>>(hbuf, W2 + l*8192, b2 + l*64,
                                        ln2g + l*64, ln2b + l*64, x);
  }
  // policy head
  k_feat<<<GRAPHS, 256, 0, stream>>>(x, obs, agents, Wr, br, feat);
  k_gemm_part<2,256,384,4,512><<<dim3(2,64,4), 512, 0, stream>>>(feat, 1536, 1515, Wp1, part);
  k_reduce<4,512,true><<<256, 256, 0, stream>>>(part, bp1, f1, 128*512);
  k_gemm_part<2,256,256,2,512><<<dim3(2,64,2), 512, 0, stream>>>(f1, 512, 512, Wp2, part);
  k_reduce<2,512,true><<<256, 256, 0, stream>>>(part, bp2, f2, 128*512);
  k_logits<<<GRAPHS, 256, 0, stream>>>(f2, Wlog, blog, out);
  // value head
  k_gemm_part<4,128,192,8,128><<<dim3(1,32,8), 512, 0, stream>>>(obs, 1500, 1500, Wv1, part);
  k_reduce<8,128,true><<<64, 256, 0, stream>>>(part, bv1, vh, 128*128);
  k_vfin<<<GRAPHS, 128, 0, stream>>>(vh, Wv2, bv2, Wvo, bvo, out);
}

// Round 4
// 682.029 us; speedup vs baseline: 2.8822x; 1.4326x over previous
//
#include <hip/hip_runtime.h>
#include <hip/hip_bf16.h>
#include <cstdint>
#include <cstddef>

#define DEV static __device__ __forceinline__

constexpr int GRAPHS = 128;
constexpr int NPG    = 1000;   // nodes per graph
constexpr int EPG    = 4000;   // edges per graph
constexpr int TOTN   = GRAPHS * NPG;  // 128000
constexpr int TOTE   = GRAPHS * EPG;  // 512000
constexpr int HD     = 64;
constexpr int OBSD   = 1500;
constexpr int AD     = 15;

typedef __attribute__((ext_vector_type(8))) short bf16x8;
typedef __attribute__((ext_vector_type(4))) float f32x4;

// ---------- helpers ----------
DEV unsigned short f2b(float f){   // round-to-nearest-even bf16
  unsigned u = __float_as_uint(f);
  return (unsigned short)((u + 0x7fffu + ((u >> 16) & 1u)) >> 16);
}
DEV float b2f(unsigned short s){ return __uint_as_float((unsigned)s << 16); }

DEV void fma4(float4& a, float s, const float4 w){
  a.x = fmaf(s, w.x, a.x); a.y = fmaf(s, w.y, a.y);
  a.z = fmaf(s, w.z, a.z); a.w = fmaf(s, w.w, a.w);
}

// ---------- weight prep: pack all layer weights to bf16 W^T ----------
// per layer (stride 32768 bf16): qkvT[192][64] | woT[64][64] | w1T[128][64] | w2T[64][128]
__global__ __launch_bounds__(256) void k_wprep(const float* __restrict__ Wq,
    const float* __restrict__ Wk, const float* __restrict__ Wv,
    const float* __restrict__ Wo, const float* __restrict__ W1,
    const float* __restrict__ W2, unsigned short* __restrict__ wpack){
  int e = blockIdx.x*256 + threadIdx.x;
  int l = e >> 15;
  int r = e & 32767;
  float val;
  if (r < 12288){
    int c = r >> 6, k = r & 63;
    val = (c < 64)  ? Wq[l*4096 + k*64 + c]
        : (c < 128) ? Wk[l*4096 + k*64 + (c-64)]
                    : Wv[l*4096 + k*64 + (c-128)];
  } else if (r < 16384){
    int i = r - 12288; int c = i >> 6, k = i & 63;
    val = Wo[l*4096 + k*64 + c];
  } else if (r < 24576){
    int i = r - 16384; int c = i >> 6, k = i & 63;
    val = W1[l*8192 + k*128 + c];
  } else {
    int i = r - 24576; int c = i >> 7, k = i & 127;
    val = W2[l*8192 + k*64 + c];
  }
  wpack[e] = f2b(val);
}

// ---------- CSR build (once per call; reused by all 4 layers) ----------
__global__ __launch_bounds__(256) void k_zero(int* __restrict__ cnt){
  cnt[blockIdx.x*256 + threadIdx.x] = 0;
}

__global__ __launch_bounds__(256) void k_hist(const int* __restrict__ edst,
                                              int* __restrict__ cnt){
  int e = blockIdx.x*256 + threadIdx.x;
  atomicAdd(&cnt[edst[e]], 1);
}

__global__ __launch_bounds__(1024) void k_scan(const int* __restrict__ cnt,
    int* __restrict__ rstart, int* __restrict__ cursor){
  __shared__ int s[1024];
  const int g = blockIdx.x, tid = threadIdx.x;
  int v = (tid < NPG) ? cnt[g*NPG + tid] : 0;
  s[tid] = v;
  __syncthreads();
  #pragma unroll
  for (int off=1; off<1024; off<<=1){
    int t = (tid >= off) ? s[tid-off] : 0;
    __syncthreads();
    s[tid] += t;
    __syncthreads();
  }
  if (tid < NPG){
    int r = g*EPG + (s[tid] - v);
    rstart[g*NPG+tid] = r;
    cursor[g*NPG+tid] = r;
  }
}

__global__ __launch_bounds__(256) void k_scatter(const int* __restrict__ esrc,
    const int* __restrict__ edst, int* __restrict__ cursor,
    int* __restrict__ esorted){
  int e = blockIdx.x*256 + threadIdx.x;
  int pos = atomicAdd(&cursor[edst[e]], 1);
  esorted[pos] = esrc[e];
}

// ---------- K1: x = node_feats @ W_in  [128000,32]x[32,64] (f32 VALU) ----------
__global__ __launch_bounds__(256) void k_in(const float* __restrict__ nf,
                                            const float* __restrict__ Win,
                                            float* __restrict__ x){
  __shared__ float  s_nf[256*36];
  __shared__ float4 s_w[512];
  const int tid = threadIdx.x;
  const int node0 = blockIdx.x * 256;
  const float4* W4 = (const float4*)Win;
  s_w[tid] = W4[tid]; s_w[tid+256] = W4[tid+256];
  const float4* nf4 = (const float4*)nf;
  float4* snf4 = (float4*)s_nf;
  #pragma unroll
  for (int r=0;r<8;r++){
    int i = tid + 256*r; int n = i>>3, k4 = i&7;
    snf4[n*9 + k4] = nf4[(size_t)(node0+n)*8 + k4];
  }
  __syncthreads();
  const int ng = tid>>2, cg = tid&3;
  float4 acc[4][4];
  #pragma unroll
  for (int i=0;i<4;i++){ acc[i][0]=make_float4(0,0,0,0); acc[i][1]=make_float4(0,0,0,0);
                         acc[i][2]=make_float4(0,0,0,0); acc[i][3]=make_float4(0,0,0,0); }
  #pragma unroll 4
  for (int k=0;k<32;k++){
    float nv[4];
    #pragma unroll
    for (int i=0;i<4;i++) nv[i] = s_nf[(ng + 64*i)*36 + k];
    float4 w[4];
    #pragma unroll
    for (int j=0;j<4;j++) w[j] = s_w[k*16 + cg*4 + j];
    #pragma unroll
    for (int i=0;i<4;i++){
      #pragma unroll
      for (int j=0;j<4;j++) fma4(acc[i][j], nv[i], w[j]);
    }
  }
  float4* x4 = (float4*)x;
  #pragma unroll
  for (int i=0;i<4;i++){
    size_t nidx = (size_t)(node0 + ng + 64*i) * 16;
    #pragma unroll
    for (int j=0;j<4;j++) x4[nidx + cg*4 + j] = acc[i][j];
  }
}

// ---------- K2 (MFMA): qkv(bf16) = x @ [Wq|Wk|Wv], 256 nodes/block ----------
__global__ __launch_bounds__(256) void k_qkv_m(const float* __restrict__ x,
    const unsigned short* __restrict__ wqkvT,   // [192][64] bf16
    unsigned short* __restrict__ qkv){
  __shared__ short s_w[192*72];   // stride 72 bf16 (144B rows: 2-way bank alias)
  const int tid = threadIdx.x;
  const int node0 = blockIdx.x * 256;
  {
    const unsigned* src = (const unsigned*)wqkvT;
    unsigned* dst = (unsigned*)s_w;
    #pragma unroll
    for (int r=0;r<24;r++){
      int j = tid + 256*r;
      int c = j >> 5, kk = j & 31;
      dst[c*36 + kk] = src[j];
    }
  }
  __syncthreads();
  const int lane = tid & 63, wave = tid >> 6;
  const int m = lane & 15, quad = lane >> 4;
  const int rowbase = node0 + wave*64;
  bf16x8 af[4][2];
  #pragma unroll
  for (int rt=0;rt<4;rt++){
    const float* xp = x + (size_t)(rowbase + rt*16 + m)*64 + quad*8;
    #pragma unroll
    for (int kc=0;kc<2;kc++){
      float4 u0 = *(const float4*)(xp + kc*32);
      float4 u1 = *(const float4*)(xp + kc*32 + 4);
      bf16x8 a;
      a[0]=(short)f2b(u0.x); a[1]=(short)f2b(u0.y); a[2]=(short)f2b(u0.z); a[3]=(short)f2b(u0.w);
      a[4]=(short)f2b(u1.x); a[5]=(short)f2b(u1.y); a[6]=(short)f2b(u1.z); a[7]=(short)f2b(u1.w);
      af[rt][kc] = a;
    }
  }
  #pragma unroll
  for (int ct=0;ct<12;ct++){
    bf16x8 b0 = *(const bf16x8*)&s_w[(ct*16+m)*72 + quad*8];
    bf16x8 b1 = *(const bf16x8*)&s_w[(ct*16+m)*72 + 32 + quad*8];
    #pragma unroll
    for (int rt=0;rt<4;rt++){
      f32x4 acc = {0.f,0.f,0.f,0.f};
      acc = __builtin_amdgcn_mfma_f32_16x16x32_bf16(af[rt][0], b0, acc, 0,0,0);
      acc = __builtin_amdgcn_mfma_f32_16x16x32_bf16(af[rt][1], b1, acc, 0,0,0);
      size_t base = (size_t)(rowbase + rt*16 + quad*4)*192 + ct*16 + m;
      qkv[base]       = f2b(acc[0]);
      qkv[base+192]   = f2b(acc[1]);
      qkv[base+384]   = f2b(acc[2]);
      qkv[base+576]   = f2b(acc[3]);
    }
  }
}

// ---------- K4: edge attention via CSR gather; writes bf16 normalized attn ----
__global__ __launch_bounds__(256) void k_edge2(const unsigned short* __restrict__ qkv,
    const int* __restrict__ rstart, const int* __restrict__ cnt,
    const int* __restrict__ esorted, unsigned short* __restrict__ attn_in){
  const int tid = threadIdx.x;
  const int lane = tid & 63;
  const int sub  = lane >> 4;
  const int dg   = lane & 15;
  const int wave = tid >> 6;
  const int node = blockIdx.x*16 + wave*4 + sub;
  const ushort4* row = (const ushort4*)(qkv + (size_t)node*192);
  ushort4 qu = row[dg];
  float q0 = b2f(qu.x), q1 = b2f(qu.y), q2 = b2f(qu.z), q3 = b2f(qu.w);
  const int rs = rstart[node];
  const int n  = cnt[node];
  float a0=0.f, a1=0.f, a2=0.f, a3=0.f, den=0.f;
  for (int i=0;i<n;i++){
    int src = esorted[rs + i];
    ushort4 ku = *(const ushort4*)(qkv + (size_t)src*192 + 64 + dg*4);
    ushort4 vu = *(const ushort4*)(qkv + (size_t)src*192 + 128 + dg*4);
    float p = q0*b2f(ku.x) + q1*b2f(ku.y) + q2*b2f(ku.z) + q3*b2f(ku.w);
    p += __shfl_xor(p, 1);
    p += __shfl_xor(p, 2);          // sum over the 4 lanes of this head
    float w = __expf(p * 0.25f);    // softmax shift-invariant; skip segment_max
    den += w;
    a0 = fmaf(w, b2f(vu.x), a0);
    a1 = fmaf(w, b2f(vu.y), a1);
    a2 = fmaf(w, b2f(vu.z), a2);
    a3 = fmaf(w, b2f(vu.w), a3);
  }
  float inv = 1.0f/(den + 1e-9f);
  ushort4 o;
  o.x = f2b(a0*inv); o.y = f2b(a1*inv); o.z = f2b(a2*inv); o.w = f2b(a3*inv);
  ((ushort4*)attn_in)[(size_t)node*16 + dg] = o;
}

// ---------- K5 (MFMA): x = LN(x + attn_in @ Wo), 256 nodes/block ----------
__global__ __launch_bounds__(256) void k_attn_m(const unsigned short* __restrict__ attn_in,
    const unsigned short* __restrict__ woT, const float* __restrict__ lg,
    const float* __restrict__ lb, float* __restrict__ x){
  __shared__ short s_w[64*72];
  const int tid = threadIdx.x;
  const int node0 = blockIdx.x*256;
  {
    const unsigned* src = (const unsigned*)woT;
    unsigned* dst = (unsigned*)s_w;
    #pragma unroll
    for (int r=0;r<8;r++){
      int j = tid + 256*r;
      int c = j >> 5, kk = j & 31;
      dst[c*36 + kk] = src[j];
    }
  }
  __syncthreads();
  const int lane = tid&63, wave = tid>>6;
  const int m = lane&15, quad = lane>>4;
  const int rowbase = node0 + wave*64;
  bf16x8 bf[4][2];
  #pragma unroll
  for (int ct=0;ct<4;ct++){
    bf[ct][0] = *(const bf16x8*)&s_w[(ct*16+m)*72 + quad*8];
    bf[ct][1] = *(const bf16x8*)&s_w[(ct*16+m)*72 + 32 + quad*8];
  }
  float g[4], bb[4];
  #pragma unroll
  for (int ct=0;ct<4;ct++){ g[ct]=lg[ct*16+m]; bb[ct]=lb[ct*16+m]; }
  #pragma unroll
  for (int rt=0;rt<4;rt++){
    const unsigned short* ap = attn_in + (size_t)(rowbase + rt*16 + m)*64 + quad*8;
    bf16x8 a0 = *(const bf16x8*)ap;
    bf16x8 a1 = *(const bf16x8*)(ap + 32);
    f32x4 acc[4];
    #pragma unroll
    for (int ct=0;ct<4;ct++){
      f32x4 z = {0.f,0.f,0.f,0.f};
      z = __builtin_amdgcn_mfma_f32_16x16x32_bf16(a0, bf[ct][0], z, 0,0,0);
      z = __builtin_amdgcn_mfma_f32_16x16x32_bf16(a1, bf[ct][1], z, 0,0,0);
      acc[ct] = z;
    }
    #pragma unroll
    for (int i=0;i<4;i++){
      size_t row = (size_t)(rowbase + rt*16 + quad*4 + i)*64;
      float v0 = acc[0][i] + x[row + m];
      float v1 = acc[1][i] + x[row + 16 + m];
      float v2 = acc[2][i] + x[row + 32 + m];
      float v3 = acc[3][i] + x[row + 48 + m];
      float sm = v0+v1+v2+v3;
      float sq = v0*v0+v1*v1+v2*v2+v3*v3;
      #pragma unroll
      for (int mk=1; mk<16; mk<<=1){ sm += __shfl_xor(sm, mk); sq += __shfl_xor(sq, mk); }
      float mean = sm*0.015625f;
      float var  = sq*0.015625f - mean*mean;
      float rs   = rsqrtf(var + 1e-5f);
      x[row + m]      = (v0-mean)*rs*g[0]+bb[0];
      x[row + 16 + m] = (v1-mean)*rs*g[1]+bb[1];
      x[row + 32 + m] = (v2-mean)*rs*g[2]+bb[2];
      x[row + 48 + m] = (v3-mean)*rs*g[3]+bb[3];
    }
  }
}

// ---------- K6 (MFMA): h(bf16) = relu(x @ W1 + b1), 256 nodes/block ----------
__global__ __launch_bounds__(256) void k_ffn1_m(const float* __restrict__ x,
    const unsigned short* __restrict__ w1T, const float* __restrict__ b1_l,
    unsigned short* __restrict__ h){
  __shared__ short s_w[128*72];
  const int tid = threadIdx.x;
  const int node0 = blockIdx.x*256;
  {
    const unsigned* src = (const unsigned*)w1T;
    unsigned* dst = (unsigned*)s_w;
    #pragma unroll
    for (int r=0;r<16;r++){
      int j = tid + 256*r;
      int c = j >> 5, kk = j & 31;
      dst[c*36 + kk] = src[j];
    }
  }
  __syncthreads();
  const int lane = tid&63, wave = tid>>6;
  const int m = lane&15, quad = lane>>4;
  const int rowbase = node0 + wave*64;
  bf16x8 af[4][2];
  #pragma unroll
  for (int rt=0;rt<4;rt++){
    const float* xp = x + (size_t)(rowbase + rt*16 + m)*64 + quad*8;
    #pragma unroll
    for (int kc=0;kc<2;kc++){
      float4 u0 = *(const float4*)(xp + kc*32);
      float4 u1 = *(const float4*)(xp + kc*32 + 4);
      bf16x8 a;
      a[0]=(short)f2b(u0.x); a[1]=(short)f2b(u0.y); a[2]=(short)f2b(u0.z); a[3]=(short)f2b(u0.w);
      a[4]=(short)f2b(u1.x); a[5]=(short)f2b(u1.y); a[6]=(short)f2b(u1.z); a[7]=(short)f2b(u1.w);
      af[rt][kc] = a;
    }
  }
  #pragma unroll
  for (int ct=0;ct<8;ct++){
    bf16x8 b0 = *(const bf16x8*)&s_w[(ct*16+m)*72 + quad*8];
    bf16x8 b1 = *(const bf16x8*)&s_w[(ct*16+m)*72 + 32 + quad*8];
    float bias = b1_l[ct*16+m];
    #pragma unroll
    for (int rt=0;rt<4;rt++){
      f32x4 acc = {0.f,0.f,0.f,0.f};
      acc = __builtin_amdgcn_mfma_f32_16x16x32_bf16(af[rt][0], b0, acc, 0,0,0);
      acc = __builtin_amdgcn_mfma_f32_16x16x32_bf16(af[rt][1], b1, acc, 0,0,0);
      size_t base = (size_t)(rowbase + rt*16 + quad*4)*128 + ct*16 + m;
      h[base]     = f2b(fmaxf(acc[0]+bias, 0.f));
      h[base+128] = f2b(fmaxf(acc[1]+bias, 0.f));
      h[base+256] = f2b(fmaxf(acc[2]+bias, 0.f));
      h[base+384] = f2b(fmaxf(acc[3]+bias, 0.f));
    }
  }
}

// ---------- K7 (MFMA): x = LN(x + h @ W2 + b2), 256 nodes/block ----------
__global__ __launch_bounds__(256) void k_ffn2_m(const unsigned short* __restrict__ h,
    const unsigned short* __restrict__ w2T, const float* __restrict__ b2_l,
    const float* __restrict__ lg, const float* __restrict__ lb,
    float* __restrict__ x){
  __shared__ short s_w[64*136];   // stride 136 bf16 (272B rows)
  const int tid = threadIdx.x;
  const int node0 = blockIdx.x*256;
  {
    const unsigned* src = (const unsigned*)w2T;
    unsigned* dst = (unsigned*)s_w;
    #pragma unroll
    for (int r=0;r<16;r++){
      int j = tid + 256*r;
      int c = j >> 6, kk = j & 63;
      dst[c*68 + kk] = src[j];
    }
  }
  __syncthreads();
  const int lane = tid&63, wave = tid>>6;
  const int m = lane&15, quad = lane>>4;
  const int rowbase = node0 + wave*64;
  bf16x8 bf[4][4];
  #pragma unroll
  for (int ct=0;ct<4;ct++){
    #pragma unroll
    for (int kc=0;kc<4;kc++)
      bf[ct][kc] = *(const bf16x8*)&s_w[(ct*16+m)*136 + kc*32 + quad*8];
  }
  float g[4], bb[4], b2v[4];
  #pragma unroll
  for (int ct=0;ct<4;ct++){ g[ct]=lg[ct*16+m]; bb[ct]=lb[ct*16+m]; b2v[ct]=b2_l[ct*16+m]; }
  #pragma unroll
  for (int rt=0;rt<4;rt++){
    const unsigned short* ap = h + (size_t)(rowbase + rt*16 + m)*128 + quad*8;
    bf16x8 a0 = *(const bf16x8*)ap;
    bf16x8 a1 = *(const bf16x8*)(ap + 32);
    bf16x8 a2 = *(const bf16x8*)(ap + 64);
    bf16x8 a3 = *(const bf16x8*)(ap + 96);
    f32x4 acc[4];
    #pragma unroll
    for (int ct=0;ct<4;ct++){
      f32x4 z = {0.f,0.f,0.f,0.f};
      z = __builtin_amdgcn_mfma_f32_16x16x32_bf16(a0, bf[ct][0], z, 0,0,0);
      z = __builtin_amdgcn_mfma_f32_16x16x32_bf16(a1, bf[ct][1], z, 0,0,0);
      z = __builtin_amdgcn_mfma_f32_16x16x32_bf16(a2, bf[ct][2], z, 0,0,0);
      z = __builtin_amdgcn_mfma_f32_16x16x32_bf16(a3, bf[ct][3], z, 0,0,0);
      acc[ct] = z;
    }
    #pragma unroll
    for (int i=0;i<4;i++){
      size_t row = (size_t)(rowbase + rt*16 + quad*4 + i)*64;
      float v0 = acc[0][i] + b2v[0] + x[row + m];
      float v1 = acc[1][i] + b2v[1] + x[row + 16 + m];
      float v2 = acc[2][i] + b2v[2] + x[row + 32 + m];
      float v3 = acc[3][i] + b2v[3] + x[row + 48 + m];
      float sm = v0+v1+v2+v3;
      float sq = v0*v0+v1*v1+v2*v2+v3*v3;
      #pragma unroll
      for (int mk=1; mk<16; mk<<=1){ sm += __shfl_xor(sm, mk); sq += __shfl_xor(sq, mk); }
      float mean = sm*0.015625f;
      float var  = sq*0.015625f - mean*mean;
      float rs   = rsqrtf(var + 1e-5f);
      x[row + m]      = (v0-mean)*rs*g[0]+bb[0];
      x[row + 16 + m] = (v1-mean)*rs*g[1]+bb[1];
      x[row + 32 + m] = (v2-mean)*rs*g[2]+bb[2];
      x[row + 48 + m] = (v3-mean)*rs*g[3]+bb[3];
    }
  }
}

// ---------- heads: feat assembly ----------
__global__ __launch_bounds__(256) void k_feat(const float* __restrict__ x,
    const float* __restrict__ obs, const int* __restrict__ agents,
    const float* __restrict__ Wr, const float* __restrict__ br,
    float* __restrict__ feat){
  __shared__ float s_xa[64];
  const int b = blockIdx.x, tid = threadIdx.x;
  if (tid < 64) s_xa[tid] = x[(size_t)agents[b]*HD + tid];
  __syncthreads();
  if (tid < AD){
    float a = br[tid];
    #pragma unroll 8
    for (int k=0;k<HD;k++) a = fmaf(s_xa[k], Wr[k*AD + tid], a);
    feat[(size_t)b*1536 + tid] = a;
  }
  for (int i=tid;i<OBSD;i+=256) feat[(size_t)b*1536 + AD + i] = obs[(size_t)b*OBSD + i];
  if (tid < 21) feat[(size_t)b*1536 + 1515 + tid] = 0.f;
}

// ---------- heads: split-K partial GEMM ----------
template<int ROWS, int COLS, int CH, int KS, int N>
__global__ __launch_bounds__(ROWS*COLS) void k_gemm_part(
    const float* __restrict__ A, int lda, int K,
    const float* __restrict__ W, float* __restrict__ part){
  constexpr int BT = ROWS*COLS;
  __shared__ float s_a[ROWS*CH];
  const int tid = threadIdx.x;
  const int ct = blockIdx.x, rg = blockIdx.y, ks = blockIdx.z;
  const int chunk = (K + KS - 1) / KS;
  const int k0 = ks * chunk;
  const int len = min(K - k0, chunk);
  const int row0 = rg * ROWS;
  #pragma unroll
  for (int rr=0; rr<ROWS; rr++)
    for (int i=tid; i<len; i+=BT)
      s_a[rr*CH + i] = A[(size_t)(row0+rr)*lda + k0 + i];
  __syncthreads();
  const int r = tid / COLS, c = tid % COLS;
  const float* wp = W + (size_t)k0*N + ct*COLS + c;
  const float* ap = s_a + r*CH;
  float acc = 0.f;
  #pragma unroll 8
  for (int k=0;k<len;k++) acc = fmaf(ap[k], wp[(size_t)k*N], acc);
  part[((size_t)ks*128 + row0 + r)*N + ct*COLS + c] = acc;
}

template<int KS, int N, bool TANH>
__global__ __launch_bounds__(256) void k_reduce(const float* __restrict__ part,
    const float* __restrict__ bias, float* __restrict__ out, int MN){
  const int idx = blockIdx.x*256 + threadIdx.x;
  if (idx >= MN) return;
  float s = bias[idx & (N-1)];
  #pragma unroll
  for (int ks=0;ks<KS;ks++) s += part[(size_t)ks*MN + idx];
  out[idx] = TANH ? tanhf(s) : s;
}

// ---------- heads: logits ----------
__global__ __launch_bounds__(256) void k_logits(const float* __restrict__ f2,
    const float* __restrict__ Wlog, const float* __restrict__ blog,
    float* __restrict__ out){
  __shared__ float s_f[512];
  __shared__ float s_p[16*AD];
  const int b = blockIdx.x, tid = threadIdx.x;
  s_f[tid]     = f2[(size_t)b*512 + tid];
  s_f[tid+256] = f2[(size_t)b*512 + 256 + tid];
  __syncthreads();
  if (tid < 240){
    int c = tid % AD, kc = tid / AD;
    float a = 0.f;
    #pragma unroll 8
    for (int j=0;j<32;j++){ int k = kc*32 + j; a = fmaf(s_f[k], Wlog[k*AD + c], a); }
    s_p[tid] = a;
  }
  __syncthreads();
  if (tid < AD){
    float a = blog[tid];
    #pragma unroll
    for (int kc=0;kc<16;kc++) a += s_p[kc*AD + tid];
    out[(size_t)b*AD + tid] = a;
  }
}

// ---------- heads: value finish ----------
__global__ __launch_bounds__(128) void k_vfin(const float* __restrict__ vh,
    const float* __restrict__ Wv2, const float* __restrict__ bv2,
    const float* __restrict__ Wvo, const float* __restrict__ bvo,
    float* __restrict__ out){
  __shared__ float s_v[128];
  __shared__ float s_r[128];
  const int b = blockIdx.x, tid = threadIdx.x;
  s_v[tid] = vh[(size_t)b*128 + tid];
  __syncthreads();
  float a = bv2[tid];
  #pragma unroll 8
  for (int k=0;k<128;k++) a = fmaf(s_v[k], Wv2[k*128 + tid], a);
  s_r[tid] = tanhf(a) * Wvo[tid];
  __syncthreads();
  if (tid < 64){
    float v = s_r[tid] + s_r[tid+64];
    #pragma unroll
    for (int m=32;m>=1;m>>=1) v += __shfl_xor(v, m);
    if (tid==0) out[GRAPHS*AD + b] = v + bvo[0];
  }
}

// ---------- launch ----------
extern "C" void kernel_launch(void* const* d_in, const int* in_sizes, int n_in,
                              void* d_out, int out_size, void* d_ws, size_t ws_size,
                              hipStream_t stream) {
  (void)in_sizes; (void)n_in; (void)out_size; (void)ws_size;
  const float* nf     = (const float*)d_in[0];
  const float* obs    = (const float*)d_in[1];
  const int*   esrc   = (const int*)d_in[2];
  const int*   edst   = (const int*)d_in[3];
  const int*   agents = (const int*)d_in[4];
  const float* Win    = (const float*)d_in[5];
  const float* Wq     = (const float*)d_in[6];
  const float* Wk     = (const float*)d_in[7];
  const float* Wv     = (const float*)d_in[8];
  const float* Wo     = (const float*)d_in[9];
  const float* ln1g   = (const float*)d_in[10];
  const float* ln1b   = (const float*)d_in[11];
  const float* W1     = (const float*)d_in[12];
  const float* b1     = (const float*)d_in[13];
  const float* W2     = (const float*)d_in[14];
  const float* b2     = (const float*)d_in[15];
  const float* ln2g   = (const float*)d_in[16];
  const float* ln2b   = (const float*)d_in[17];
  const float* Wr     = (const float*)d_in[18];
  const float* br     = (const float*)d_in[19];
  const float* Wp1    = (const float*)d_in[20];
  const float* bp1    = (const float*)d_in[21];
  const float* Wp2    = (const float*)d_in[22];
  const float* bp2    = (const float*)d_in[23];
  const float* Wlog   = (const float*)d_in[24];
  const float* blog   = (const float*)d_in[25];
  const float* Wv1    = (const float*)d_in[26];
  const float* bv1    = (const float*)d_in[27];
  const float* Wv2    = (const float*)d_in[28];
  const float* bv2    = (const float*)d_in[29];
  const float* Wvo    = (const float*)d_in[30];
  const float* bvo    = (const float*)d_in[31];
  float* out = (float*)d_out;

  // workspace layout
  float* x = (float*)d_ws;                                     // TOTN*64 f32
  unsigned short* qkv     = (unsigned short*)(x + (size_t)TOTN*HD); // TOTN*192 bf16
  unsigned short* hbuf    = qkv;                               // ffn intermediate aliases qkv
  unsigned short* attn_in = qkv + (size_t)TOTN*192;            // TOTN*64 bf16
  unsigned short* wpack   = attn_in + (size_t)TOTN*HD;         // 131072 bf16
  int* cnt     = (int*)(wpack + 131072);                       // TOTN
  int* rstart  = cnt + TOTN;
  int* cursor  = rstart + TOTN;
  int* esorted = cursor + TOTN;                                // TOTE
  // head buffers alias attn_in (dead after last k_attn_m)
  float* feat = (float*)attn_in;
  float* f1   = feat + 128*1536;
  float* f2   = f1 + 128*512;
  float* vh   = f2 + 128*512;
  float* part = vh + 128*128;

  // weight prep + CSR build (edge topology is layer-invariant)
  k_wprep  <<<512, 256, 0, stream>>>(Wq, Wk, Wv, Wo, W1, W2, wpack);
  k_zero   <<<TOTN/256, 256, 0, stream>>>(cnt);
  k_hist   <<<TOTE/256, 256, 0, stream>>>(edst, cnt);
  k_scan   <<<GRAPHS, 1024, 0, stream>>>(cnt, rstart, cursor);
  k_scatter<<<TOTE/256, 256, 0, stream>>>(esrc, edst, cursor, esorted);

  k_in<<<TOTN/256, 256, 0, stream>>>(nf, Win, x);
  for (int l=0; l<4; l++){
    const unsigned short* wl = wpack + l*32768;
    k_qkv_m <<<TOTN/256, 256, 0, stream>>>(x, wl, qkv);
    k_edge2 <<<TOTN/16, 256, 0, stream>>>(qkv, rstart, cnt, esorted, attn_in);
    k_attn_m<<<TOTN/256, 256, 0, stream>>>(attn_in, wl + 12288,
                                           ln1g + l*64, ln1b + l*64, x);
    k_ffn1_m<<<TOTN/256, 256, 0, stream>>>(x, wl + 16384, b1 + l*128, hbuf);
    k_ffn2_m<<<TOTN/256, 256, 0, stream>>>(hbuf, wl + 24576, b2 + l*64,
                                           ln2g + l*64, ln2b + l*64, x);
  }
  // policy head
  k_feat<<<GRAPHS, 256, 0, stream>>>(x, obs, agents, Wr, br, feat);
  k_gemm_part<2,256,384,4,512><<<dim3(2,64,4), 512, 0, stream>>>(feat, 1536, 1515, Wp1, part);
  k_reduce<4,512,true><<<256, 256, 0, stream>>>(part, bp1, f1, 128*512);
  k_gemm_part<2,256,256,2,512><<<dim3(2,64,2), 512, 0, stream>>>(f1, 512, 512, Wp2, part);
  k_reduce<2,512,true><<<256, 256, 0, stream>>>(part, bp2, f2, 128*512);
  k_logits<<<GRAPHS, 256, 0, stream>>>(f2, Wlog, blog, out);
  // value head
  k_gemm_part<4,128,192,8,128><<<dim3(1,32,8), 512, 0, stream>>>(obs, 1500, 1500, Wv1, part);
  k_reduce<8,128,true><<<64, 256, 0, stream>>>(part, bv1, vh, 128*128);
  k_vfin<<<GRAPHS, 128, 0, stream>>>(vh, Wv2, bv2, Wvo, bvo, out);
}

// Round 5
// 613.092 us; speedup vs baseline: 3.2062x; 1.1124x over previous
//
#include <hip/hip_runtime.h>
#include <hip/hip_bf16.h>
#include <cstdint>
#include <cstddef>

#define DEV static __device__ __forceinline__

constexpr int GRAPHS = 128;
constexpr int NPG    = 1000;   // nodes per graph
constexpr int EPG    = 4000;   // edges per graph
constexpr int TOTN   = GRAPHS * NPG;  // 128000
constexpr int TOTE   = GRAPHS * EPG;  // 512000
constexpr int HD     = 64;
constexpr int OBSD   = 1500;
constexpr int AD     = 15;

typedef __attribute__((ext_vector_type(8))) short bf16x8;
typedef __attribute__((ext_vector_type(4))) float f32x4;

// ---------- helpers ----------
DEV unsigned short f2b(float f){   // round-to-nearest-even bf16
  unsigned u = __float_as_uint(f);
  return (unsigned short)((u + 0x7fffu + ((u >> 16) & 1u)) >> 16);
}
DEV float b2f(unsigned short s){ return __uint_as_float((unsigned)s << 16); }

DEV void fma4(float4& a, float s, const float4 w){
  a.x = fmaf(s, w.x, a.x); a.y = fmaf(s, w.y, a.y);
  a.z = fmaf(s, w.z, a.z); a.w = fmaf(s, w.w, a.w);
}

DEV ushort4 pack4(float4 v){
  ushort4 r; r.x=f2b(v.x); r.y=f2b(v.y); r.z=f2b(v.z); r.w=f2b(v.w); return r;
}

// ---------- weight prep: pack all layer weights to bf16 W^T ----------
// per layer (stride 32768 bf16): qkvT[192][64] | woT[64][64] | w1T[128][64] | w2T[64][128]
__global__ __launch_bounds__(256) void k_wprep(const float* __restrict__ Wq,
    const float* __restrict__ Wk, const float* __restrict__ Wv,
    const float* __restrict__ Wo, const float* __restrict__ W1,
    const float* __restrict__ W2, unsigned short* __restrict__ wpack){
  int e = blockIdx.x*256 + threadIdx.x;
  int l = e >> 15;
  int r = e & 32767;
  float val;
  if (r < 12288){
    int c = r >> 6, k = r & 63;
    val = (c < 64)  ? Wq[l*4096 + k*64 + c]
        : (c < 128) ? Wk[l*4096 + k*64 + (c-64)]
                    : Wv[l*4096 + k*64 + (c-128)];
  } else if (r < 16384){
    int i = r - 12288; int c = i >> 6, k = i & 63;
    val = Wo[l*4096 + k*64 + c];
  } else if (r < 24576){
    int i = r - 16384; int c = i >> 6, k = i & 63;
    val = W1[l*8192 + k*128 + c];
  } else {
    int i = r - 24576; int c = i >> 7, k = i & 127;
    val = W2[l*8192 + k*64 + c];
  }
  wpack[e] = f2b(val);
}

// ---------- CSR build (once per call; reused by all 4 layers) ----------
__global__ __launch_bounds__(256) void k_zero(int* __restrict__ cnt){
  cnt[blockIdx.x*256 + threadIdx.x] = 0;
}

__global__ __launch_bounds__(256) void k_hist(const int* __restrict__ edst,
                                              int* __restrict__ cnt){
  int e = blockIdx.x*256 + threadIdx.x;
  atomicAdd(&cnt[edst[e]], 1);
}

__global__ __launch_bounds__(1024) void k_scan(const int* __restrict__ cnt,
    int* __restrict__ rstart, int* __restrict__ cursor){
  __shared__ int s[1024];
  const int g = blockIdx.x, tid = threadIdx.x;
  int v = (tid < NPG) ? cnt[g*NPG + tid] : 0;
  s[tid] = v;
  __syncthreads();
  #pragma unroll
  for (int off=1; off<1024; off<<=1){
    int t = (tid >= off) ? s[tid-off] : 0;
    __syncthreads();
    s[tid] += t;
    __syncthreads();
  }
  if (tid < NPG){
    int r = g*EPG + (s[tid] - v);
    rstart[g*NPG+tid] = r;
    cursor[g*NPG+tid] = r;
  }
}

__global__ __launch_bounds__(256) void k_scatter(const int* __restrict__ esrc,
    const int* __restrict__ edst, int* __restrict__ cursor,
    int* __restrict__ esorted){
  int e = blockIdx.x*256 + threadIdx.x;
  int pos = atomicAdd(&cursor[edst[e]], 1);
  esorted[pos] = esrc[e];
}

// ---------- K1: x(bf16) = node_feats @ W_in  [128000,32]x[32,64] ----------
__global__ __launch_bounds__(256) void k_in(const float* __restrict__ nf,
                                            const float* __restrict__ Win,
                                            unsigned short* __restrict__ xb){
  __shared__ float  s_nf[256*36];
  __shared__ float4 s_w[512];
  const int tid = threadIdx.x;
  const int node0 = blockIdx.x * 256;
  const float4* W4 = (const float4*)Win;
  s_w[tid] = W4[tid]; s_w[tid+256] = W4[tid+256];
  const float4* nf4 = (const float4*)nf;
  float4* snf4 = (float4*)s_nf;
  #pragma unroll
  for (int r=0;r<8;r++){
    int i = tid + 256*r; int n = i>>3, k4 = i&7;
    snf4[n*9 + k4] = nf4[(size_t)(node0+n)*8 + k4];
  }
  __syncthreads();
  const int ng = tid>>2, cg = tid&3;
  float4 acc[4][4];
  #pragma unroll
  for (int i=0;i<4;i++){ acc[i][0]=make_float4(0,0,0,0); acc[i][1]=make_float4(0,0,0,0);
                         acc[i][2]=make_float4(0,0,0,0); acc[i][3]=make_float4(0,0,0,0); }
  #pragma unroll 4
  for (int k=0;k<32;k++){
    float nv[4];
    #pragma unroll
    for (int i=0;i<4;i++) nv[i] = s_nf[(ng + 64*i)*36 + k];
    float4 w[4];
    #pragma unroll
    for (int j=0;j<4;j++) w[j] = s_w[k*16 + cg*4 + j];
    #pragma unroll
    for (int i=0;i<4;i++){
      #pragma unroll
      for (int j=0;j<4;j++) fma4(acc[i][j], nv[i], w[j]);
    }
  }
  ushort4* xb4 = (ushort4*)xb;
  #pragma unroll
  for (int i=0;i<4;i++){
    size_t nidx = (size_t)(node0 + ng + 64*i) * 16;
    #pragma unroll
    for (int j=0;j<4;j++) xb4[nidx + cg*4 + j] = pack4(acc[i][j]);
  }
}

// ---------- K2 (MFMA): qkv(bf16) = x @ [Wq|Wk|Wv], 256 nodes/block ----------
__global__ __launch_bounds__(256) void k_qkv_m(const unsigned short* __restrict__ xb,
    const unsigned short* __restrict__ wqkvT,   // [192][64] bf16
    unsigned short* __restrict__ qkv){
  __shared__ short s_w[192*72];   // stride 72 bf16 (144B rows: 2-way bank alias)
  const int tid = threadIdx.x;
  const int node0 = blockIdx.x * 256;
  {
    const unsigned* src = (const unsigned*)wqkvT;
    unsigned* dst = (unsigned*)s_w;
    #pragma unroll
    for (int r=0;r<24;r++){
      int j = tid + 256*r;
      int c = j >> 5, kk = j & 31;
      dst[c*36 + kk] = src[j];
    }
  }
  __syncthreads();
  const int lane = tid & 63, wave = tid >> 6;
  const int m = lane & 15, quad = lane >> 4;
  const int rowbase = node0 + wave*64;
  bf16x8 af[4][2];
  #pragma unroll
  for (int rt=0;rt<4;rt++){
    const unsigned short* xp = xb + (size_t)(rowbase + rt*16 + m)*64 + quad*8;
    af[rt][0] = *(const bf16x8*)xp;
    af[rt][1] = *(const bf16x8*)(xp + 32);
  }
  #pragma unroll
  for (int ct=0;ct<12;ct++){
    bf16x8 b0 = *(const bf16x8*)&s_w[(ct*16+m)*72 + quad*8];
    bf16x8 b1 = *(const bf16x8*)&s_w[(ct*16+m)*72 + 32 + quad*8];
    #pragma unroll
    for (int rt=0;rt<4;rt++){
      f32x4 acc = {0.f,0.f,0.f,0.f};
      acc = __builtin_amdgcn_mfma_f32_16x16x32_bf16(af[rt][0], b0, acc, 0,0,0);
      acc = __builtin_amdgcn_mfma_f32_16x16x32_bf16(af[rt][1], b1, acc, 0,0,0);
      size_t base = (size_t)(rowbase + rt*16 + quad*4)*192 + ct*16 + m;
      qkv[base]       = f2b(acc[0]);
      qkv[base+192]   = f2b(acc[1]);
      qkv[base+384]   = f2b(acc[2]);
      qkv[base+576]   = f2b(acc[3]);
    }
  }
}

// ---------- K4: edge attention via CSR gather; XCD-swizzled ----------
__global__ __launch_bounds__(256) void k_edge2(const unsigned short* __restrict__ qkv,
    const int* __restrict__ rstart, const int* __restrict__ cnt,
    const int* __restrict__ esorted, unsigned short* __restrict__ attn_in){
  const int tid = threadIdx.x;
  // XCD swizzle: blocks i%8==k (dispatched to XCD k) handle a contiguous
  // 16-graph slice -> per-XCD L2 working set ~6MB instead of 49MB.
  const int wb = (blockIdx.x & 7)*1000 + (blockIdx.x >> 3);
  const int lane = tid & 63;
  const int sub  = lane >> 4;
  const int dg   = lane & 15;
  const int wave = tid >> 6;
  const int node = wb*16 + wave*4 + sub;
  const ushort4* row = (const ushort4*)(qkv + (size_t)node*192);
  ushort4 qu = row[dg];
  float q0 = b2f(qu.x), q1 = b2f(qu.y), q2 = b2f(qu.z), q3 = b2f(qu.w);
  const int rs = rstart[node];
  const int n  = cnt[node];
  float a0=0.f, a1=0.f, a2=0.f, a3=0.f, den=0.f;
  for (int i=0;i<n;i++){
    int src = esorted[rs + i];
    ushort4 ku = *(const ushort4*)(qkv + (size_t)src*192 + 64 + dg*4);
    ushort4 vu = *(const ushort4*)(qkv + (size_t)src*192 + 128 + dg*4);
    float p = q0*b2f(ku.x) + q1*b2f(ku.y) + q2*b2f(ku.z) + q3*b2f(ku.w);
    p += __shfl_xor(p, 1);
    p += __shfl_xor(p, 2);          // sum over the 4 lanes of this head
    float w = __expf(p * 0.25f);    // softmax shift-invariant; skip segment_max
    den += w;
    a0 = fmaf(w, b2f(vu.x), a0);
    a1 = fmaf(w, b2f(vu.y), a1);
    a2 = fmaf(w, b2f(vu.z), a2);
    a3 = fmaf(w, b2f(vu.w), a3);
  }
  float inv = 1.0f/(den + 1e-9f);
  ushort4 o;
  o.x = f2b(a0*inv); o.y = f2b(a1*inv); o.z = f2b(a2*inv); o.w = f2b(a3*inv);
  ((ushort4*)attn_in)[(size_t)node*16 + dg] = o;
}

// ---------- K5 (MFMA): x = LN(x + attn_in @ Wo), 256 nodes/block ----------
__global__ __launch_bounds__(256) void k_attn_m(const unsigned short* __restrict__ attn_in,
    const unsigned short* __restrict__ woT, const float* __restrict__ lg,
    const float* __restrict__ lb, unsigned short* __restrict__ xb){
  __shared__ short s_w[64*72];
  const int tid = threadIdx.x;
  const int node0 = blockIdx.x*256;
  {
    const unsigned* src = (const unsigned*)woT;
    unsigned* dst = (unsigned*)s_w;
    #pragma unroll
    for (int r=0;r<8;r++){
      int j = tid + 256*r;
      int c = j >> 5, kk = j & 31;
      dst[c*36 + kk] = src[j];
    }
  }
  __syncthreads();
  const int lane = tid&63, wave = tid>>6;
  const int m = lane&15, quad = lane>>4;
  const int rowbase = node0 + wave*64;
  bf16x8 bf[4][2];
  #pragma unroll
  for (int ct=0;ct<4;ct++){
    bf[ct][0] = *(const bf16x8*)&s_w[(ct*16+m)*72 + quad*8];
    bf[ct][1] = *(const bf16x8*)&s_w[(ct*16+m)*72 + 32 + quad*8];
  }
  float g[4], bb[4];
  #pragma unroll
  for (int ct=0;ct<4;ct++){ g[ct]=lg[ct*16+m]; bb[ct]=lb[ct*16+m]; }
  #pragma unroll
  for (int rt=0;rt<4;rt++){
    const unsigned short* ap = attn_in + (size_t)(rowbase + rt*16 + m)*64 + quad*8;
    bf16x8 a0 = *(const bf16x8*)ap;
    bf16x8 a1 = *(const bf16x8*)(ap + 32);
    f32x4 acc[4];
    #pragma unroll
    for (int ct=0;ct<4;ct++){
      f32x4 z = {0.f,0.f,0.f,0.f};
      z = __builtin_amdgcn_mfma_f32_16x16x32_bf16(a0, bf[ct][0], z, 0,0,0);
      z = __builtin_amdgcn_mfma_f32_16x16x32_bf16(a1, bf[ct][1], z, 0,0,0);
      acc[ct] = z;
    }
    #pragma unroll
    for (int i=0;i<4;i++){
      size_t row = (size_t)(rowbase + rt*16 + quad*4 + i)*64;
      float v0 = acc[0][i] + b2f(xb[row + m]);
      float v1 = acc[1][i] + b2f(xb[row + 16 + m]);
      float v2 = acc[2][i] + b2f(xb[row + 32 + m]);
      float v3 = acc[3][i] + b2f(xb[row + 48 + m]);
      float sm = v0+v1+v2+v3;
      float sq = v0*v0+v1*v1+v2*v2+v3*v3;
      #pragma unroll
      for (int mk=1; mk<16; mk<<=1){ sm += __shfl_xor(sm, mk); sq += __shfl_xor(sq, mk); }
      float mean = sm*0.015625f;
      float var  = sq*0.015625f - mean*mean;
      float rs   = rsqrtf(var + 1e-5f);
      xb[row + m]      = f2b((v0-mean)*rs*g[0]+bb[0]);
      xb[row + 16 + m] = f2b((v1-mean)*rs*g[1]+bb[1]);
      xb[row + 32 + m] = f2b((v2-mean)*rs*g[2]+bb[2]);
      xb[row + 48 + m] = f2b((v3-mean)*rs*g[3]+bb[3]);
    }
  }
}

// ---------- K6 (MFMA): h(bf16) = relu(x @ W1 + b1), 256 nodes/block ----------
__global__ __launch_bounds__(256) void k_ffn1_m(const unsigned short* __restrict__ xb,
    const unsigned short* __restrict__ w1T, const float* __restrict__ b1_l,
    unsigned short* __restrict__ h){
  __shared__ short s_w[128*72];
  const int tid = threadIdx.x;
  const int node0 = blockIdx.x*256;
  {
    const unsigned* src = (const unsigned*)w1T;
    unsigned* dst = (unsigned*)s_w;
    #pragma unroll
    for (int r=0;r<16;r++){
      int j = tid + 256*r;
      int c = j >> 5, kk = j & 31;
      dst[c*36 + kk] = src[j];
    }
  }
  __syncthreads();
  const int lane = tid&63, wave = tid>>6;
  const int m = lane&15, quad = lane>>4;
  const int rowbase = node0 + wave*64;
  bf16x8 af[4][2];
  #pragma unroll
  for (int rt=0;rt<4;rt++){
    const unsigned short* xp = xb + (size_t)(rowbase + rt*16 + m)*64 + quad*8;
    af[rt][0] = *(const bf16x8*)xp;
    af[rt][1] = *(const bf16x8*)(xp + 32);
  }
  #pragma unroll
  for (int ct=0;ct<8;ct++){
    bf16x8 b0 = *(const bf16x8*)&s_w[(ct*16+m)*72 + quad*8];
    bf16x8 b1 = *(const bf16x8*)&s_w[(ct*16+m)*72 + 32 + quad*8];
    float bias = b1_l[ct*16+m];
    #pragma unroll
    for (int rt=0;rt<4;rt++){
      f32x4 acc = {0.f,0.f,0.f,0.f};
      acc = __builtin_amdgcn_mfma_f32_16x16x32_bf16(af[rt][0], b0, acc, 0,0,0);
      acc = __builtin_amdgcn_mfma_f32_16x16x32_bf16(af[rt][1], b1, acc, 0,0,0);
      size_t base = (size_t)(rowbase + rt*16 + quad*4)*128 + ct*16 + m;
      h[base]     = f2b(fmaxf(acc[0]+bias, 0.f));
      h[base+128] = f2b(fmaxf(acc[1]+bias, 0.f));
      h[base+256] = f2b(fmaxf(acc[2]+bias, 0.f));
      h[base+384] = f2b(fmaxf(acc[3]+bias, 0.f));
    }
  }
}

// ---------- K7 (MFMA): x = LN(x + h @ W2 + b2), 256 nodes/block ----------
__global__ __launch_bounds__(256) void k_ffn2_m(const unsigned short* __restrict__ h,
    const unsigned short* __restrict__ w2T, const float* __restrict__ b2_l,
    const float* __restrict__ lg, const float* __restrict__ lb,
    unsigned short* __restrict__ xb){
  __shared__ short s_w[64*136];   // stride 136 bf16 (272B rows)
  const int tid = threadIdx.x;
  const int node0 = blockIdx.x*256;
  {
    const unsigned* src = (const unsigned*)w2T;
    unsigned* dst = (unsigned*)s_w;
    #pragma unroll
    for (int r=0;r<16;r++){
      int j = tid + 256*r;
      int c = j >> 6, kk = j & 63;
      dst[c*68 + kk] = src[j];
    }
  }
  __syncthreads();
  const int lane = tid&63, wave = tid>>6;
  const int m = lane&15, quad = lane>>4;
  const int rowbase = node0 + wave*64;
  bf16x8 bf[4][4];
  #pragma unroll
  for (int ct=0;ct<4;ct++){
    #pragma unroll
    for (int kc=0;kc<4;kc++)
      bf[ct][kc] = *(const bf16x8*)&s_w[(ct*16+m)*136 + kc*32 + quad*8];
  }
  float g[4], bb[4], b2v[4];
  #pragma unroll
  for (int ct=0;ct<4;ct++){ g[ct]=lg[ct*16+m]; bb[ct]=lb[ct*16+m]; b2v[ct]=b2_l[ct*16+m]; }
  #pragma unroll
  for (int rt=0;rt<4;rt++){
    const unsigned short* ap = h + (size_t)(rowbase + rt*16 + m)*128 + quad*8;
    bf16x8 a0 = *(const bf16x8*)ap;
    bf16x8 a1 = *(const bf16x8*)(ap + 32);
    bf16x8 a2 = *(const bf16x8*)(ap + 64);
    bf16x8 a3 = *(const bf16x8*)(ap + 96);
    f32x4 acc[4];
    #pragma unroll
    for (int ct=0;ct<4;ct++){
      f32x4 z = {0.f,0.f,0.f,0.f};
      z = __builtin_amdgcn_mfma_f32_16x16x32_bf16(a0, bf[ct][0], z, 0,0,0);
      z = __builtin_amdgcn_mfma_f32_16x16x32_bf16(a1, bf[ct][1], z, 0,0,0);
      z = __builtin_amdgcn_mfma_f32_16x16x32_bf16(a2, bf[ct][2], z, 0,0,0);
      z = __builtin_amdgcn_mfma_f32_16x16x32_bf16(a3, bf[ct][3], z, 0,0,0);
      acc[ct] = z;
    }
    #pragma unroll
    for (int i=0;i<4;i++){
      size_t row = (size_t)(rowbase + rt*16 + quad*4 + i)*64;
      float v0 = acc[0][i] + b2v[0] + b2f(xb[row + m]);
      float v1 = acc[1][i] + b2v[1] + b2f(xb[row + 16 + m]);
      float v2 = acc[2][i] + b2v[2] + b2f(xb[row + 32 + m]);
      float v3 = acc[3][i] + b2v[3] + b2f(xb[row + 48 + m]);
      float sm = v0+v1+v2+v3;
      float sq = v0*v0+v1*v1+v2*v2+v3*v3;
      #pragma unroll
      for (int mk=1; mk<16; mk<<=1){ sm += __shfl_xor(sm, mk); sq += __shfl_xor(sq, mk); }
      float mean = sm*0.015625f;
      float var  = sq*0.015625f - mean*mean;
      float rs   = rsqrtf(var + 1e-5f);
      xb[row + m]      = f2b((v0-mean)*rs*g[0]+bb[0]);
      xb[row + 16 + m] = f2b((v1-mean)*rs*g[1]+bb[1]);
      xb[row + 32 + m] = f2b((v2-mean)*rs*g[2]+bb[2]);
      xb[row + 48 + m] = f2b((v3-mean)*rs*g[3]+bb[3]);
    }
  }
}

// ---------- heads: feat assembly ----------
__global__ __launch_bounds__(256) void k_feat(const unsigned short* __restrict__ xb,
    const float* __restrict__ obs, const int* __restrict__ agents,
    const float* __restrict__ Wr, const float* __restrict__ br,
    float* __restrict__ feat){
  __shared__ float s_xa[64];
  const int b = blockIdx.x, tid = threadIdx.x;
  if (tid < 64) s_xa[tid] = b2f(xb[(size_t)agents[b]*HD + tid]);
  __syncthreads();
  if (tid < AD){
    float a = br[tid];
    #pragma unroll 8
    for (int k=0;k<HD;k++) a = fmaf(s_xa[k], Wr[k*AD + tid], a);
    feat[(size_t)b*1536 + tid] = a;
  }
  for (int i=tid;i<OBSD;i+=256) feat[(size_t)b*1536 + AD + i] = obs[(size_t)b*OBSD + i];
  if (tid < 21) feat[(size_t)b*1536 + 1515 + tid] = 0.f;
}

// ---------- heads: split-K partial GEMM ----------
template<int ROWS, int COLS, int CH, int KS, int N>
__global__ __launch_bounds__(ROWS*COLS) void k_gemm_part(
    const float* __restrict__ A, int lda, int K,
    const float* __restrict__ W, float* __restrict__ part){
  constexpr int BT = ROWS*COLS;
  __shared__ float s_a[ROWS*CH];
  const int tid = threadIdx.x;
  const int ct = blockIdx.x, rg = blockIdx.y, ks = blockIdx.z;
  const int chunk = (K + KS - 1) / KS;
  const int k0 = ks * chunk;
  const int len = min(K - k0, chunk);
  const int row0 = rg * ROWS;
  #pragma unroll
  for (int rr=0; rr<ROWS; rr++)
    for (int i=tid; i<len; i+=BT)
      s_a[rr*CH + i] = A[(size_t)(row0+rr)*lda + k0 + i];
  __syncthreads();
  const int r = tid / COLS, c = tid % COLS;
  const float* wp = W + (size_t)k0*N + ct*COLS + c;
  const float* ap = s_a + r*CH;
  float acc = 0.f;
  #pragma unroll 8
  for (int k=0;k<len;k++) acc = fmaf(ap[k], wp[(size_t)k*N], acc);
  part[((size_t)ks*128 + row0 + r)*N + ct*COLS + c] = acc;
}

template<int KS, int N, bool TANH>
__global__ __launch_bounds__(256) void k_reduce(const float* __restrict__ part,
    const float* __restrict__ bias, float* __restrict__ out, int MN){
  const int idx = blockIdx.x*256 + threadIdx.x;
  if (idx >= MN) return;
  float s = bias[idx & (N-1)];
  #pragma unroll
  for (int ks=0;ks<KS;ks++) s += part[(size_t)ks*MN + idx];
  out[idx] = TANH ? tanhf(s) : s;
}

// ---------- heads: logits ----------
__global__ __launch_bounds__(256) void k_logits(const float* __restrict__ f2,
    const float* __restrict__ Wlog, const float* __restrict__ blog,
    float* __restrict__ out){
  __shared__ float s_f[512];
  __shared__ float s_p[16*AD];
  const int b = blockIdx.x, tid = threadIdx.x;
  s_f[tid]     = f2[(size_t)b*512 + tid];
  s_f[tid+256] = f2[(size_t)b*512 + 256 + tid];
  __syncthreads();
  if (tid < 240){
    int c = tid % AD, kc = tid / AD;
    float a = 0.f;
    #pragma unroll 8
    for (int j=0;j<32;j++){ int k = kc*32 + j; a = fmaf(s_f[k], Wlog[k*AD + c], a); }
    s_p[tid] = a;
  }
  __syncthreads();
  if (tid < AD){
    float a = blog[tid];
    #pragma unroll
    for (int kc=0;kc<16;kc++) a += s_p[kc*AD + tid];
    out[(size_t)b*AD + tid] = a;
  }
}

// ---------- heads: value finish ----------
__global__ __launch_bounds__(128) void k_vfin(const float* __restrict__ vh,
    const float* __restrict__ Wv2, const float* __restrict__ bv2,
    const float* __restrict__ Wvo, const float* __restrict__ bvo,
    float* __restrict__ out){
  __shared__ float s_v[128];
  __shared__ float s_r[128];
  const int b = blockIdx.x, tid = threadIdx.x;
  s_v[tid] = vh[(size_t)b*128 + tid];
  __syncthreads();
  float a = bv2[tid];
  #pragma unroll 8
  for (int k=0;k<128;k++) a = fmaf(s_v[k], Wv2[k*128 + tid], a);
  s_r[tid] = tanhf(a) * Wvo[tid];
  __syncthreads();
  if (tid < 64){
    float v = s_r[tid] + s_r[tid+64];
    #pragma unroll
    for (int m=32;m>=1;m>>=1) v += __shfl_xor(v, m);
    if (tid==0) out[GRAPHS*AD + b] = v + bvo[0];
  }
}

// ---------- launch ----------
extern "C" void kernel_launch(void* const* d_in, const int* in_sizes, int n_in,
                              void* d_out, int out_size, void* d_ws, size_t ws_size,
                              hipStream_t stream) {
  (void)in_sizes; (void)n_in; (void)out_size; (void)ws_size;
  const float* nf     = (const float*)d_in[0];
  const float* obs    = (const float*)d_in[1];
  const int*   esrc   = (const int*)d_in[2];
  const int*   edst   = (const int*)d_in[3];
  const int*   agents = (const int*)d_in[4];
  const float* Win    = (const float*)d_in[5];
  const float* Wq     = (const float*)d_in[6];
  const float* Wk     = (const float*)d_in[7];
  const float* Wv     = (const float*)d_in[8];
  const float* Wo     = (const float*)d_in[9];
  const float* ln1g   = (const float*)d_in[10];
  const float* ln1b   = (const float*)d_in[11];
  const float* W1     = (const float*)d_in[12];
  const float* b1     = (const float*)d_in[13];
  const float* W2     = (const float*)d_in[14];
  const float* b2     = (const float*)d_in[15];
  const float* ln2g   = (const float*)d_in[16];
  const float* ln2b   = (const float*)d_in[17];
  const float* Wr     = (const float*)d_in[18];
  const float* br     = (const float*)d_in[19];
  const float* Wp1    = (const float*)d_in[20];
  const float* bp1    = (const float*)d_in[21];
  const float* Wp2    = (const float*)d_in[22];
  const float* bp2    = (const float*)d_in[23];
  const float* Wlog   = (const float*)d_in[24];
  const float* blog   = (const float*)d_in[25];
  const float* Wv1    = (const float*)d_in[26];
  const float* bv1    = (const float*)d_in[27];
  const float* Wv2    = (const float*)d_in[28];
  const float* bv2    = (const float*)d_in[29];
  const float* Wvo    = (const float*)d_in[30];
  const float* bvo    = (const float*)d_in[31];
  float* out = (float*)d_out;

  // workspace layout (all bf16 activations)
  unsigned short* xb      = (unsigned short*)d_ws;             // TOTN*64 bf16
  unsigned short* qkv     = xb + (size_t)TOTN*HD;              // TOTN*192 bf16
  unsigned short* hbuf    = qkv;                               // ffn intermediate aliases qkv
  unsigned short* attn_in = qkv + (size_t)TOTN*192;            // TOTN*64 bf16
  unsigned short* wpack   = attn_in + (size_t)TOTN*HD;         // 131072 bf16
  int* cnt     = (int*)(wpack + 131072);                       // TOTN
  int* rstart  = cnt + TOTN;
  int* cursor  = rstart + TOTN;
  int* esorted = cursor + TOTN;                                // TOTE
  // head buffers (float) after the int region
  float* feat = (float*)(esorted + TOTE);                      // 128*1536
  float* f1   = feat + 128*1536;
  float* f2   = f1 + 128*512;
  float* vh   = f2 + 128*512;
  float* part = vh + 128*128;                                  // up to 4*128*512

  // weight prep + CSR build (edge topology is layer-invariant)
  k_wprep  <<<512, 256, 0, stream>>>(Wq, Wk, Wv, Wo, W1, W2, wpack);
  k_zero   <<<TOTN/256, 256, 0, stream>>>(cnt);
  k_hist   <<<TOTE/256, 256, 0, stream>>>(edst, cnt);
  k_scan   <<<GRAPHS, 1024, 0, stream>>>(cnt, rstart, cursor);
  k_scatter<<<TOTE/256, 256, 0, stream>>>(esrc, edst, cursor, esorted);

  k_in<<<TOTN/256, 256, 0, stream>>>(nf, Win, xb);
  for (int l=0; l<4; l++){
    const unsigned short* wl = wpack + l*32768;
    k_qkv_m <<<TOTN/256, 256, 0, stream>>>(xb, wl, qkv);
    k_edge2 <<<TOTN/16, 256, 0, stream>>>(qkv, rstart, cnt, esorted, attn_in);
    k_attn_m<<<TOTN/256, 256, 0, stream>>>(attn_in, wl + 12288,
                                           ln1g + l*64, ln1b + l*64, xb);
    k_ffn1_m<<<TOTN/256, 256, 0, stream>>>(xb, wl + 16384, b1 + l*128, hbuf);
    k_ffn2_m<<<TOTN/256, 256, 0, stream>>>(hbuf, wl + 24576, b2 + l*64,
                                           ln2g + l*64, ln2b + l*64, xb);
  }
  // policy head
  k_feat<<<GRAPHS, 256, 0, stream>>>(xb, obs, agents, Wr, br, feat);
  k_gemm_part<2,256,384,4,512><<<dim3(2,64,4), 512, 0, stream>>>(feat, 1536, 1515, Wp1, part);
  k_reduce<4,512,true><<<256, 256, 0, stream>>>(part, bp1, f1, 128*512);
  k_gemm_part<2,256,256,2,512><<<dim3(2,64,2), 512, 0, stream>>>(f1, 512, 512, Wp2, part);
  k_reduce<2,512,true><<<256, 256, 0, stream>>>(part, bp2, f2, 128*512);
  k_logits<<<GRAPHS, 256, 0, stream>>>(f2, Wlog, blog, out);
  // value head
  k_gemm_part<4,128,192,8,128><<<dim3(1,32,8), 512, 0, stream>>>(obs, 1500, 1500, Wv1, part);
  k_reduce<8,128,true><<<64, 256, 0, stream>>>(part, bv1, vh, 128*128);
  k_vfin<<<GRAPHS, 128, 0, stream>>>(vh, Wv2, bv2, Wvo, bvo, out);
}

// Round 6
// 579.186 us; speedup vs baseline: 3.3939x; 1.0585x over previous
//
#include <hip/hip_runtime.h>
#include <hip/hip_bf16.h>
#include <cstdint>
#include <cstddef>

#define DEV static __device__ __forceinline__

constexpr int GRAPHS = 128;
constexpr int NPG    = 1000;   // nodes per graph
constexpr int EPG    = 4000;   // edges per graph
constexpr int TOTN   = GRAPHS * NPG;  // 128000
constexpr int TOTE   = GRAPHS * EPG;  // 512000
constexpr int HD     = 64;
constexpr int OBSD   = 1500;
constexpr int AD     = 15;

typedef __attribute__((ext_vector_type(8))) short bf16x8;
typedef __attribute__((ext_vector_type(4))) float f32x4;

// ---------- helpers ----------
DEV unsigned short f2b(float f){   // round-to-nearest-even bf16
  unsigned u = __float_as_uint(f);
  return (unsigned short)((u + 0x7fffu + ((u >> 16) & 1u)) >> 16);
}
DEV float b2f(unsigned short s){ return __uint_as_float((unsigned)s << 16); }

DEV void fma4(float4& a, float s, const float4 w){
  a.x = fmaf(s, w.x, a.x); a.y = fmaf(s, w.y, a.y);
  a.z = fmaf(s, w.z, a.z); a.w = fmaf(s, w.w, a.w);
}

DEV ushort4 pack4(float4 v){
  ushort4 r; r.x=f2b(v.x); r.y=f2b(v.y); r.z=f2b(v.z); r.w=f2b(v.w); return r;
}

// ---------- weight prep: pack all layer weights to bf16 W^T ----------
// per layer (stride 32768 bf16): qkvT[192][64] | woT[64][64] | w1T[128][64] | w2T[64][128]
__global__ __launch_bounds__(256) void k_wprep(const float* __restrict__ Wq,
    const float* __restrict__ Wk, const float* __restrict__ Wv,
    const float* __restrict__ Wo, const float* __restrict__ W1,
    const float* __restrict__ W2, unsigned short* __restrict__ wpack){
  int e = blockIdx.x*256 + threadIdx.x;
  int l = e >> 15;
  int r = e & 32767;
  float val;
  if (r < 12288){
    int c = r >> 6, k = r & 63;
    val = (c < 64)  ? Wq[l*4096 + k*64 + c]
        : (c < 128) ? Wk[l*4096 + k*64 + (c-64)]
                    : Wv[l*4096 + k*64 + (c-128)];
  } else if (r < 16384){
    int i = r - 12288; int c = i >> 6, k = i & 63;
    val = Wo[l*4096 + k*64 + c];
  } else if (r < 24576){
    int i = r - 16384; int c = i >> 6, k = i & 63;
    val = W1[l*8192 + k*128 + c];
  } else {
    int i = r - 24576; int c = i >> 7, k = i & 127;
    val = W2[l*8192 + k*64 + c];
  }
  wpack[e] = f2b(val);
}

// ---------- CSR build (once per call; reused by all 4 layers) ----------
__global__ __launch_bounds__(256) void k_zero(int* __restrict__ cnt){
  cnt[blockIdx.x*256 + threadIdx.x] = 0;
}

__global__ __launch_bounds__(256) void k_hist(const int* __restrict__ edst,
                                              int* __restrict__ cnt){
  int e = blockIdx.x*256 + threadIdx.x;
  atomicAdd(&cnt[edst[e]], 1);
}

__global__ __launch_bounds__(1024) void k_scan(const int* __restrict__ cnt,
    int* __restrict__ rstart, int* __restrict__ cursor){
  __shared__ int s[1024];
  const int g = blockIdx.x, tid = threadIdx.x;
  int v = (tid < NPG) ? cnt[g*NPG + tid] : 0;
  s[tid] = v;
  __syncthreads();
  #pragma unroll
  for (int off=1; off<1024; off<<=1){
    int t = (tid >= off) ? s[tid-off] : 0;
    __syncthreads();
    s[tid] += t;
    __syncthreads();
  }
  if (tid < NPG){
    int r = g*EPG + (s[tid] - v);
    rstart[g*NPG+tid] = r;
    cursor[g*NPG+tid] = r;
  }
}

__global__ __launch_bounds__(256) void k_scatter(const int* __restrict__ esrc,
    const int* __restrict__ edst, int* __restrict__ cursor,
    int* __restrict__ esorted){
  int e = blockIdx.x*256 + threadIdx.x;
  int pos = atomicAdd(&cursor[edst[e]], 1);
  esorted[pos] = esrc[e];
}

// ---------- K1: x(bf16) = node_feats @ W_in  [128000,32]x[32,64] ----------
__global__ __launch_bounds__(256) void k_in(const float* __restrict__ nf,
                                            const float* __restrict__ Win,
                                            unsigned short* __restrict__ xb){
  __shared__ float  s_nf[256*36];
  __shared__ float4 s_w[512];
  const int tid = threadIdx.x;
  const int node0 = blockIdx.x * 256;
  const float4* W4 = (const float4*)Win;
  s_w[tid] = W4[tid]; s_w[tid+256] = W4[tid+256];
  const float4* nf4 = (const float4*)nf;
  float4* snf4 = (float4*)s_nf;
  #pragma unroll
  for (int r=0;r<8;r++){
    int i = tid + 256*r; int n = i>>3, k4 = i&7;
    snf4[n*9 + k4] = nf4[(size_t)(node0+n)*8 + k4];
  }
  __syncthreads();
  const int ng = tid>>2, cg = tid&3;
  float4 acc[4][4];
  #pragma unroll
  for (int i=0;i<4;i++){ acc[i][0]=make_float4(0,0,0,0); acc[i][1]=make_float4(0,0,0,0);
                         acc[i][2]=make_float4(0,0,0,0); acc[i][3]=make_float4(0,0,0,0); }
  #pragma unroll 4
  for (int k=0;k<32;k++){
    float nv[4];
    #pragma unroll
    for (int i=0;i<4;i++) nv[i] = s_nf[(ng + 64*i)*36 + k];
    float4 w[4];
    #pragma unroll
    for (int j=0;j<4;j++) w[j] = s_w[k*16 + cg*4 + j];
    #pragma unroll
    for (int i=0;i<4;i++){
      #pragma unroll
      for (int j=0;j<4;j++) fma4(acc[i][j], nv[i], w[j]);
    }
  }
  ushort4* xb4 = (ushort4*)xb;
  #pragma unroll
  for (int i=0;i<4;i++){
    size_t nidx = (size_t)(node0 + ng + 64*i) * 16;
    #pragma unroll
    for (int j=0;j<4;j++) xb4[nidx + cg*4 + j] = pack4(acc[i][j]);
  }
}

// ---------- K2 (MFMA): qkv(bf16) = x @ [Wq|Wk|Wv], 256 nodes/block ----------
// Epilogue staged through per-wave LDS for coalesced dwordx4 stores.
__global__ __launch_bounds__(256) void k_qkv_m(const unsigned short* __restrict__ xb,
    const unsigned short* __restrict__ wqkvT,   // [192][64] bf16
    unsigned short* __restrict__ qkv){
  __shared__ short s_w[192*72];        // 27.6KB
  __shared__ short s_st[4][16*200];    // 25.6KB; row pitch 200 (400B, 16B-aligned)
  const int tid = threadIdx.x;
  const int node0 = blockIdx.x * 256;
  {
    const unsigned* src = (const unsigned*)wqkvT;
    unsigned* dst = (unsigned*)s_w;
    #pragma unroll
    for (int r=0;r<24;r++){
      int j = tid + 256*r;
      int c = j >> 5, kk = j & 31;
      dst[c*36 + kk] = src[j];
    }
  }
  __syncthreads();
  const int lane = tid & 63, wave = tid >> 6;
  const int m = lane & 15, quad = lane >> 4;
  const int rowbase = node0 + wave*64;
  bf16x8 af[4][2];
  #pragma unroll
  for (int rt=0;rt<4;rt++){
    const unsigned short* xp = xb + (size_t)(rowbase + rt*16 + m)*64 + quad*8;
    af[rt][0] = *(const bf16x8*)xp;
    af[rt][1] = *(const bf16x8*)(xp + 32);
  }
  short* st = s_st[wave];
  #pragma unroll
  for (int rt=0;rt<4;rt++){
    #pragma unroll
    for (int ct=0;ct<12;ct++){
      bf16x8 b0 = *(const bf16x8*)&s_w[(ct*16+m)*72 + quad*8];
      bf16x8 b1 = *(const bf16x8*)&s_w[(ct*16+m)*72 + 32 + quad*8];
      f32x4 acc = {0.f,0.f,0.f,0.f};
      acc = __builtin_amdgcn_mfma_f32_16x16x32_bf16(af[rt][0], b0, acc, 0,0,0);
      acc = __builtin_amdgcn_mfma_f32_16x16x32_bf16(af[rt][1], b1, acc, 0,0,0);
      #pragma unroll
      for (int i=0;i<4;i++)
        st[(quad*4+i)*200 + ct*16 + m] = (short)f2b(acc[i]);
    }
    // coalesced writeout: 16 rows x 192 cols, contiguous in qkv
    #pragma unroll
    for (int j=0;j<6;j++){
      int flat = (j*64 + lane)*8;
      int r = flat / 192, c = flat % 192;
      bf16x8 v = *(const bf16x8*)&st[r*200 + c];
      *(bf16x8*)(qkv + (size_t)(rowbase + rt*16 + r)*192 + c) = v;
    }
  }
}

// ---------- K4: edge attention via CSR gather; XCD-swizzled ----------
__global__ __launch_bounds__(256) void k_edge2(const unsigned short* __restrict__ qkv,
    const int* __restrict__ rstart, const int* __restrict__ cnt,
    const int* __restrict__ esorted, unsigned short* __restrict__ attn_in){
  const int tid = threadIdx.x;
  const int wb = (blockIdx.x & 7)*1000 + (blockIdx.x >> 3);
  const int lane = tid & 63;
  const int sub  = lane >> 4;
  const int dg   = lane & 15;
  const int wave = tid >> 6;
  const int node = wb*16 + wave*4 + sub;
  const ushort4* row = (const ushort4*)(qkv + (size_t)node*192);
  ushort4 qu = row[dg];
  float q0 = b2f(qu.x), q1 = b2f(qu.y), q2 = b2f(qu.z), q3 = b2f(qu.w);
  const int rs = rstart[node];
  const int n  = cnt[node];
  float a0=0.f, a1=0.f, a2=0.f, a3=0.f, den=0.f;
  for (int i=0;i<n;i++){
    int src = esorted[rs + i];
    ushort4 ku = *(const ushort4*)(qkv + (size_t)src*192 + 64 + dg*4);
    ushort4 vu = *(const ushort4*)(qkv + (size_t)src*192 + 128 + dg*4);
    float p = q0*b2f(ku.x) + q1*b2f(ku.y) + q2*b2f(ku.z) + q3*b2f(ku.w);
    p += __shfl_xor(p, 1);
    p += __shfl_xor(p, 2);          // sum over the 4 lanes of this head
    float w = __expf(p * 0.25f);    // softmax shift-invariant; skip segment_max
    den += w;
    a0 = fmaf(w, b2f(vu.x), a0);
    a1 = fmaf(w, b2f(vu.y), a1);
    a2 = fmaf(w, b2f(vu.z), a2);
    a3 = fmaf(w, b2f(vu.w), a3);
  }
  float inv = 1.0f/(den + 1e-9f);
  ushort4 o;
  o.x = f2b(a0*inv); o.y = f2b(a1*inv); o.z = f2b(a2*inv); o.w = f2b(a3*inv);
  ((ushort4*)attn_in)[(size_t)node*16 + dg] = o;
}

// ---------- K5 (MFMA): x = LN(x + attn_in @ Wo), 256 nodes/block ----------
__global__ __launch_bounds__(256) void k_attn_m(const unsigned short* __restrict__ attn_in,
    const unsigned short* __restrict__ woT, const float* __restrict__ lg,
    const float* __restrict__ lb, unsigned short* __restrict__ xb){
  __shared__ short s_w[64*72];        // 9.2KB
  __shared__ short s_st[4][16*72];    // 9.2KB
  const int tid = threadIdx.x;
  const int node0 = blockIdx.x*256;
  {
    const unsigned* src = (const unsigned*)woT;
    unsigned* dst = (unsigned*)s_w;
    #pragma unroll
    for (int r=0;r<8;r++){
      int j = tid + 256*r;
      int c = j >> 5, kk = j & 31;
      dst[c*36 + kk] = src[j];
    }
  }
  __syncthreads();
  const int lane = tid&63, wave = tid>>6;
  const int m = lane&15, quad = lane>>4;
  const int rowbase = node0 + wave*64;
  bf16x8 bf[4][2];
  #pragma unroll
  for (int ct=0;ct<4;ct++){
    bf[ct][0] = *(const bf16x8*)&s_w[(ct*16+m)*72 + quad*8];
    bf[ct][1] = *(const bf16x8*)&s_w[(ct*16+m)*72 + 32 + quad*8];
  }
  float g[4], bb[4];
  #pragma unroll
  for (int ct=0;ct<4;ct++){ g[ct]=lg[ct*16+m]; bb[ct]=lb[ct*16+m]; }
  short* st = s_st[wave];
  #pragma unroll
  for (int rt=0;rt<4;rt++){
    const unsigned short* ap = attn_in + (size_t)(rowbase + rt*16 + m)*64 + quad*8;
    bf16x8 a0 = *(const bf16x8*)ap;
    bf16x8 a1 = *(const bf16x8*)(ap + 32);
    f32x4 acc[4];
    #pragma unroll
    for (int ct=0;ct<4;ct++){
      f32x4 z = {0.f,0.f,0.f,0.f};
      z = __builtin_amdgcn_mfma_f32_16x16x32_bf16(a0, bf[ct][0], z, 0,0,0);
      z = __builtin_amdgcn_mfma_f32_16x16x32_bf16(a1, bf[ct][1], z, 0,0,0);
      acc[ct] = z;
    }
    #pragma unroll
    for (int i=0;i<4;i++){
      size_t row = (size_t)(rowbase + rt*16 + quad*4 + i)*64;
      float v0 = acc[0][i] + b2f(xb[row + m]);
      float v1 = acc[1][i] + b2f(xb[row + 16 + m]);
      float v2 = acc[2][i] + b2f(xb[row + 32 + m]);
      float v3 = acc[3][i] + b2f(xb[row + 48 + m]);
      float sm = v0+v1+v2+v3;
      float sq = v0*v0+v1*v1+v2*v2+v3*v3;
      #pragma unroll
      for (int mk=1; mk<16; mk<<=1){ sm += __shfl_xor(sm, mk); sq += __shfl_xor(sq, mk); }
      float mean = sm*0.015625f;
      float var  = sq*0.015625f - mean*mean;
      float rs   = rsqrtf(var + 1e-5f);
      int rl = quad*4 + i;
      st[rl*72 + m]      = (short)f2b((v0-mean)*rs*g[0]+bb[0]);
      st[rl*72 + 16 + m] = (short)f2b((v1-mean)*rs*g[1]+bb[1]);
      st[rl*72 + 32 + m] = (short)f2b((v2-mean)*rs*g[2]+bb[2]);
      st[rl*72 + 48 + m] = (short)f2b((v3-mean)*rs*g[3]+bb[3]);
    }
    #pragma unroll
    for (int j=0;j<2;j++){
      int flat = (j*64 + lane)*8;
      int r = flat >> 6, c = flat & 63;
      bf16x8 v = *(const bf16x8*)&st[r*72 + c];
      *(bf16x8*)(xb + (size_t)(rowbase + rt*16 + r)*64 + c) = v;
    }
  }
}

// ---------- K6 (MFMA): h(bf16) = relu(x @ W1 + b1), 256 nodes/block ----------
__global__ __launch_bounds__(256) void k_ffn1_m(const unsigned short* __restrict__ xb,
    const unsigned short* __restrict__ w1T, const float* __restrict__ b1_l,
    unsigned short* __restrict__ h){
  __shared__ short s_w[128*72];       // 18.4KB
  __shared__ short s_st[4][16*136];   // 17.4KB; pitch 136 (272B, 16B-aligned)
  const int tid = threadIdx.x;
  const int node0 = blockIdx.x*256;
  {
    const unsigned* src = (const unsigned*)w1T;
    unsigned* dst = (unsigned*)s_w;
    #pragma unroll
    for (int r=0;r<16;r++){
      int j = tid + 256*r;
      int c = j >> 5, kk = j & 31;
      dst[c*36 + kk] = src[j];
    }
  }
  __syncthreads();
  const int lane = tid&63, wave = tid>>6;
  const int m = lane&15, quad = lane>>4;
  const int rowbase = node0 + wave*64;
  bf16x8 af[4][2];
  #pragma unroll
  for (int rt=0;rt<4;rt++){
    const unsigned short* xp = xb + (size_t)(rowbase + rt*16 + m)*64 + quad*8;
    af[rt][0] = *(const bf16x8*)xp;
    af[rt][1] = *(const bf16x8*)(xp + 32);
  }
  short* st = s_st[wave];
  #pragma unroll
  for (int rt=0;rt<4;rt++){
    #pragma unroll
    for (int ct=0;ct<8;ct++){
      bf16x8 b0 = *(const bf16x8*)&s_w[(ct*16+m)*72 + quad*8];
      bf16x8 b1 = *(const bf16x8*)&s_w[(ct*16+m)*72 + 32 + quad*8];
      float bias = b1_l[ct*16+m];
      f32x4 acc = {0.f,0.f,0.f,0.f};
      acc = __builtin_amdgcn_mfma_f32_16x16x32_bf16(af[rt][0], b0, acc, 0,0,0);
      acc = __builtin_amdgcn_mfma_f32_16x16x32_bf16(af[rt][1], b1, acc, 0,0,0);
      #pragma unroll
      for (int i=0;i<4;i++)
        st[(quad*4+i)*136 + ct*16 + m] = (short)f2b(fmaxf(acc[i]+bias, 0.f));
    }
    #pragma unroll
    for (int j=0;j<4;j++){
      int flat = (j*64 + lane)*8;
      int r = flat >> 7, c = flat & 127;
      bf16x8 v = *(const bf16x8*)&st[r*136 + c];
      *(bf16x8*)(h + (size_t)(rowbase + rt*16 + r)*128 + c) = v;
    }
  }
}

// ---------- K7 (MFMA): x = LN(x + h @ W2 + b2), 256 nodes/block ----------
__global__ __launch_bounds__(256) void k_ffn2_m(const unsigned short* __restrict__ h,
    const unsigned short* __restrict__ w2T, const float* __restrict__ b2_l,
    const float* __restrict__ lg, const float* __restrict__ lb,
    unsigned short* __restrict__ xb){
  __shared__ short s_w[64*136];       // 17.4KB
  __shared__ short s_st[4][16*72];    // 9.2KB
  const int tid = threadIdx.x;
  const int node0 = blockIdx.x*256;
  {
    const unsigned* src = (const unsigned*)w2T;
    unsigned* dst = (unsigned*)s_w;
    #pragma unroll
    for (int r=0;r<16;r++){
      int j = tid + 256*r;
      int c = j >> 6, kk = j & 63;
      dst[c*68 + kk] = src[j];
    }
  }
  __syncthreads();
  const int lane = tid&63, wave = tid>>6;
  const int m = lane&15, quad = lane>>4;
  const int rowbase = node0 + wave*64;
  bf16x8 bf[4][4];
  #pragma unroll
  for (int ct=0;ct<4;ct++){
    #pragma unroll
    for (int kc=0;kc<4;kc++)
      bf[ct][kc] = *(const bf16x8*)&s_w[(ct*16+m)*136 + kc*32 + quad*8];
  }
  float g[4], bb[4], b2v[4];
  #pragma unroll
  for (int ct=0;ct<4;ct++){ g[ct]=lg[ct*16+m]; bb[ct]=lb[ct*16+m]; b2v[ct]=b2_l[ct*16+m]; }
  short* st = s_st[wave];
  #pragma unroll
  for (int rt=0;rt<4;rt++){
    const unsigned short* ap = h + (size_t)(rowbase + rt*16 + m)*128 + quad*8;
    bf16x8 a0 = *(const bf16x8*)ap;
    bf16x8 a1 = *(const bf16x8*)(ap + 32);
    bf16x8 a2 = *(const bf16x8*)(ap + 64);
    bf16x8 a3 = *(const bf16x8*)(ap + 96);
    f32x4 acc[4];
    #pragma unroll
    for (int ct=0;ct<4;ct++){
      f32x4 z = {0.f,0.f,0.f,0.f};
      z = __builtin_amdgcn_mfma_f32_16x16x32_bf16(a0, bf[ct][0], z, 0,0,0);
      z = __builtin_amdgcn_mfma_f32_16x16x32_bf16(a1, bf[ct][1], z, 0,0,0);
      z = __builtin_amdgcn_mfma_f32_16x16x32_bf16(a2, bf[ct][2], z, 0,0,0);
      z = __builtin_amdgcn_mfma_f32_16x16x32_bf16(a3, bf[ct][3], z, 0,0,0);
      acc[ct] = z;
    }
    #pragma unroll
    for (int i=0;i<4;i++){
      size_t row = (size_t)(rowbase + rt*16 + quad*4 + i)*64;
      float v0 = acc[0][i] + b2v[0] + b2f(xb[row + m]);
      float v1 = acc[1][i] + b2v[1] + b2f(xb[row + 16 + m]);
      float v2 = acc[2][i] + b2v[2] + b2f(xb[row + 32 + m]);
      float v3 = acc[3][i] + b2v[3] + b2f(xb[row + 48 + m]);
      float sm = v0+v1+v2+v3;
      float sq = v0*v0+v1*v1+v2*v2+v3*v3;
      #pragma unroll
      for (int mk=1; mk<16; mk<<=1){ sm += __shfl_xor(sm, mk); sq += __shfl_xor(sq, mk); }
      float mean = sm*0.015625f;
      float var  = sq*0.015625f - mean*mean;
      float rs   = rsqrtf(var + 1e-5f);
      int rl = quad*4 + i;
      st[rl*72 + m]      = (short)f2b((v0-mean)*rs*g[0]+bb[0]);
      st[rl*72 + 16 + m] = (short)f2b((v1-mean)*rs*g[1]+bb[1]);
      st[rl*72 + 32 + m] = (short)f2b((v2-mean)*rs*g[2]+bb[2]);
      st[rl*72 + 48 + m] = (short)f2b((v3-mean)*rs*g[3]+bb[3]);
    }
    #pragma unroll
    for (int j=0;j<2;j++){
      int flat = (j*64 + lane)*8;
      int r = flat >> 6, c = flat & 63;
      bf16x8 v = *(const bf16x8*)&st[r*72 + c];
      *(bf16x8*)(xb + (size_t)(rowbase + rt*16 + r)*64 + c) = v;
    }
  }
}

// ---------- heads: feat assembly ----------
__global__ __launch_bounds__(256) void k_feat(const unsigned short* __restrict__ xb,
    const float* __restrict__ obs, const int* __restrict__ agents,
    const float* __restrict__ Wr, const float* __restrict__ br,
    float* __restrict__ feat){
  __shared__ float s_xa[64];
  const int b = blockIdx.x, tid = threadIdx.x;
  if (tid < 64) s_xa[tid] = b2f(xb[(size_t)agents[b]*HD + tid]);
  __syncthreads();
  if (tid < AD){
    float a = br[tid];
    #pragma unroll 8
    for (int k=0;k<HD;k++) a = fmaf(s_xa[k], Wr[k*AD + tid], a);
    feat[(size_t)b*1536 + tid] = a;
  }
  for (int i=tid;i<OBSD;i+=256) feat[(size_t)b*1536 + AD + i] = obs[(size_t)b*OBSD + i];
  if (tid < 21) feat[(size_t)b*1536 + 1515 + tid] = 0.f;
}

// ---------- heads: split-K partial GEMM ----------
template<int ROWS, int COLS, int CH, int KS, int N>
__global__ __launch_bounds__(ROWS*COLS) void k_gemm_part(
    const float* __restrict__ A, int lda, int K,
    const float* __restrict__ W, float* __restrict__ part){
  constexpr int BT = ROWS*COLS;
  __shared__ float s_a[ROWS*CH];
  const int tid = threadIdx.x;
  const int ct = blockIdx.x, rg = blockIdx.y, ks = blockIdx.z;
  const int chunk = (K + KS - 1) / KS;
  const int k0 = ks * chunk;
  const int len = min(K - k0, chunk);
  const int row0 = rg * ROWS;
  #pragma unroll
  for (int rr=0; rr<ROWS; rr++)
    for (int i=tid; i<len; i+=BT)
      s_a[rr*CH + i] = A[(size_t)(row0+rr)*lda + k0 + i];
  __syncthreads();
  const int r = tid / COLS, c = tid % COLS;
  const float* wp = W + (size_t)k0*N + ct*COLS + c;
  const float* ap = s_a + r*CH;
  float acc = 0.f;
  #pragma unroll 8
  for (int k=0;k<len;k++) acc = fmaf(ap[k], wp[(size_t)k*N], acc);
  part[((size_t)ks*128 + row0 + r)*N + ct*COLS + c] = acc;
}

template<int KS, int N, bool TANH>
__global__ __launch_bounds__(256) void k_reduce(const float* __restrict__ part,
    const float* __restrict__ bias, float* __restrict__ out, int MN){
  const int idx = blockIdx.x*256 + threadIdx.x;
  if (idx >= MN) return;
  float s = bias[idx & (N-1)];
  #pragma unroll
  for (int ks=0;ks<KS;ks++) s += part[(size_t)ks*MN + idx];
  out[idx] = TANH ? tanhf(s) : s;
}

// ---------- heads: logits ----------
__global__ __launch_bounds__(256) void k_logits(const float* __restrict__ f2,
    const float* __restrict__ Wlog, const float* __restrict__ blog,
    float* __restrict__ out){
  __shared__ float s_f[512];
  __shared__ float s_p[16*AD];
  const int b = blockIdx.x, tid = threadIdx.x;
  s_f[tid]     = f2[(size_t)b*512 + tid];
  s_f[tid+256] = f2[(size_t)b*512 + 256 + tid];
  __syncthreads();
  if (tid < 240){
    int c = tid % AD, kc = tid / AD;
    float a = 0.f;
    #pragma unroll 8
    for (int j=0;j<32;j++){ int k = kc*32 + j; a = fmaf(s_f[k], Wlog[k*AD + c], a); }
    s_p[tid] = a;
  }
  __syncthreads();
  if (tid < AD){
    float a = blog[tid];
    #pragma unroll
    for (int kc=0;kc<16;kc++) a += s_p[kc*AD + tid];
    out[(size_t)b*AD + tid] = a;
  }
}

// ---------- heads: value finish ----------
__global__ __launch_bounds__(128) void k_vfin(const float* __restrict__ vh,
    const float* __restrict__ Wv2, const float* __restrict__ bv2,
    const float* __restrict__ Wvo, const float* __restrict__ bvo,
    float* __restrict__ out){
  __shared__ float s_v[128];
  __shared__ float s_r[128];
  const int b = blockIdx.x, tid = threadIdx.x;
  s_v[tid] = vh[(size_t)b*128 + tid];
  __syncthreads();
  float a = bv2[tid];
  #pragma unroll 8
  for (int k=0;k<128;k++) a = fmaf(s_v[k], Wv2[k*128 + tid], a);
  s_r[tid] = tanhf(a) * Wvo[tid];
  __syncthreads();
  if (tid < 64){
    float v = s_r[tid] + s_r[tid+64];
    #pragma unroll
    for (int m=32;m>=1;m>>=1) v += __shfl_xor(v, m);
    if (tid==0) out[GRAPHS*AD + b] = v + bvo[0];
  }
}

// ---------- launch ----------
extern "C" void kernel_launch(void* const* d_in, const int* in_sizes, int n_in,
                              void* d_out, int out_size, void* d_ws, size_t ws_size,
                              hipStream_t stream) {
  (void)in_sizes; (void)n_in; (void)out_size; (void)ws_size;
  const float* nf     = (const float*)d_in[0];
  const float* obs    = (const float*)d_in[1];
  const int*   esrc   = (const int*)d_in[2];
  const int*   edst   = (const int*)d_in[3];
  const int*   agents = (const int*)d_in[4];
  const float* Win    = (const float*)d_in[5];
  const float* Wq     = (const float*)d_in[6];
  const float* Wk     = (const float*)d_in[7];
  const float* Wv     = (const float*)d_in[8];
  const float* Wo     = (const float*)d_in[9];
  const float* ln1g   = (const float*)d_in[10];
  const float* ln1b   = (const float*)d_in[11];
  const float* W1     = (const float*)d_in[12];
  const float* b1     = (const float*)d_in[13];
  const float* W2     = (const float*)d_in[14];
  const float* b2     = (const float*)d_in[15];
  const float* ln2g   = (const float*)d_in[16];
  const float* ln2b   = (const float*)d_in[17];
  const float* Wr     = (const float*)d_in[18];
  const float* br     = (const float*)d_in[19];
  const float* Wp1    = (const float*)d_in[20];
  const float* bp1    = (const float*)d_in[21];
  const float* Wp2    = (const float*)d_in[22];
  const float* bp2    = (const float*)d_in[23];
  const float* Wlog   = (const float*)d_in[24];
  const float* blog   = (const float*)d_in[25];
  const float* Wv1    = (const float*)d_in[26];
  const float* bv1    = (const float*)d_in[27];
  const float* Wv2    = (const float*)d_in[28];
  const float* bv2    = (const float*)d_in[29];
  const float* Wvo    = (const float*)d_in[30];
  const float* bvo    = (const float*)d_in[31];
  float* out = (float*)d_out;

  // workspace layout (all bf16 activations)
  unsigned short* xb      = (unsigned short*)d_ws;             // TOTN*64 bf16
  unsigned short* qkv     = xb + (size_t)TOTN*HD;              // TOTN*192 bf16
  unsigned short* hbuf    = qkv;                               // ffn intermediate aliases qkv
  unsigned short* attn_in = qkv + (size_t)TOTN*192;            // TOTN*64 bf16
  unsigned short* wpack   = attn_in + (size_t)TOTN*HD;         // 131072 bf16
  int* cnt     = (int*)(wpack + 131072);                       // TOTN
  int* rstart  = cnt + TOTN;
  int* cursor  = rstart + TOTN;
  int* esorted = cursor + TOTN;                                // TOTE
  // head buffers (float) after the int region
  float* feat = (float*)(esorted + TOTE);                      // 128*1536
  float* f1   = feat + 128*1536;
  float* f2   = f1 + 128*512;
  float* vh   = f2 + 128*512;
  float* part = vh + 128*128;                                  // up to 4*128*512

  // weight prep + CSR build (edge topology is layer-invariant)
  k_wprep  <<<512, 256, 0, stream>>>(Wq, Wk, Wv, Wo, W1, W2, wpack);
  k_zero   <<<TOTN/256, 256, 0, stream>>>(cnt);
  k_hist   <<<TOTE/256, 256, 0, stream>>>(edst, cnt);
  k_scan   <<<GRAPHS, 1024, 0, stream>>>(cnt, rstart, cursor);
  k_scatter<<<TOTE/256, 256, 0, stream>>>(esrc, edst, cursor, esorted);

  k_in<<<TOTN/256, 256, 0, stream>>>(nf, Win, xb);
  for (int l=0; l<4; l++){
    const unsigned short* wl = wpack + l*32768;
    k_qkv_m <<<TOTN/256, 256, 0, stream>>>(xb, wl, qkv);
    k_edge2 <<<TOTN/16, 256, 0, stream>>>(qkv, rstart, cnt, esorted, attn_in);
    k_attn_m<<<TOTN/256, 256, 0, stream>>>(attn_in, wl + 12288,
                                           ln1g + l*64, ln1b + l*64, xb);
    k_ffn1_m<<<TOTN/256, 256, 0, stream>>>(xb, wl + 16384, b1 + l*128, hbuf);
    k_ffn2_m<<<TOTN/256, 256, 0, stream>>>(hbuf, wl + 24576, b2 + l*64,
                                           ln2g + l*64, ln2b + l*64, xb);
  }
  // policy head
  k_feat<<<GRAPHS, 256, 0, stream>>>(xb, obs, agents, Wr, br, feat);
  k_gemm_part<2,256,384,4,512><<<dim3(2,64,4), 512, 0, stream>>>(feat, 1536, 1515, Wp1, part);
  k_reduce<4,512,true><<<256, 256, 0, stream>>>(part, bp1, f1, 128*512);
  k_gemm_part<2,256,256,2,512><<<dim3(2,64,2), 512, 0, stream>>>(f1, 512, 512, Wp2, part);
  k_reduce<2,512,true><<<256, 256, 0, stream>>>(part, bp2, f2, 128*512);
  k_logits<<<GRAPHS, 256, 0, stream>>>(f2, Wlog, blog, out);
  // value head
  k_gemm_part<4,128,192,8,128><<<dim3(1,32,8), 512, 0, stream>>>(obs, 1500, 1500, Wv1, part);
  k_reduce<8,128,true><<<64, 256, 0, stream>>>(part, bv1, vh, 128*128);
  k_vfin<<<GRAPHS, 128, 0, stream>>>(vh, Wv2, bv2, Wvo, bvo, out);
}

// Round 7
// 534.493 us; speedup vs baseline: 3.6777x; 1.0836x over previous
//
#include <hip/hip_runtime.h>
#include <hip/hip_bf16.h>
#include <cstdint>
#include <cstddef>

#define DEV static __device__ __forceinline__

constexpr int GRAPHS = 128;
constexpr int NPG    = 1000;   // nodes per graph
constexpr int EPG    = 4000;   // edges per graph
constexpr int TOTN   = GRAPHS * NPG;  // 128000
constexpr int TOTE   = GRAPHS * EPG;  // 512000
constexpr int HD     = 64;
constexpr int OBSD   = 1500;
constexpr int AD     = 15;

typedef __attribute__((ext_vector_type(8))) short bf16x8;
typedef __attribute__((ext_vector_type(4))) float f32x4;

// ---------- helpers ----------
DEV unsigned short f2b(float f){   // round-to-nearest-even bf16
  unsigned u = __float_as_uint(f);
  return (unsigned short)((u + 0x7fffu + ((u >> 16) & 1u)) >> 16);
}
DEV float b2f(unsigned short s){ return __uint_as_float((unsigned)s << 16); }

DEV void fma4(float4& a, float s, const float4 w){
  a.x = fmaf(s, w.x, a.x); a.y = fmaf(s, w.y, a.y);
  a.z = fmaf(s, w.z, a.z); a.w = fmaf(s, w.w, a.w);
}

DEV ushort4 pack4(float4 v){
  ushort4 r; r.x=f2b(v.x); r.y=f2b(v.y); r.z=f2b(v.z); r.w=f2b(v.w); return r;
}

// ---------- weight prep: pack all layer weights to bf16 W^T ----------
// per layer (stride 32768 bf16): qkvT[192][64] | woT[64][64] | w1T[128][64] | w2T[64][128]
__global__ __launch_bounds__(256) void k_wprep(const float* __restrict__ Wq,
    const float* __restrict__ Wk, const float* __restrict__ Wv,
    const float* __restrict__ Wo, const float* __restrict__ W1,
    const float* __restrict__ W2, unsigned short* __restrict__ wpack){
  int e = blockIdx.x*256 + threadIdx.x;
  int l = e >> 15;
  int r = e & 32767;
  float val;
  if (r < 12288){
    int c = r >> 6, k = r & 63;
    val = (c < 64)  ? Wq[l*4096 + k*64 + c]
        : (c < 128) ? Wk[l*4096 + k*64 + (c-64)]
                    : Wv[l*4096 + k*64 + (c-128)];
  } else if (r < 16384){
    int i = r - 12288; int c = i >> 6, k = i & 63;
    val = Wo[l*4096 + k*64 + c];
  } else if (r < 24576){
    int i = r - 16384; int c = i >> 6, k = i & 63;
    val = W1[l*8192 + k*128 + c];
  } else {
    int i = r - 24576; int c = i >> 7, k = i & 127;
    val = W2[l*8192 + k*64 + c];
  }
  wpack[e] = f2b(val);
}

// ---------- CSR build (once per call; reused by all 4 layers) ----------
__global__ __launch_bounds__(256) void k_zero(int* __restrict__ cnt){
  cnt[blockIdx.x*256 + threadIdx.x] = 0;
}

__global__ __launch_bounds__(256) void k_hist(const int* __restrict__ edst,
                                              int* __restrict__ cnt){
  int e = blockIdx.x*256 + threadIdx.x;
  atomicAdd(&cnt[edst[e]], 1);
}

__global__ __launch_bounds__(1024) void k_scan(const int* __restrict__ cnt,
    int* __restrict__ rstart, int* __restrict__ cursor){
  __shared__ int s[1024];
  const int g = blockIdx.x, tid = threadIdx.x;
  int v = (tid < NPG) ? cnt[g*NPG + tid] : 0;
  s[tid] = v;
  __syncthreads();
  #pragma unroll
  for (int off=1; off<1024; off<<=1){
    int t = (tid >= off) ? s[tid-off] : 0;
    __syncthreads();
    s[tid] += t;
    __syncthreads();
  }
  if (tid < NPG){
    int r = g*EPG + (s[tid] - v);
    rstart[g*NPG+tid] = r;
    cursor[g*NPG+tid] = r;
  }
}

__global__ __launch_bounds__(256) void k_scatter(const int* __restrict__ esrc,
    const int* __restrict__ edst, int* __restrict__ cursor,
    int* __restrict__ esorted){
  int e = blockIdx.x*256 + threadIdx.x;
  int pos = atomicAdd(&cursor[edst[e]], 1);
  esorted[pos] = esrc[e];
}

// ---------- K1: x(bf16) = node_feats @ W_in  [128000,32]x[32,64] ----------
__global__ __launch_bounds__(256) void k_in(const float* __restrict__ nf,
                                            const float* __restrict__ Win,
                                            unsigned short* __restrict__ xb){
  __shared__ float  s_nf[256*36];
  __shared__ float4 s_w[512];
  const int tid = threadIdx.x;
  const int node0 = blockIdx.x * 256;
  const float4* W4 = (const float4*)Win;
  s_w[tid] = W4[tid]; s_w[tid+256] = W4[tid+256];
  const float4* nf4 = (const float4*)nf;
  float4* snf4 = (float4*)s_nf;
  #pragma unroll
  for (int r=0;r<8;r++){
    int i = tid + 256*r; int n = i>>3, k4 = i&7;
    snf4[n*9 + k4] = nf4[(size_t)(node0+n)*8 + k4];
  }
  __syncthreads();
  const int ng = tid>>2, cg = tid&3;
  float4 acc[4][4];
  #pragma unroll
  for (int i=0;i<4;i++){ acc[i][0]=make_float4(0,0,0,0); acc[i][1]=make_float4(0,0,0,0);
                         acc[i][2]=make_float4(0,0,0,0); acc[i][3]=make_float4(0,0,0,0); }
  #pragma unroll 4
  for (int k=0;k<32;k++){
    float nv[4];
    #pragma unroll
    for (int i=0;i<4;i++) nv[i] = s_nf[(ng + 64*i)*36 + k];
    float4 w[4];
    #pragma unroll
    for (int j=0;j<4;j++) w[j] = s_w[k*16 + cg*4 + j];
    #pragma unroll
    for (int i=0;i<4;i++){
      #pragma unroll
      for (int j=0;j<4;j++) fma4(acc[i][j], nv[i], w[j]);
    }
  }
  ushort4* xb4 = (ushort4*)xb;
  #pragma unroll
  for (int i=0;i<4;i++){
    size_t nidx = (size_t)(node0 + ng + 64*i) * 16;
    #pragma unroll
    for (int j=0;j<4;j++) xb4[nidx + cg*4 + j] = pack4(acc[i][j]);
  }
}

// ---------- K2 (MFMA): qkv(bf16) = x @ [Wq|Wk|Wv], 256 nodes/block ----------
// Column-half staged epilogue: 40KB LDS -> 4 blocks/CU (was 53KB -> 2).
__global__ __launch_bounds__(256) void k_qkv_m(const unsigned short* __restrict__ xb,
    const unsigned short* __restrict__ wqkvT,   // [192][64] bf16
    unsigned short* __restrict__ qkv){
  __shared__ short s_w[192*72];        // 27.6KB
  __shared__ short s_st[4][16*104];    // 13.3KB; pitch 104 (208B, 16B-aligned)
  const int tid = threadIdx.x;
  const int node0 = blockIdx.x * 256;
  {
    const unsigned* src = (const unsigned*)wqkvT;
    unsigned* dst = (unsigned*)s_w;
    #pragma unroll
    for (int r=0;r<24;r++){
      int j = tid + 256*r;
      int c = j >> 5, kk = j & 31;
      dst[c*36 + kk] = src[j];
    }
  }
  __syncthreads();
  const int lane = tid & 63, wave = tid >> 6;
  const int m = lane & 15, quad = lane >> 4;
  const int rowbase = node0 + wave*64;
  bf16x8 af[4][2];
  #pragma unroll
  for (int rt=0;rt<4;rt++){
    const unsigned short* xp = xb + (size_t)(rowbase + rt*16 + m)*64 + quad*8;
    af[rt][0] = *(const bf16x8*)xp;
    af[rt][1] = *(const bf16x8*)(xp + 32);
  }
  short* st = s_st[wave];
  #pragma unroll
  for (int rt=0;rt<4;rt++){
    #pragma unroll
    for (int half=0; half<2; half++){
      #pragma unroll
      for (int c6=0;c6<6;c6++){
        int ct = half*6 + c6;
        bf16x8 b0 = *(const bf16x8*)&s_w[(ct*16+m)*72 + quad*8];
        bf16x8 b1 = *(const bf16x8*)&s_w[(ct*16+m)*72 + 32 + quad*8];
        f32x4 acc = {0.f,0.f,0.f,0.f};
        acc = __builtin_amdgcn_mfma_f32_16x16x32_bf16(af[rt][0], b0, acc, 0,0,0);
        acc = __builtin_amdgcn_mfma_f32_16x16x32_bf16(af[rt][1], b1, acc, 0,0,0);
        #pragma unroll
        for (int i=0;i<4;i++)
          st[(quad*4+i)*104 + c6*16 + m] = (short)f2b(acc[i]);
      }
      // coalesced writeout of this 16x96 half-tile
      #pragma unroll
      for (int j=0;j<3;j++){
        int flat = (j*64 + lane)*8;
        int r = flat / 96, c = flat % 96;
        bf16x8 v = *(const bf16x8*)&st[r*104 + c];
        *(bf16x8*)(qkv + (size_t)(rowbase + rt*16 + r)*192 + half*96 + c) = v;
      }
    }
  }
}

// ---------- K4: edge attention via CSR gather; XCD-swizzled ----------
__global__ __launch_bounds__(256) void k_edge2(const unsigned short* __restrict__ qkv,
    const int* __restrict__ rstart, const int* __restrict__ cnt,
    const int* __restrict__ esorted, unsigned short* __restrict__ attn_in){
  const int tid = threadIdx.x;
  const int wb = (blockIdx.x & 7)*1000 + (blockIdx.x >> 3);
  const int lane = tid & 63;
  const int sub  = lane >> 4;
  const int dg   = lane & 15;
  const int wave = tid >> 6;
  const int node = wb*16 + wave*4 + sub;
  const ushort4* row = (const ushort4*)(qkv + (size_t)node*192);
  ushort4 qu = row[dg];
  float q0 = b2f(qu.x), q1 = b2f(qu.y), q2 = b2f(qu.z), q3 = b2f(qu.w);
  const int rs = rstart[node];
  const int n  = cnt[node];
  float a0=0.f, a1=0.f, a2=0.f, a3=0.f, den=0.f;
  for (int i=0;i<n;i++){
    int src = esorted[rs + i];
    ushort4 ku = *(const ushort4*)(qkv + (size_t)src*192 + 64 + dg*4);
    ushort4 vu = *(const ushort4*)(qkv + (size_t)src*192 + 128 + dg*4);
    float p = q0*b2f(ku.x) + q1*b2f(ku.y) + q2*b2f(ku.z) + q3*b2f(ku.w);
    p += __shfl_xor(p, 1);
    p += __shfl_xor(p, 2);          // sum over the 4 lanes of this head
    float w = __expf(p * 0.25f);    // softmax shift-invariant; skip segment_max
    den += w;
    a0 = fmaf(w, b2f(vu.x), a0);
    a1 = fmaf(w, b2f(vu.y), a1);
    a2 = fmaf(w, b2f(vu.z), a2);
    a3 = fmaf(w, b2f(vu.w), a3);
  }
  float inv = 1.0f/(den + 1e-9f);
  ushort4 o;
  o.x = f2b(a0*inv); o.y = f2b(a1*inv); o.z = f2b(a2*inv); o.w = f2b(a3*inv);
  ((ushort4*)attn_in)[(size_t)node*16 + dg] = o;
}

// ---------- K5 (MFMA): x = LN(x + attn_in @ Wo), 256 nodes/block ----------
__global__ __launch_bounds__(256) void k_attn_m(const unsigned short* __restrict__ attn_in,
    const unsigned short* __restrict__ woT, const float* __restrict__ lg,
    const float* __restrict__ lb, unsigned short* __restrict__ xb){
  __shared__ short s_w[64*72];        // 9.2KB
  __shared__ short s_st[4][16*72];    // 9.2KB
  const int tid = threadIdx.x;
  const int node0 = blockIdx.x*256;
  {
    const unsigned* src = (const unsigned*)woT;
    unsigned* dst = (unsigned*)s_w;
    #pragma unroll
    for (int r=0;r<8;r++){
      int j = tid + 256*r;
      int c = j >> 5, kk = j & 31;
      dst[c*36 + kk] = src[j];
    }
  }
  __syncthreads();
  const int lane = tid&63, wave = tid>>6;
  const int m = lane&15, quad = lane>>4;
  const int rowbase = node0 + wave*64;
  bf16x8 bf[4][2];
  #pragma unroll
  for (int ct=0;ct<4;ct++){
    bf[ct][0] = *(const bf16x8*)&s_w[(ct*16+m)*72 + quad*8];
    bf[ct][1] = *(const bf16x8*)&s_w[(ct*16+m)*72 + 32 + quad*8];
  }
  float g[4], bb[4];
  #pragma unroll
  for (int ct=0;ct<4;ct++){ g[ct]=lg[ct*16+m]; bb[ct]=lb[ct*16+m]; }
  short* st = s_st[wave];
  #pragma unroll
  for (int rt=0;rt<4;rt++){
    const unsigned short* ap = attn_in + (size_t)(rowbase + rt*16 + m)*64 + quad*8;
    bf16x8 a0 = *(const bf16x8*)ap;
    bf16x8 a1 = *(const bf16x8*)(ap + 32);
    f32x4 acc[4];
    #pragma unroll
    for (int ct=0;ct<4;ct++){
      f32x4 z = {0.f,0.f,0.f,0.f};
      z = __builtin_amdgcn_mfma_f32_16x16x32_bf16(a0, bf[ct][0], z, 0,0,0);
      z = __builtin_amdgcn_mfma_f32_16x16x32_bf16(a1, bf[ct][1], z, 0,0,0);
      acc[ct] = z;
    }
    #pragma unroll
    for (int i=0;i<4;i++){
      size_t row = (size_t)(rowbase + rt*16 + quad*4 + i)*64;
      float v0 = acc[0][i] + b2f(xb[row + m]);
      float v1 = acc[1][i] + b2f(xb[row + 16 + m]);
      float v2 = acc[2][i] + b2f(xb[row + 32 + m]);
      float v3 = acc[3][i] + b2f(xb[row + 48 + m]);
      float sm = v0+v1+v2+v3;
      float sq = v0*v0+v1*v1+v2*v2+v3*v3;
      #pragma unroll
      for (int mk=1; mk<16; mk<<=1){ sm += __shfl_xor(sm, mk); sq += __shfl_xor(sq, mk); }
      float mean = sm*0.015625f;
      float var  = sq*0.015625f - mean*mean;
      float rs   = rsqrtf(var + 1e-5f);
      int rl = quad*4 + i;
      st[rl*72 + m]      = (short)f2b((v0-mean)*rs*g[0]+bb[0]);
      st[rl*72 + 16 + m] = (short)f2b((v1-mean)*rs*g[1]+bb[1]);
      st[rl*72 + 32 + m] = (short)f2b((v2-mean)*rs*g[2]+bb[2]);
      st[rl*72 + 48 + m] = (short)f2b((v3-mean)*rs*g[3]+bb[3]);
    }
    #pragma unroll
    for (int j=0;j<2;j++){
      int flat = (j*64 + lane)*8;
      int r = flat >> 6, c = flat & 63;
      bf16x8 v = *(const bf16x8*)&st[r*72 + c];
      *(bf16x8*)(xb + (size_t)(rowbase + rt*16 + r)*64 + c) = v;
    }
  }
}

// ---------- K6+K7 fused (MFMA): x = LN(x + ffn(x)), h never leaves LDS ----------
// Per-wave: h tile (16x128) computed into private LDS stage, re-read as ffn2
// A-fragments (wave-synchronous), residual+LN2, coalesced store of xb.
// LDS = 18432 + 17408 + 17408 = 53248 B -> 3 blocks/CU (159744 <= 163840).
__global__ __launch_bounds__(256) void k_ffn_m(unsigned short* __restrict__ xb,
    const unsigned short* __restrict__ w1T, const float* __restrict__ b1_l,
    const unsigned short* __restrict__ w2T, const float* __restrict__ b2_l,
    const float* __restrict__ lg, const float* __restrict__ lb){
  __shared__ short s_w1[128*72];      // 18.4KB
  __shared__ short s_w2[64*136];      // 17.4KB
  __shared__ short s_st[4][16*136];   // 17.4KB (h stage; cols 0..63 reused for LN2 out)
  const int tid = threadIdx.x;
  const int node0 = blockIdx.x*256;
  {
    const unsigned* src = (const unsigned*)w1T;
    unsigned* dst = (unsigned*)s_w1;
    #pragma unroll
    for (int r=0;r<16;r++){
      int j = tid + 256*r;
      int c = j >> 5, kk = j & 31;
      dst[c*36 + kk] = src[j];
    }
  }
  {
    const unsigned* src = (const unsigned*)w2T;
    unsigned* dst = (unsigned*)s_w2;
    #pragma unroll
    for (int r=0;r<16;r++){
      int j = tid + 256*r;
      int c = j >> 6, kk = j & 63;
      dst[c*68 + kk] = src[j];
    }
  }
  __syncthreads();
  const int lane = tid&63, wave = tid>>6;
  const int m = lane&15, quad = lane>>4;
  const int rowbase = node0 + wave*64;
  bf16x8 af[4][2];
  #pragma unroll
  for (int rt=0;rt<4;rt++){
    const unsigned short* xp = xb + (size_t)(rowbase + rt*16 + m)*64 + quad*8;
    af[rt][0] = *(const bf16x8*)xp;
    af[rt][1] = *(const bf16x8*)(xp + 32);
  }
  float g[4], bb[4], b2v[4];
  #pragma unroll
  for (int ct=0;ct<4;ct++){ g[ct]=lg[ct*16+m]; bb[ct]=lb[ct*16+m]; b2v[ct]=b2_l[ct*16+m]; }
  short* st = s_st[wave];
  #pragma unroll
  for (int rt=0;rt<4;rt++){
    // ---- ffn1: h = relu(x@W1 + b1) into stage ----
    #pragma unroll
    for (int ct=0;ct<8;ct++){
      bf16x8 b0 = *(const bf16x8*)&s_w1[(ct*16+m)*72 + quad*8];
      bf16x8 b1 = *(const bf16x8*)&s_w1[(ct*16+m)*72 + 32 + quad*8];
      float bias = b1_l[ct*16+m];
      f32x4 acc = {0.f,0.f,0.f,0.f};
      acc = __builtin_amdgcn_mfma_f32_16x16x32_bf16(af[rt][0], b0, acc, 0,0,0);
      acc = __builtin_amdgcn_mfma_f32_16x16x32_bf16(af[rt][1], b1, acc, 0,0,0);
      #pragma unroll
      for (int i=0;i<4;i++)
        st[(quad*4+i)*136 + ct*16 + m] = (short)f2b(fmaxf(acc[i]+bias, 0.f));
    }
    // ---- ffn2 A-fragments from stage (wave-synchronous) ----
    bf16x8 h0 = *(const bf16x8*)&st[m*136 + quad*8];
    bf16x8 h1 = *(const bf16x8*)&st[m*136 + 32 + quad*8];
    bf16x8 h2 = *(const bf16x8*)&st[m*136 + 64 + quad*8];
    bf16x8 h3 = *(const bf16x8*)&st[m*136 + 96 + quad*8];
    f32x4 acc2[4];
    #pragma unroll
    for (int ct=0;ct<4;ct++){
      f32x4 z = {0.f,0.f,0.f,0.f};
      z = __builtin_amdgcn_mfma_f32_16x16x32_bf16(h0, *(const bf16x8*)&s_w2[(ct*16+m)*136 + quad*8],      z, 0,0,0);
      z = __builtin_amdgcn_mfma_f32_16x16x32_bf16(h1, *(const bf16x8*)&s_w2[(ct*16+m)*136 + 32 + quad*8], z, 0,0,0);
      z = __builtin_amdgcn_mfma_f32_16x16x32_bf16(h2, *(const bf16x8*)&s_w2[(ct*16+m)*136 + 64 + quad*8], z, 0,0,0);
      z = __builtin_amdgcn_mfma_f32_16x16x32_bf16(h3, *(const bf16x8*)&s_w2[(ct*16+m)*136 + 96 + quad*8], z, 0,0,0);
      acc2[ct] = z;
    }
    // ---- residual + LN2; write into stage cols 0..63 (h frags already consumed) ----
    #pragma unroll
    for (int i=0;i<4;i++){
      size_t row = (size_t)(rowbase + rt*16 + quad*4 + i)*64;
      float v0 = acc2[0][i] + b2v[0] + b2f(xb[row + m]);
      float v1 = acc2[1][i] + b2v[1] + b2f(xb[row + 16 + m]);
      float v2 = acc2[2][i] + b2v[2] + b2f(xb[row + 32 + m]);
      float v3 = acc2[3][i] + b2v[3] + b2f(xb[row + 48 + m]);
      float sm = v0+v1+v2+v3;
      float sq = v0*v0+v1*v1+v2*v2+v3*v3;
      #pragma unroll
      for (int mk=1; mk<16; mk<<=1){ sm += __shfl_xor(sm, mk); sq += __shfl_xor(sq, mk); }
      float mean = sm*0.015625f;
      float var  = sq*0.015625f - mean*mean;
      float rs   = rsqrtf(var + 1e-5f);
      int rl = quad*4 + i;
      st[rl*136 + m]      = (short)f2b((v0-mean)*rs*g[0]+bb[0]);
      st[rl*136 + 16 + m] = (short)f2b((v1-mean)*rs*g[1]+bb[1]);
      st[rl*136 + 32 + m] = (short)f2b((v2-mean)*rs*g[2]+bb[2]);
      st[rl*136 + 48 + m] = (short)f2b((v3-mean)*rs*g[3]+bb[3]);
    }
    #pragma unroll
    for (int j=0;j<2;j++){
      int flat = (j*64 + lane)*8;
      int r = flat >> 6, c = flat & 63;
      bf16x8 v = *(const bf16x8*)&st[r*136 + c];
      *(bf16x8*)(xb + (size_t)(rowbase + rt*16 + r)*64 + c) = v;
    }
  }
}

// ---------- heads: feat assembly ----------
__global__ __launch_bounds__(256) void k_feat(const unsigned short* __restrict__ xb,
    const float* __restrict__ obs, const int* __restrict__ agents,
    const float* __restrict__ Wr, const float* __restrict__ br,
    float* __restrict__ feat){
  __shared__ float s_xa[64];
  const int b = blockIdx.x, tid = threadIdx.x;
  if (tid < 64) s_xa[tid] = b2f(xb[(size_t)agents[b]*HD + tid]);
  __syncthreads();
  if (tid < AD){
    float a = br[tid];
    #pragma unroll 8
    for (int k=0;k<HD;k++) a = fmaf(s_xa[k], Wr[k*AD + tid], a);
    feat[(size_t)b*1536 + tid] = a;
  }
  for (int i=tid;i<OBSD;i+=256) feat[(size_t)b*1536 + AD + i] = obs[(size_t)b*OBSD + i];
  if (tid < 21) feat[(size_t)b*1536 + 1515 + tid] = 0.f;
}

// ---------- heads: split-K partial GEMM ----------
template<int ROWS, int COLS, int CH, int KS, int N>
__global__ __launch_bounds__(ROWS*COLS) void k_gemm_part(
    const float* __restrict__ A, int lda, int K,
    const float* __restrict__ W, float* __restrict__ part){
  constexpr int BT = ROWS*COLS;
  __shared__ float s_a[ROWS*CH];
  const int tid = threadIdx.x;
  const int ct = blockIdx.x, rg = blockIdx.y, ks = blockIdx.z;
  const int chunk = (K + KS - 1) / KS;
  const int k0 = ks * chunk;
  const int len = min(K - k0, chunk);
  const int row0 = rg * ROWS;
  #pragma unroll
  for (int rr=0; rr<ROWS; rr++)
    for (int i=tid; i<len; i+=BT)
      s_a[rr*CH + i] = A[(size_t)(row0+rr)*lda + k0 + i];
  __syncthreads();
  const int r = tid / COLS, c = tid % COLS;
  const float* wp = W + (size_t)k0*N + ct*COLS + c;
  const float* ap = s_a + r*CH;
  float acc = 0.f;
  #pragma unroll 8
  for (int k=0;k<len;k++) acc = fmaf(ap[k], wp[(size_t)k*N], acc);
  part[((size_t)ks*128 + row0 + r)*N + ct*COLS + c] = acc;
}

template<int KS, int N, bool TANH>
__global__ __launch_bounds__(256) void k_reduce(const float* __restrict__ part,
    const float* __restrict__ bias, float* __restrict__ out, int MN){
  const int idx = blockIdx.x*256 + threadIdx.x;
  if (idx >= MN) return;
  float s = bias[idx & (N-1)];
  #pragma unroll
  for (int ks=0;ks<KS;ks++) s += part[(size_t)ks*MN + idx];
  out[idx] = TANH ? tanhf(s) : s;
}

// ---------- heads: logits ----------
__global__ __launch_bounds__(256) void k_logits(const float* __restrict__ f2,
    const float* __restrict__ Wlog, const float* __restrict__ blog,
    float* __restrict__ out){
  __shared__ float s_f[512];
  __shared__ float s_p[16*AD];
  const int b = blockIdx.x, tid = threadIdx.x;
  s_f[tid]     = f2[(size_t)b*512 + tid];
  s_f[tid+256] = f2[(size_t)b*512 + 256 + tid];
  __syncthreads();
  if (tid < 240){
    int c = tid % AD, kc = tid / AD;
    float a = 0.f;
    #pragma unroll 8
    for (int j=0;j<32;j++){ int k = kc*32 + j; a = fmaf(s_f[k], Wlog[k*AD + c], a); }
    s_p[tid] = a;
  }
  __syncthreads();
  if (tid < AD){
    float a = blog[tid];
    #pragma unroll
    for (int kc=0;kc<16;kc++) a += s_p[kc*AD + tid];
    out[(size_t)b*AD + tid] = a;
  }
}

// ---------- heads: value finish ----------
__global__ __launch_bounds__(128) void k_vfin(const float* __restrict__ vh,
    const float* __restrict__ Wv2, const float* __restrict__ bv2,
    const float* __restrict__ Wvo, const float* __restrict__ bvo,
    float* __restrict__ out){
  __shared__ float s_v[128];
  __shared__ float s_r[128];
  const int b = blockIdx.x, tid = threadIdx.x;
  s_v[tid] = vh[(size_t)b*128 + tid];
  __syncthreads();
  float a = bv2[tid];
  #pragma unroll 8
  for (int k=0;k<128;k++) a = fmaf(s_v[k], Wv2[k*128 + tid], a);
  s_r[tid] = tanhf(a) * Wvo[tid];
  __syncthreads();
  if (tid < 64){
    float v = s_r[tid] + s_r[tid+64];
    #pragma unroll
    for (int m=32;m>=1;m>>=1) v += __shfl_xor(v, m);
    if (tid==0) out[GRAPHS*AD + b] = v + bvo[0];
  }
}

// ---------- launch ----------
extern "C" void kernel_launch(void* const* d_in, const int* in_sizes, int n_in,
                              void* d_out, int out_size, void* d_ws, size_t ws_size,
                              hipStream_t stream) {
  (void)in_sizes; (void)n_in; (void)out_size; (void)ws_size;
  const float* nf     = (const float*)d_in[0];
  const float* obs    = (const float*)d_in[1];
  const int*   esrc   = (const int*)d_in[2];
  const int*   edst   = (const int*)d_in[3];
  const int*   agents = (const int*)d_in[4];
  const float* Win    = (const float*)d_in[5];
  const float* Wq     = (const float*)d_in[6];
  const float* Wk     = (const float*)d_in[7];
  const float* Wv     = (const float*)d_in[8];
  const float* Wo     = (const float*)d_in[9];
  const float* ln1g   = (const float*)d_in[10];
  const float* ln1b   = (const float*)d_in[11];
  const float* W1     = (const float*)d_in[12];
  const float* b1     = (const float*)d_in[13];
  const float* W2     = (const float*)d_in[14];
  const float* b2     = (const float*)d_in[15];
  const float* ln2g   = (const float*)d_in[16];
  const float* ln2b   = (const float*)d_in[17];
  const float* Wr     = (const float*)d_in[18];
  const float* br     = (const float*)d_in[19];
  const float* Wp1    = (const float*)d_in[20];
  const float* bp1    = (const float*)d_in[21];
  const float* Wp2    = (const float*)d_in[22];
  const float* bp2    = (const float*)d_in[23];
  const float* Wlog   = (const float*)d_in[24];
  const float* blog   = (const float*)d_in[25];
  const float* Wv1    = (const float*)d_in[26];
  const float* bv1    = (const float*)d_in[27];
  const float* Wv2    = (const float*)d_in[28];
  const float* bv2    = (const float*)d_in[29];
  const float* Wvo    = (const float*)d_in[30];
  const float* bvo    = (const float*)d_in[31];
  float* out = (float*)d_out;

  // workspace layout (all bf16 activations)
  unsigned short* xb      = (unsigned short*)d_ws;             // TOTN*64 bf16
  unsigned short* qkv     = xb + (size_t)TOTN*HD;              // TOTN*192 bf16
  unsigned short* attn_in = qkv + (size_t)TOTN*192;            // TOTN*64 bf16
  unsigned short* wpack   = attn_in + (size_t)TOTN*HD;         // 131072 bf16
  int* cnt     = (int*)(wpack + 131072);                       // TOTN
  int* rstart  = cnt + TOTN;
  int* cursor  = rstart + TOTN;
  int* esorted = cursor + TOTN;                                // TOTE
  // head buffers (float) after the int region
  float* feat = (float*)(esorted + TOTE);                      // 128*1536
  float* f1   = feat + 128*1536;
  float* f2   = f1 + 128*512;
  float* vh   = f2 + 128*512;
  float* part = vh + 128*128;                                  // up to 4*128*512

  // weight prep + CSR build (edge topology is layer-invariant)
  k_wprep  <<<512, 256, 0, stream>>>(Wq, Wk, Wv, Wo, W1, W2, wpack);
  k_zero   <<<TOTN/256, 256, 0, stream>>>(cnt);
  k_hist   <<<TOTE/256, 256, 0, stream>>>(edst, cnt);
  k_scan   <<<GRAPHS, 1024, 0, stream>>>(cnt, rstart, cursor);
  k_scatter<<<TOTE/256, 256, 0, stream>>>(esrc, edst, cursor, esorted);

  k_in<<<TOTN/256, 256, 0, stream>>>(nf, Win, xb);
  for (int l=0; l<4; l++){
    const unsigned short* wl = wpack + l*32768;
    k_qkv_m <<<TOTN/256, 256, 0, stream>>>(xb, wl, qkv);
    k_edge2 <<<TOTN/16, 256, 0, stream>>>(qkv, rstart, cnt, esorted, attn_in);
    k_attn_m<<<TOTN/256, 256, 0, stream>>>(attn_in, wl + 12288,
                                           ln1g + l*64, ln1b + l*64, xb);
    k_ffn_m <<<TOTN/256, 256, 0, stream>>>(xb, wl + 16384, b1 + l*128,
                                           wl + 24576, b2 + l*64,
                                           ln2g + l*64, ln2b + l*64);
  }
  // policy head
  k_feat<<<GRAPHS, 256, 0, stream>>>(xb, obs, agents, Wr, br, feat);
  k_gemm_part<2,256,384,4,512><<<dim3(2,64,4), 512, 0, stream>>>(feat, 1536, 1515, Wp1, part);
  k_reduce<4,512,true><<<256, 256, 0, stream>>>(part, bp1, f1, 128*512);
  k_gemm_part<2,256,256,2,512><<<dim3(2,64,2), 512, 0, stream>>>(f1, 512, 512, Wp2, part);
  k_reduce<2,512,true><<<256, 256, 0, stream>>>(part, bp2, f2, 128*512);
  k_logits<<<GRAPHS, 256, 0, stream>>>(f2, Wlog, blog, out);
  // value head
  k_gemm_part<4,128,192,8,128><<<dim3(1,32,8), 512, 0, stream>>>(obs, 1500, 1500, Wv1, part);
  k_reduce<8,128,true><<<64, 256, 0, stream>>>(part, bv1, vh, 128*128);
  k_vfin<<<GRAPHS, 128, 0, stream>>>(vh, Wv2, bv2, Wvo, bvo, out);
}